// Round 3
// baseline (1158.675 us; speedup 1.0000x reference)
//
#include <hip/hip_runtime.h>
#include <hip/hip_bf16.h>

#define DEV __device__ __forceinline__

constexpr int B = 2;
constexpr int CM = 1536;
constexpr int CS = 384;
constexpr int HP = 32, WP = 32, P = 1024;
constexpr int HI = 448, WI = 448;
constexpr int HM = 128;
constexpr int NSEG = 64;

// ws layout (floats)
constexpr size_t OFF_AVG  = 0;                          // B*64*384      = 49152
constexpr size_t OFF_SEM  = 49152;                      // B*384*1024    = 786432
constexpr size_t OFF_HSH  = 835584;                     // B*384*1024    = 786432
constexpr size_t OFF_OUT0 = 1622016;                    // B*1536*1024   = 3145728
constexpr size_t OFF_P6   = 4767744;                    // B*24*8*1024   = 393216
constexpr size_t OFF_H1A  = 5160960;                    // B*8*1024      = 16384
constexpr size_t OFF_OUT1 = 5177344;                    // 16384
constexpr size_t OFF_H2A  = 5193728;                    // B*16*1024     = 32768
constexpr size_t OFF_OUT2 = 5226496;                    // 32768
constexpr size_t OFF_STATS= 5259264;                    // 16 floats: (stage*B + b)*2 + {sum,sumsq}

DEV float softplus_f(float x) {
    return fmaxf(x, 0.f) + log1pf(expf(-fabsf(x)));
}

// -------------------- 1. segment averages over 14-strided 32x32 samples -----
__global__ __launch_bounds__(256) void k_seg_avg(const float* __restrict__ f_sem,
                                                 const int* __restrict__ segmap,
                                                 float* __restrict__ ws) {
    int b = blockIdx.y, cc = blockIdx.x;      // cc: chunk of 64 channels (6 chunks)
    __shared__ float sums[NSEG][64];
    __shared__ float cnt[NSEG];
    __shared__ int   segs[P];
    int t = threadIdx.x;
    for (int i = t; i < NSEG * 64; i += 256) sums[i / 64][i % 64] = 0.f;
    if (t < NSEG) cnt[t] = 0.f;
    __syncthreads();
    for (int p = t; p < P; p += 256) {
        int i = p >> 5, j = p & 31;
        int s = segmap[(b * HI + i * 14) * WI + j * 14];
        s = min(max(s, 0), NSEG - 1);
        segs[p] = s;
        atomicAdd(&cnt[s], 1.f);
    }
    __syncthreads();
    int c = cc * 64 + (t & 63);
    int g = t >> 6;
    const float* fp = f_sem + ((size_t)b * CS + c) * P;
    for (int p = g; p < P; p += 4) {
        atomicAdd(&sums[segs[p]][t & 63], fp[p]);
    }
    __syncthreads();
    for (int i = t; i < NSEG * 64; i += 256) {
        int s = i / 64, cl = i % 64;
        float cv = cnt[s];
        ws[OFF_AVG + ((size_t)(b * NSEG + s)) * CS + cc * 64 + cl] =
            cv > 0.f ? sums[s][cl] / cv : 0.f;
    }
}

// -------------------- 2. fused paint + antialiased bilinear downsample ------
__global__ __launch_bounds__(256) void k_paint(const int* __restrict__ segmap,
                                               float* __restrict__ ws) {
    int pixb = blockIdx.x;            // b*1024 + opix
    int b = pixb >> 10, op = pixb & 1023;
    int oy = op >> 5, ox = op & 31;
    __shared__ float Wb[NSEG];
    __shared__ float normv;
    int t = threadIdx.x;
    if (t < NSEG) Wb[t] = 0.f;
    __syncthreads();
    float cy = 14.f * oy + 6.5f, cx = 14.f * ox + 6.5f;
    int y0 = 14 * oy - 7, x0 = 14 * ox - 7;
    for (int k = t; k < 28 * 28; k += 256) {
        int jy = y0 + k / 28, jx = x0 + k % 28;
        if (jy < 0 || jy >= HI || jx < 0 || jx >= WI) continue;
        float wy = 1.f - fabsf(cy - (float)jy) * (1.f / 14.f);
        float wx = 1.f - fabsf(cx - (float)jx) * (1.f / 14.f);
        int s = segmap[(b * HI + jy) * WI + jx];
        s = min(max(s, 0), NSEG - 1);
        atomicAdd(&Wb[s], wy * wx);
    }
    if (t == 0) {
        float sy = 0.f, sx = 0.f;
        for (int d = 0; d < 28; d++) {
            int jy = y0 + d;
            if (jy >= 0 && jy < HI) sy += 1.f - fabsf(cy - (float)jy) * (1.f / 14.f);
            int jx = x0 + d;
            if (jx >= 0 && jx < WI) sx += 1.f - fabsf(cx - (float)jx) * (1.f / 14.f);
        }
        normv = 1.f / (sy * sx);
    }
    __syncthreads();
    float nv = normv;
    for (int c = t; c < CS; c += 256) {
        float acc = 0.f;
        const float* ap = ws + OFF_AVG + ((size_t)b * NSEG) * CS + c;
        #pragma unroll
        for (int s = 0; s < NSEG; s++) acc += Wb[s] * ap[(size_t)s * CS];
        ws[OFF_SEM + ((size_t)b * CS + c) * P + op] = acc * nv;
    }
}

// -------------------- 3. LN0 stats over x_main --------------------
__global__ __launch_bounds__(256) void k_ln0_stats(const float* __restrict__ x,
                                                   float* __restrict__ stats) {
    int b = blockIdx.y;
    const float4* xp = (const float4*)(x + (size_t)b * CM * P);
    int n4 = CM * P / 4;
    float s = 0.f, q = 0.f;
    for (int i = blockIdx.x * 256 + threadIdx.x; i < n4; i += 64 * 256) {
        float4 v = xp[i];
        s += v.x + v.y + v.z + v.w;
        q += v.x * v.x + v.y * v.y + v.z * v.z + v.w * v.w;
    }
    for (int o = 32; o > 0; o >>= 1) { s += __shfl_down(s, o); q += __shfl_down(q, o); }
    __shared__ float ls[4], lq[4];
    int w = threadIdx.x >> 6;
    if ((threadIdx.x & 63) == 0) { ls[w] = s; lq[w] = q; }
    __syncthreads();
    if (threadIdx.x == 0) {
        atomicAdd(&stats[b * 2],     ls[0] + ls[1] + ls[2] + ls[3]);
        atomicAdd(&stats[b * 2 + 1], lq[0] + lq[1] + lq[2] + lq[3]);
    }
}

// -------------------- 4. shared conv: sem_rs -> relu, 3 stages fused --------
__global__ __launch_bounds__(256) void k_conv_sh(
    const float* __restrict__ w0, const float* __restrict__ bb0,
    const float* __restrict__ w1, const float* __restrict__ bb1,
    const float* __restrict__ w2, const float* __restrict__ bb2,
    float* __restrict__ ws) {
    int pt = blockIdx.x, ct = blockIdx.y, b = blockIdx.z;
    int y0 = pt * 8;
    __shared__ float sin_[8][10][34];
    int t = threadIdx.x, px = t & 31, py = t >> 5;
    float acc[8] = {};
    const float* sem = ws + OFF_SEM + (size_t)b * CS * P;
    int sel = (ct * 8) / 128;
    const float* wsel = sel == 0 ? w0 : (sel == 1 ? w1 : w2);
    const float* bsel = sel == 0 ? bb0 : (sel == 1 ? bb1 : bb2);
    int coBase = (ct * 8) & 127;
    for (int c0 = 0; c0 < CS; c0 += 8) {
        __syncthreads();
        for (int i = t; i < 2720; i += 256) {
            int ci = i / 340, rem = i % 340, r = rem / 34, cc = rem % 34;
            int gy = y0 - 1 + r, gx = cc - 1;
            sin_[ci][r][cc] = (gy >= 0 && gy < HP && gx >= 0 && gx < WP)
                                  ? sem[(size_t)(c0 + ci) * P + gy * WP + gx] : 0.f;
        }
        __syncthreads();
        for (int ci = 0; ci < 8; ci++) {
            float i00 = sin_[ci][py][px],     i01 = sin_[ci][py][px + 1],     i02 = sin_[ci][py][px + 2];
            float i10 = sin_[ci][py + 1][px], i11 = sin_[ci][py + 1][px + 1], i12 = sin_[ci][py + 1][px + 2];
            float i20 = sin_[ci][py + 2][px], i21 = sin_[ci][py + 2][px + 1], i22 = sin_[ci][py + 2][px + 2];
            #pragma unroll
            for (int co = 0; co < 8; co++) {
                const float* wp = wsel + ((size_t)(coBase + co) * CS + c0 + ci) * 9;
                acc[co] += wp[0]*i00 + wp[1]*i01 + wp[2]*i02
                         + wp[3]*i10 + wp[4]*i11 + wp[5]*i12
                         + wp[6]*i20 + wp[7]*i21 + wp[8]*i22;
            }
        }
    }
    #pragma unroll
    for (int co = 0; co < 8; co++) {
        int cog = ct * 8 + co;
        float v = acc[co] + bsel[coBase + co];
        ws[OFF_HSH + ((size_t)b * 384 + cog) * P + pt * 256 + t] = fmaxf(v, 0.f);
    }
}

// -------------------- 5. big gamma/beta conv (128->1536 pairs) + LN combine -
__global__ __launch_bounds__(256) void k_conv_gb_big(
    const float* __restrict__ hshBase,
    const float* __restrict__ wg, const float* __restrict__ bg,
    const float* __restrict__ wbe, const float* __restrict__ bbe,
    const float* __restrict__ xsrc, const float* __restrict__ st, float Ninv,
    float* __restrict__ outp) {
    int pt = blockIdx.x, ct = blockIdx.y, b = blockIdx.z;
    int y0 = pt * 8;
    __shared__ float sin_[8][10][34];
    int t = threadIdx.x, px = t & 31, py = t >> 5;
    float ag[8] = {}, ab[8] = {};
    const float* in = hshBase + (size_t)b * 384 * P;   // stage 0 at offset 0
    for (int c0 = 0; c0 < HM; c0 += 8) {
        __syncthreads();
        for (int i = t; i < 2720; i += 256) {
            int ci = i / 340, rem = i % 340, r = rem / 34, cc = rem % 34;
            int gy = y0 - 1 + r, gx = cc - 1;
            sin_[ci][r][cc] = (gy >= 0 && gy < HP && gx >= 0 && gx < WP)
                                  ? in[(size_t)(c0 + ci) * P + gy * WP + gx] : 0.f;
        }
        __syncthreads();
        for (int ci = 0; ci < 8; ci++) {
            float i00 = sin_[ci][py][px],     i01 = sin_[ci][py][px + 1],     i02 = sin_[ci][py][px + 2];
            float i10 = sin_[ci][py + 1][px], i11 = sin_[ci][py + 1][px + 1], i12 = sin_[ci][py + 1][px + 2];
            float i20 = sin_[ci][py + 2][px], i21 = sin_[ci][py + 2][px + 1], i22 = sin_[ci][py + 2][px + 2];
            #pragma unroll
            for (int co = 0; co < 8; co++) {
                int cog = ct * 8 + co;
                const float* wp = wg + ((size_t)cog * HM + c0 + ci) * 9;
                ag[co] += wp[0]*i00 + wp[1]*i01 + wp[2]*i02
                        + wp[3]*i10 + wp[4]*i11 + wp[5]*i12
                        + wp[6]*i20 + wp[7]*i21 + wp[8]*i22;
                const float* wq = wbe + ((size_t)cog * HM + c0 + ci) * 9;
                ab[co] += wq[0]*i00 + wq[1]*i01 + wq[2]*i02
                        + wq[3]*i10 + wq[4]*i11 + wq[5]*i12
                        + wq[6]*i20 + wq[7]*i21 + wq[8]*i22;
            }
        }
    }
    float mu = st[b * 2] * Ninv;
    float var = st[b * 2 + 1] * Ninv - mu * mu;
    float rs = rsqrtf(var + 1e-12f);
    int p = pt * 256 + t;
    #pragma unroll
    for (int co = 0; co < 8; co++) {
        int cog = ct * 8 + co;
        float xv = xsrc[((size_t)b * CM + cog) * P + p];
        float xn = (xv - mu) * rs;
        outp[((size_t)b * CM + cog) * P + p] =
            xn * (1.f + ag[co] + bg[cog]) + ab[co] + bbe[cog];
    }
}

// -------------------- small gamma/beta conv (spade1/2) + LN combine ---------
DEV float in_at(const float* p, int y, int x) {
    return (y >= 0 && y < HP && x >= 0 && x < WP) ? p[y * WP + x] : 0.f;
}

__global__ __launch_bounds__(256) void k_conv_gb_small(
    const float* __restrict__ hshBase, int stage,
    const float* __restrict__ wg, const float* __restrict__ bg,
    const float* __restrict__ wbe, const float* __restrict__ bbe,
    const float* __restrict__ xsrc, const float* __restrict__ st, float Ninv,
    float* __restrict__ outp, int NP) {
    int b = blockIdx.z, ct = blockIdx.y;
    int t = threadIdx.x, lp = t & 63, g = t >> 6;
    int p = blockIdx.x * 64 + lp;
    int y = p >> 5, x = p & 31;
    const float* in = hshBase + ((size_t)b * 384 + stage * 128) * P;
    float ag[8] = {}, ab[8] = {};
    for (int ci = g * 32; ci < g * 32 + 32; ci++) {
        const float* ip = in + (size_t)ci * P;
        float v0 = in_at(ip, y - 1, x - 1), v1 = in_at(ip, y - 1, x), v2 = in_at(ip, y - 1, x + 1);
        float v3 = in_at(ip, y,     x - 1), v4 = ip[y * WP + x],      v5 = in_at(ip, y,     x + 1);
        float v6 = in_at(ip, y + 1, x - 1), v7 = in_at(ip, y + 1, x), v8 = in_at(ip, y + 1, x + 1);
        #pragma unroll
        for (int co = 0; co < 8; co++) {
            int cog = ct * 8 + co;
            const float* wp = wg + ((size_t)cog * HM + ci) * 9;
            ag[co] += wp[0]*v0 + wp[1]*v1 + wp[2]*v2 + wp[3]*v3 + wp[4]*v4
                    + wp[5]*v5 + wp[6]*v6 + wp[7]*v7 + wp[8]*v8;
            const float* wq = wbe + ((size_t)cog * HM + ci) * 9;
            ab[co] += wq[0]*v0 + wq[1]*v1 + wq[2]*v2 + wq[3]*v3 + wq[4]*v4
                    + wq[5]*v5 + wq[6]*v6 + wq[7]*v7 + wq[8]*v8;
        }
    }
    __shared__ float red[4][64][16];
    #pragma unroll
    for (int co = 0; co < 8; co++) {
        red[g][lp][co] = ag[co];
        red[g][lp][8 + co] = ab[co];
    }
    __syncthreads();
    float mu = st[b * 2] * Ninv;
    float var = st[b * 2 + 1] * Ninv - mu * mu;
    float rs = rsqrtf(var + 1e-12f);
    for (int idx = t; idx < 512; idx += 256) {
        int pp = idx >> 3, co = idx & 7;
        int cog = ct * 8 + co;
        float gam = red[0][pp][co] + red[1][pp][co] + red[2][pp][co] + red[3][pp][co] + bg[cog];
        float bet = red[0][pp][8+co] + red[1][pp][8+co] + red[2][pp][8+co] + red[3][pp][8+co] + bbe[cog];
        int pgl = blockIdx.x * 64 + pp;
        float xv = xsrc[((size_t)b * NP + cog) * P + pgl];
        float xn = (xv - mu) * rs;
        outp[((size_t)b * NP + cog) * P + pgl] = xn * (1.f + gam) + bet;
    }
}

// -------------------- 1x1 conv 1536->8, split-K partials --------------------
__global__ __launch_bounds__(256) void k_c1x1_a(const float* __restrict__ out0,
                                                const float* __restrict__ w,
                                                float* __restrict__ part) {
    int b = blockIdx.z, ks = blockIdx.y, pg = blockIdx.x;
    int t = threadIdx.x, lp = t & 63, g = t >> 6;
    int pix = pg * 64 + lp;
    float acc[8] = {};
    int ci0 = ks * 64 + g * 16;
    for (int i = 0; i < 16; i++) {
        int ci = ci0 + i;
        float v = out0[((size_t)b * CM + ci) * P + pix];
        #pragma unroll
        for (int o = 0; o < 8; o++) acc[o] += w[o * CM + ci] * v;
    }
    __shared__ float red[4][64][8];
    #pragma unroll
    for (int o = 0; o < 8; o++) red[g][lp][o] = acc[o];
    __syncthreads();
    for (int idx = t; idx < 512; idx += 256) {
        int pp = idx >> 3, o = idx & 7;
        float s = red[0][pp][o] + red[1][pp][o] + red[2][pp][o] + red[3][pp][o];
        part[(((size_t)b * 24 + ks) * 8 + o) * P + pg * 64 + pp] = s;
    }
}

__global__ __launch_bounds__(256) void k_c1x1_a_fin(const float* __restrict__ part,
                                                    const float* __restrict__ bias,
                                                    float* __restrict__ h1a,
                                                    float* __restrict__ stats) {
    int b = blockIdx.x, t = threadIdx.x;
    float s = 0.f, q = 0.f;
    for (int idx = t; idx < 8 * P; idx += 256) {
        int o = idx >> 10, pix = idx & 1023;
        float v = 0.f;
        for (int ks = 0; ks < 24; ks++) v += part[(((size_t)b * 24 + ks) * 8 + o) * P + pix];
        v += bias[o];
        v = softplus_f(v);
        h1a[((size_t)b * 8 + o) * P + pix] = v;
        s += v; q += v * v;
    }
    for (int o2 = 32; o2 > 0; o2 >>= 1) { s += __shfl_down(s, o2); q += __shfl_down(q, o2); }
    __shared__ float ls[4], lq[4];
    int w = t >> 6;
    if ((t & 63) == 0) { ls[w] = s; lq[w] = q; }
    __syncthreads();
    if (t == 0) {
        stats[(B + b) * 2]     = ls[0] + ls[1] + ls[2] + ls[3];
        stats[(B + b) * 2 + 1] = lq[0] + lq[1] + lq[2] + lq[3];
    }
}

// -------------------- 1x1 conv 8->16 + softplus + LN2 stats ----------------
__global__ __launch_bounds__(256) void k_c1x1_b(const float* __restrict__ out1,
                                                const float* __restrict__ w,
                                                const float* __restrict__ bias,
                                                float* __restrict__ h2a,
                                                float* __restrict__ stats) {
    int b = blockIdx.y, t = threadIdx.x;
    int pix = blockIdx.x * 256 + t;
    float vin[8];
    #pragma unroll
    for (int ci = 0; ci < 8; ci++) vin[ci] = out1[((size_t)b * 8 + ci) * P + pix];
    float s = 0.f, q = 0.f;
    #pragma unroll
    for (int o = 0; o < 16; o++) {
        float a = bias[o];
        #pragma unroll
        for (int ci = 0; ci < 8; ci++) a += w[o * 8 + ci] * vin[ci];
        a = softplus_f(a);
        h2a[((size_t)b * 16 + o) * P + pix] = a;
        s += a; q += a * a;
    }
    for (int o2 = 32; o2 > 0; o2 >>= 1) { s += __shfl_down(s, o2); q += __shfl_down(q, o2); }
    __shared__ float ls[4], lq[4];
    int w2 = t >> 6;
    if ((t & 63) == 0) { ls[w2] = s; lq[w2] = q; }
    __syncthreads();
    if (t == 0) {
        atomicAdd(&stats[(2 * B + b) * 2],     ls[0] + ls[1] + ls[2] + ls[3]);
        atomicAdd(&stats[(2 * B + b) * 2 + 1], lq[0] + lq[1] + lq[2] + lq[3]);
    }
}

// -------------------- final 1x1 conv 16->1 + softplus -> f32 ---------------
__global__ __launch_bounds__(256) void k_final(const float* __restrict__ out2,
                                               const float* __restrict__ w,
                                               const float* __restrict__ bias,
                                               float* __restrict__ out) {
    int b = blockIdx.y, t = threadIdx.x;
    int pix = blockIdx.x * 256 + t;
    float a = bias[0];
    #pragma unroll
    for (int ci = 0; ci < 16; ci++) a += w[ci] * out2[((size_t)b * 16 + ci) * P + pix];
    a = softplus_f(a);
    out[(size_t)b * P + pix] = a;   // reference output dtype is float32
}

extern "C" void kernel_launch(void* const* d_in, const int* in_sizes, int n_in,
                              void* d_out, int out_size, void* d_ws, size_t ws_size,
                              hipStream_t stream) {
    const float* x_main = (const float*)d_in[0];
    const float* f_sem  = (const float*)d_in[1];
    const float* w_sh0 = (const float*)d_in[2];  const float* b_sh0 = (const float*)d_in[3];
    const float* w_g0  = (const float*)d_in[4];  const float* b_g0  = (const float*)d_in[5];
    const float* w_be0 = (const float*)d_in[6];  const float* b_be0 = (const float*)d_in[7];
    const float* w_sh1 = (const float*)d_in[8];  const float* b_sh1 = (const float*)d_in[9];
    const float* w_g1  = (const float*)d_in[10]; const float* b_g1  = (const float*)d_in[11];
    const float* w_be1 = (const float*)d_in[12]; const float* b_be1 = (const float*)d_in[13];
    const float* w_sh2 = (const float*)d_in[14]; const float* b_sh2 = (const float*)d_in[15];
    const float* w_g2  = (const float*)d_in[16]; const float* b_g2  = (const float*)d_in[17];
    const float* w_be2 = (const float*)d_in[18]; const float* b_be2 = (const float*)d_in[19];
    const float* w_c0  = (const float*)d_in[20]; const float* bias0 = (const float*)d_in[21];
    const float* w_c1  = (const float*)d_in[22]; const float* bias1 = (const float*)d_in[23];
    const float* w_c2  = (const float*)d_in[24]; const float* bias2 = (const float*)d_in[25];
    const int*   segmap = (const int*)d_in[26];

    float* ws = (float*)d_ws;
    float* out = (float*)d_out;
    float* stats = ws + OFF_STATS;

    hipMemsetAsync((void*)stats, 0, 16 * sizeof(float), stream);

    k_seg_avg<<<dim3(6, B), 256, 0, stream>>>(f_sem, segmap, ws);
    k_paint<<<dim3(B * P), 256, 0, stream>>>(segmap, ws);
    k_ln0_stats<<<dim3(64, B), 256, 0, stream>>>(x_main, stats);
    k_conv_sh<<<dim3(4, 48, B), 256, 0, stream>>>(w_sh0, b_sh0, w_sh1, b_sh1, w_sh2, b_sh2, ws);
    k_conv_gb_big<<<dim3(4, 192, B), 256, 0, stream>>>(
        ws + OFF_HSH, w_g0, b_g0, w_be0, b_be0, x_main, stats,
        1.f / (float)(CM * P), ws + OFF_OUT0);
    k_c1x1_a<<<dim3(16, 24, B), 256, 0, stream>>>(ws + OFF_OUT0, w_c0, ws + OFF_P6);
    k_c1x1_a_fin<<<dim3(B), 256, 0, stream>>>(ws + OFF_P6, bias0, ws + OFF_H1A, stats);
    k_conv_gb_small<<<dim3(16, 1, B), 256, 0, stream>>>(
        ws + OFF_HSH, 1, w_g1, b_g1, w_be1, b_be1, ws + OFF_H1A,
        stats + 2 * B, 1.f / (float)(8 * P), ws + OFF_OUT1, 8);
    k_c1x1_b<<<dim3(4, B), 256, 0, stream>>>(ws + OFF_OUT1, w_c1, bias1, ws + OFF_H2A, stats);
    k_conv_gb_small<<<dim3(16, 2, B), 256, 0, stream>>>(
        ws + OFF_HSH, 2, w_g2, b_g2, w_be2, b_be2, ws + OFF_H2A,
        stats + 4 * B, 1.f / (float)(16 * P), ws + OFF_OUT2, 16);
    k_final<<<dim3(4, B), 256, 0, stream>>>(ws + OFF_OUT2, w_c2, bias2, out);
}

// Round 6
// 635.171 us; speedup vs baseline: 1.8242x; 1.8242x over previous
//
#include <hip/hip_runtime.h>
#include <hip/hip_bf16.h>

#define DEV __device__ __forceinline__

constexpr int B = 2;
constexpr int CM = 1536;
constexpr int CS = 384;
constexpr int HP = 32, WP = 32, P = 1024;
constexpr int HI = 448, WI = 448;
constexpr int HM = 128;
constexpr int NSEG = 64;

// ws layout (floats)
constexpr size_t OFF_AVG  = 0;                          // B*64*384      = 49152
constexpr size_t OFF_SEM  = 49152;                      // B*384*1024    = 786432
constexpr size_t OFF_HSH  = 835584;                     // bf16 B*384*1024 (uses half the region)
constexpr size_t OFF_OUT0 = 1622016;                    // B*1536*1024   = 3145728
constexpr size_t OFF_P6   = 4767744;                    // B*24*8*1024   = 393216
constexpr size_t OFF_H1A  = 5160960;                    // B*8*1024      = 16384
constexpr size_t OFF_OUT1 = 5177344;                    // 16384
constexpr size_t OFF_H2A  = 5193728;                    // B*16*1024     = 32768
constexpr size_t OFF_OUT2 = 5226496;                    // 32768
constexpr size_t OFF_STATS= 5259264;                    // 16 floats

typedef __attribute__((ext_vector_type(8))) short s16x8;
typedef __attribute__((ext_vector_type(4))) float f32x4;

DEV float softplus_f(float x) {
    return fmaxf(x, 0.f) + log1pf(expf(-fabsf(x)));
}
DEV ushort f2bf(float f) {                 // round-to-nearest-even bf16
    union { float f; unsigned u; } x; x.f = f;
    unsigned r = x.u + 0x7fffu + ((x.u >> 16) & 1u);
    return (ushort)(r >> 16);
}
DEV float bf2f(ushort u) {
    union { unsigned u; float f; } x; x.u = ((unsigned)u) << 16;
    return x.f;
}

// -------------------- 1. segment averages over 14-strided 32x32 samples -----
__global__ __launch_bounds__(256) void k_seg_avg(const float* __restrict__ f_sem,
                                                 const int* __restrict__ segmap,
                                                 float* __restrict__ ws) {
    int b = blockIdx.y, cc = blockIdx.x;
    __shared__ float sums[NSEG][64];
    __shared__ float cnt[NSEG];
    __shared__ int   segs[P];
    int t = threadIdx.x;
    for (int i = t; i < NSEG * 64; i += 256) sums[i / 64][i % 64] = 0.f;
    if (t < NSEG) cnt[t] = 0.f;
    __syncthreads();
    for (int p = t; p < P; p += 256) {
        int i = p >> 5, j = p & 31;
        int s = segmap[(b * HI + i * 14) * WI + j * 14];
        s = min(max(s, 0), NSEG - 1);
        segs[p] = s;
        atomicAdd(&cnt[s], 1.f);
    }
    __syncthreads();
    int c = cc * 64 + (t & 63);
    int g = t >> 6;
    const float* fp = f_sem + ((size_t)b * CS + c) * P;
    for (int p = g; p < P; p += 4) {
        atomicAdd(&sums[segs[p]][t & 63], fp[p]);
    }
    __syncthreads();
    for (int i = t; i < NSEG * 64; i += 256) {
        int s = i / 64, cl = i % 64;
        float cv = cnt[s];
        ws[OFF_AVG + ((size_t)(b * NSEG + s)) * CS + cc * 64 + cl] =
            cv > 0.f ? sums[s][cl] / cv : 0.f;
    }
}

// -------------------- 2. fused paint + antialiased bilinear downsample ------
__global__ __launch_bounds__(256) void k_paint(const int* __restrict__ segmap,
                                               float* __restrict__ ws) {
    int pixb = blockIdx.x;
    int b = pixb >> 10, op = pixb & 1023;
    int oy = op >> 5, ox = op & 31;
    __shared__ float Wb[NSEG];
    __shared__ float normv;
    int t = threadIdx.x;
    if (t < NSEG) Wb[t] = 0.f;
    __syncthreads();
    float cy = 14.f * oy + 6.5f, cx = 14.f * ox + 6.5f;
    int y0 = 14 * oy - 7, x0 = 14 * ox - 7;
    for (int k = t; k < 28 * 28; k += 256) {
        int jy = y0 + k / 28, jx = x0 + k % 28;
        if (jy < 0 || jy >= HI || jx < 0 || jx >= WI) continue;
        float wy = 1.f - fabsf(cy - (float)jy) * (1.f / 14.f);
        float wx = 1.f - fabsf(cx - (float)jx) * (1.f / 14.f);
        int s = segmap[(b * HI + jy) * WI + jx];
        s = min(max(s, 0), NSEG - 1);
        atomicAdd(&Wb[s], wy * wx);
    }
    if (t == 0) {
        float sy = 0.f, sx = 0.f;
        for (int d = 0; d < 28; d++) {
            int jy = y0 + d;
            if (jy >= 0 && jy < HI) sy += 1.f - fabsf(cy - (float)jy) * (1.f / 14.f);
            int jx = x0 + d;
            if (jx >= 0 && jx < WI) sx += 1.f - fabsf(cx - (float)jx) * (1.f / 14.f);
        }
        normv = 1.f / (sy * sx);
    }
    __syncthreads();
    float nv = normv;
    for (int c = t; c < CS; c += 256) {
        float acc = 0.f;
        const float* ap = ws + OFF_AVG + ((size_t)b * NSEG) * CS + c;
        #pragma unroll
        for (int s = 0; s < NSEG; s++) acc += Wb[s] * ap[(size_t)s * CS];
        ws[OFF_SEM + ((size_t)b * CS + c) * P + op] = acc * nv;
    }
}

// -------------------- 3. LN0 stats over x_main --------------------
__global__ __launch_bounds__(256) void k_ln0_stats(const float* __restrict__ x,
                                                   float* __restrict__ stats) {
    int b = blockIdx.y;
    const float4* xp = (const float4*)(x + (size_t)b * CM * P);
    int n4 = CM * P / 4;
    float s = 0.f, q = 0.f;
    for (int i = blockIdx.x * 256 + threadIdx.x; i < n4; i += 64 * 256) {
        float4 v = xp[i];
        s += v.x + v.y + v.z + v.w;
        q += v.x * v.x + v.y * v.y + v.z * v.z + v.w * v.w;
    }
    for (int o = 32; o > 0; o >>= 1) { s += __shfl_down(s, o); q += __shfl_down(q, o); }
    __shared__ float ls[4], lq[4];
    int w = threadIdx.x >> 6;
    if ((threadIdx.x & 63) == 0) { ls[w] = s; lq[w] = q; }
    __syncthreads();
    if (threadIdx.x == 0) {
        atomicAdd(&stats[b * 2],     ls[0] + ls[1] + ls[2] + ls[3]);
        atomicAdd(&stats[b * 2 + 1], lq[0] + lq[1] + lq[2] + lq[3]);
    }
}

// -------------------- MFMA 3x3 conv as 9 shifted GEMMs ----------------------
// MODE 0 (SH): in f32 sem, Cin=384, 32 co of [w_sh0;w_sh1;w_sh2], bias+relu -> bf16 hsh
// MODE 1 (GB): in bf16 hsh(ch 0..127), Cin=128, 16 gamma-co + 16 beta-co of same cog,
//              epilogue LN-combine -> f32 out0
template<int MODE>
__global__ __launch_bounds__(256) void k_conv_mfma(
    const void* __restrict__ in_,
    const float* __restrict__ w0, const float* __restrict__ b0,
    const float* __restrict__ w1, const float* __restrict__ b1,
    const float* __restrict__ w2, const float* __restrict__ b2,
    const float* __restrict__ xsrc, const float* __restrict__ st, float Ninv,
    void* __restrict__ out_)
{
    constexpr int CIN = (MODE == 0) ? 384 : 128;
    int pt = blockIdx.x;            // 4 pixel tiles of 256 (8 rows)
    int ctile = blockIdx.y;         // SH: 12 x 32co ; GB: 96 x 16cog
    int b  = blockIdx.z;
    int t = threadIdx.x, l = t & 63, wv = t >> 6;
    int y0 = pt * 8;

    __shared__ __align__(16) ushort Wl[9][32][40];   // [tap][co-row][ci+pad]
    __shared__ __align__(16) ushort Xl[10][34][40];  // [row][col][ci+pad]

    f32x4 acc[2][4] = {};

    const float*  inF = (const float*)in_;
    const ushort* inH = (const ushort*)in_;

    for (int kc = 0; kc < CIN; kc += 32) {
        __syncthreads();
        // ---- stage X tile (transposed, bf16) ----
        for (int j = t; j < 1360; j += 256) {
            int cg = j / 340, slot = j % 340;
            int r = slot / 34, c = slot % 34;
            int gy = y0 - 1 + r, gx = c - 1;
            s16x8 v = {};
            if (gy >= 0 && gy < HP && gx >= 0 && gx < WP) {
                int pix = gy * WP + gx;
                #pragma unroll
                for (int i = 0; i < 8; ++i) {
                    int ch = kc + cg * 8 + i;
                    if constexpr (MODE == 0)
                        v[i] = (short)f2bf(inF[((size_t)b * 384 + ch) * P + pix]);
                    else
                        v[i] = (short)inH[((size_t)b * 384 + ch) * P + pix];
                }
            }
            *(s16x8*)&Xl[r][c][cg * 8] = v;
        }
        // ---- stage W tile (bf16) ----
        for (int j = t; j < 9216; j += 256) {
            int co2 = j / 288, rem = j % 288;
            int ci = rem / 9, tap = rem % 9;
            float wval;
            if constexpr (MODE == 0) {
                int coG = ctile * 32 + co2;
                int sel = coG >> 7, cow = coG & 127;
                const float* wp = sel == 0 ? w0 : (sel == 1 ? w1 : w2);
                wval = wp[((size_t)cow * CS + kc + ci) * 9 + tap];
            } else {
                int cog = ctile * 16 + (co2 & 15);
                const float* wp = (co2 < 16) ? w0 : w1;   // wg : wbe
                wval = wp[((size_t)cog * HM + kc + ci) * 9 + tap];
            }
            Wl[tap][co2][ci] = f2bf(wval);
        }
        __syncthreads();
        // ---- 9 shifted MFMA GEMMs ----
        #pragma unroll
        for (int tap = 0; tap < 9; ++tap) {
            int dy = tap / 3, dx = tap % 3;
            s16x8 a0 = *(const s16x8*)&Wl[tap][l & 15][(l >> 4) * 8];
            s16x8 a1 = *(const s16x8*)&Wl[tap][16 + (l & 15)][(l >> 4) * 8];
            #pragma unroll
            for (int nt = 0; nt < 4; ++nt) {
                int q = wv * 64 + nt * 16 + (l & 15);
                int ry = (q >> 5) + dy, rx = (q & 31) + dx;
                s16x8 bf = *(const s16x8*)&Xl[ry][rx][(l >> 4) * 8];
                acc[0][nt] = __builtin_amdgcn_mfma_f32_16x16x32_bf16(a0, bf, acc[0][nt], 0, 0, 0);
                acc[1][nt] = __builtin_amdgcn_mfma_f32_16x16x32_bf16(a1, bf, acc[1][nt], 0, 0, 0);
            }
        }
    }

    // ---- epilogue ----
    if constexpr (MODE == 0) {
        ushort* outH = (ushort*)out_;
        #pragma unroll
        for (int mt = 0; mt < 2; ++mt)
            #pragma unroll
            for (int nt = 0; nt < 4; ++nt)
                #pragma unroll
                for (int r = 0; r < 4; ++r) {
                    int co = ctile * 32 + mt * 16 + (l >> 4) * 4 + r;
                    int px = pt * 256 + wv * 64 + nt * 16 + (l & 15);
                    int sel = co >> 7, cow = co & 127;
                    const float* bp = sel == 0 ? b0 : (sel == 1 ? b1 : b2);
                    float v = acc[mt][nt][r] + bp[cow];
                    outH[((size_t)b * 384 + co) * P + px] = f2bf(fmaxf(v, 0.f));
                }
    } else {
        float* outF = (float*)out_;
        float mu = st[b * 2] * Ninv;
        float var = st[b * 2 + 1] * Ninv - mu * mu;
        float rs = rsqrtf(var + 1e-12f);
        #pragma unroll
        for (int nt = 0; nt < 4; ++nt)
            #pragma unroll
            for (int r = 0; r < 4; ++r) {
                int cog = ctile * 16 + (l >> 4) * 4 + r;
                int px = pt * 256 + wv * 64 + nt * 16 + (l & 15);
                float gam = acc[0][nt][r] + b0[cog];
                float bet = acc[1][nt][r] + b1[cog];
                float xv = xsrc[((size_t)b * CM + cog) * P + px];
                outF[((size_t)b * CM + cog) * P + px] = (xv - mu) * rs * (1.f + gam) + bet;
            }
    }
}

// -------------------- small gamma/beta conv (spade1/2) + LN combine ---------
DEV float in_atH(const ushort* p, int y, int x) {
    return (y >= 0 && y < HP && x >= 0 && x < WP) ? bf2f(p[y * WP + x]) : 0.f;
}

__global__ __launch_bounds__(256) void k_conv_gb_small(
    const ushort* __restrict__ hshBase, int stage,
    const float* __restrict__ wg, const float* __restrict__ bg,
    const float* __restrict__ wbe, const float* __restrict__ bbe,
    const float* __restrict__ xsrc, const float* __restrict__ st, float Ninv,
    float* __restrict__ outp, int NP) {
    int b = blockIdx.z, ct = blockIdx.y;
    int t = threadIdx.x, lp = t & 63, g = t >> 6;
    int p = blockIdx.x * 64 + lp;
    int y = p >> 5, x = p & 31;
    const ushort* in = hshBase + ((size_t)b * 384 + stage * 128) * P;
    float ag[8] = {}, ab[8] = {};
    for (int ci = g * 32; ci < g * 32 + 32; ci++) {
        const ushort* ip = in + (size_t)ci * P;
        float v0 = in_atH(ip, y - 1, x - 1), v1 = in_atH(ip, y - 1, x), v2 = in_atH(ip, y - 1, x + 1);
        float v3 = in_atH(ip, y,     x - 1), v4 = bf2f(ip[y * WP + x]), v5 = in_atH(ip, y,     x + 1);
        float v6 = in_atH(ip, y + 1, x - 1), v7 = in_atH(ip, y + 1, x), v8 = in_atH(ip, y + 1, x + 1);
        #pragma unroll
        for (int co = 0; co < 8; co++) {
            int cog = ct * 8 + co;
            const float* wp = wg + ((size_t)cog * HM + ci) * 9;
            ag[co] += wp[0]*v0 + wp[1]*v1 + wp[2]*v2 + wp[3]*v3 + wp[4]*v4
                    + wp[5]*v5 + wp[6]*v6 + wp[7]*v7 + wp[8]*v8;
            const float* wq = wbe + ((size_t)cog * HM + ci) * 9;
            ab[co] += wq[0]*v0 + wq[1]*v1 + wq[2]*v2 + wq[3]*v3 + wq[4]*v4
                    + wq[5]*v5 + wq[6]*v6 + wq[7]*v7 + wq[8]*v8;
        }
    }
    __shared__ float red[4][64][16];
    #pragma unroll
    for (int co = 0; co < 8; co++) {
        red[g][lp][co] = ag[co];
        red[g][lp][8 + co] = ab[co];
    }
    __syncthreads();
    float mu = st[b * 2] * Ninv;
    float var = st[b * 2 + 1] * Ninv - mu * mu;
    float rs = rsqrtf(var + 1e-12f);
    for (int idx = t; idx < 512; idx += 256) {
        int pp = idx >> 3, co = idx & 7;
        int cog = ct * 8 + co;
        float gam = red[0][pp][co] + red[1][pp][co] + red[2][pp][co] + red[3][pp][co] + bg[cog];
        float bet = red[0][pp][8+co] + red[1][pp][8+co] + red[2][pp][8+co] + red[3][pp][8+co] + bbe[cog];
        int pgl = blockIdx.x * 64 + pp;
        float xv = xsrc[((size_t)b * NP + cog) * P + pgl];
        float xn = (xv - mu) * rs;
        outp[((size_t)b * NP + cog) * P + pgl] = xn * (1.f + gam) + bet;
    }
}

// -------------------- 1x1 conv 1536->8, split-K partials --------------------
__global__ __launch_bounds__(256) void k_c1x1_a(const float* __restrict__ out0,
                                                const float* __restrict__ w,
                                                float* __restrict__ part) {
    int b = blockIdx.z, ks = blockIdx.y, pg = blockIdx.x;
    int t = threadIdx.x, lp = t & 63, g = t >> 6;
    int pix = pg * 64 + lp;
    float acc[8] = {};
    int ci0 = ks * 64 + g * 16;
    for (int i = 0; i < 16; i++) {
        int ci = ci0 + i;
        float v = out0[((size_t)b * CM + ci) * P + pix];
        #pragma unroll
        for (int o = 0; o < 8; o++) acc[o] += w[o * CM + ci] * v;
    }
    __shared__ float red[4][64][8];
    #pragma unroll
    for (int o = 0; o < 8; o++) red[g][lp][o] = acc[o];
    __syncthreads();
    for (int idx = t; idx < 512; idx += 256) {
        int pp = idx >> 3, o = idx & 7;
        float s = red[0][pp][o] + red[1][pp][o] + red[2][pp][o] + red[3][pp][o];
        part[(((size_t)b * 24 + ks) * 8 + o) * P + pg * 64 + pp] = s;
    }
}

__global__ __launch_bounds__(256) void k_c1x1_a_fin(const float* __restrict__ part,
                                                    const float* __restrict__ bias,
                                                    float* __restrict__ h1a,
                                                    float* __restrict__ stats) {
    int b = blockIdx.x, t = threadIdx.x;
    float s = 0.f, q = 0.f;
    for (int idx = t; idx < 8 * P; idx += 256) {
        int o = idx >> 10, pix = idx & 1023;
        float v = 0.f;
        for (int ks = 0; ks < 24; ks++) v += part[(((size_t)b * 24 + ks) * 8 + o) * P + pix];
        v += bias[o];
        v = softplus_f(v);
        h1a[((size_t)b * 8 + o) * P + pix] = v;
        s += v; q += v * v;
    }
    for (int o2 = 32; o2 > 0; o2 >>= 1) { s += __shfl_down(s, o2); q += __shfl_down(q, o2); }
    __shared__ float ls[4], lq[4];
    int w = t >> 6;
    if ((t & 63) == 0) { ls[w] = s; lq[w] = q; }
    __syncthreads();
    if (t == 0) {
        stats[(B + b) * 2]     = ls[0] + ls[1] + ls[2] + ls[3];
        stats[(B + b) * 2 + 1] = lq[0] + lq[1] + lq[2] + lq[3];
    }
}

// -------------------- 1x1 conv 8->16 + softplus + LN2 stats ----------------
__global__ __launch_bounds__(256) void k_c1x1_b(const float* __restrict__ out1,
                                                const float* __restrict__ w,
                                                const float* __restrict__ bias,
                                                float* __restrict__ h2a,
                                                float* __restrict__ stats) {
    int b = blockIdx.y, t = threadIdx.x;
    int pix = blockIdx.x * 256 + t;
    float vin[8];
    #pragma unroll
    for (int ci = 0; ci < 8; ci++) vin[ci] = out1[((size_t)b * 8 + ci) * P + pix];
    float s = 0.f, q = 0.f;
    #pragma unroll
    for (int o = 0; o < 16; o++) {
        float a = bias[o];
        #pragma unroll
        for (int ci = 0; ci < 8; ci++) a += w[o * 8 + ci] * vin[ci];
        a = softplus_f(a);
        h2a[((size_t)b * 16 + o) * P + pix] = a;
        s += a; q += a * a;
    }
    for (int o2 = 32; o2 > 0; o2 >>= 1) { s += __shfl_down(s, o2); q += __shfl_down(q, o2); }
    __shared__ float ls[4], lq[4];
    int w2 = t >> 6;
    if ((t & 63) == 0) { ls[w2] = s; lq[w2] = q; }
    __syncthreads();
    if (t == 0) {
        atomicAdd(&stats[(2 * B + b) * 2],     ls[0] + ls[1] + ls[2] + ls[3]);
        atomicAdd(&stats[(2 * B + b) * 2 + 1], lq[0] + lq[1] + lq[2] + lq[3]);
    }
}

// -------------------- final 1x1 conv 16->1 + softplus -> f32 ---------------
__global__ __launch_bounds__(256) void k_final(const float* __restrict__ out2,
                                               const float* __restrict__ w,
                                               const float* __restrict__ bias,
                                               float* __restrict__ out) {
    int b = blockIdx.y, t = threadIdx.x;
    int pix = blockIdx.x * 256 + t;
    float a = bias[0];
    #pragma unroll
    for (int ci = 0; ci < 16; ci++) a += w[ci] * out2[((size_t)b * 16 + ci) * P + pix];
    a = softplus_f(a);
    out[(size_t)b * P + pix] = a;
}

extern "C" void kernel_launch(void* const* d_in, const int* in_sizes, int n_in,
                              void* d_out, int out_size, void* d_ws, size_t ws_size,
                              hipStream_t stream) {
    const float* x_main = (const float*)d_in[0];
    const float* f_sem  = (const float*)d_in[1];
    const float* w_sh0 = (const float*)d_in[2];  const float* b_sh0 = (const float*)d_in[3];
    const float* w_g0  = (const float*)d_in[4];  const float* b_g0  = (const float*)d_in[5];
    const float* w_be0 = (const float*)d_in[6];  const float* b_be0 = (const float*)d_in[7];
    const float* w_sh1 = (const float*)d_in[8];  const float* b_sh1 = (const float*)d_in[9];
    const float* w_g1  = (const float*)d_in[10]; const float* b_g1  = (const float*)d_in[11];
    const float* w_be1 = (const float*)d_in[12]; const float* b_be1 = (const float*)d_in[13];
    const float* w_sh2 = (const float*)d_in[14]; const float* b_sh2 = (const float*)d_in[15];
    const float* w_g2  = (const float*)d_in[16]; const float* b_g2  = (const float*)d_in[17];
    const float* w_be2 = (const float*)d_in[18]; const float* b_be2 = (const float*)d_in[19];
    const float* w_c0  = (const float*)d_in[20]; const float* bias0 = (const float*)d_in[21];
    const float* w_c1  = (const float*)d_in[22]; const float* bias1 = (const float*)d_in[23];
    const float* w_c2  = (const float*)d_in[24]; const float* bias2 = (const float*)d_in[25];
    const int*   segmap = (const int*)d_in[26];

    float* ws = (float*)d_ws;
    float* out = (float*)d_out;
    float* stats = ws + OFF_STATS;
    ushort* hshU = (ushort*)(ws + OFF_HSH);

    hipMemsetAsync((void*)stats, 0, 16 * sizeof(float), stream);

    k_seg_avg<<<dim3(6, B), 256, 0, stream>>>(f_sem, segmap, ws);
    k_paint<<<dim3(B * P), 256, 0, stream>>>(segmap, ws);
    k_ln0_stats<<<dim3(64, B), 256, 0, stream>>>(x_main, stats);
    // shared conv (3 stages fused): sem -> relu -> bf16 hsh
    k_conv_mfma<0><<<dim3(4, 12, B), 256, 0, stream>>>(
        (const void*)(ws + OFF_SEM),
        w_sh0, b_sh0, w_sh1, b_sh1, w_sh2, b_sh2,
        nullptr, nullptr, 0.f, (void*)hshU);
    // big gamma/beta conv + LN0 combine -> out0
    k_conv_mfma<1><<<dim3(4, 96, B), 256, 0, stream>>>(
        (const void*)hshU,
        w_g0, b_g0, w_be0, b_be0, nullptr, nullptr,
        x_main, stats, 1.f / (float)(CM * P), (void*)(ws + OFF_OUT0));
    k_c1x1_a<<<dim3(16, 24, B), 256, 0, stream>>>(ws + OFF_OUT0, w_c0, ws + OFF_P6);
    k_c1x1_a_fin<<<dim3(B), 256, 0, stream>>>(ws + OFF_P6, bias0, ws + OFF_H1A, stats);
    k_conv_gb_small<<<dim3(16, 1, B), 256, 0, stream>>>(
        hshU, 1, w_g1, b_g1, w_be1, b_be1, ws + OFF_H1A,
        stats + 2 * B, 1.f / (float)(8 * P), ws + OFF_OUT1, 8);
    k_c1x1_b<<<dim3(4, B), 256, 0, stream>>>(ws + OFF_OUT1, w_c1, bias1, ws + OFF_H2A, stats);
    k_conv_gb_small<<<dim3(16, 2, B), 256, 0, stream>>>(
        hshU, 2, w_g2, b_g2, w_be2, b_be2, ws + OFF_H2A,
        stats + 4 * B, 1.f / (float)(16 * P), ws + OFF_OUT2, 16);
    k_final<<<dim3(4, B), 256, 0, stream>>>(ws + OFF_OUT2, w_c2, bias2, out);
}

// Round 7
// 457.229 us; speedup vs baseline: 2.5341x; 1.3892x over previous
//
#include <hip/hip_runtime.h>
#include <hip/hip_bf16.h>

#define DEV __device__ __forceinline__

constexpr int B = 2;
constexpr int CM = 1536;
constexpr int CS = 384;
constexpr int HP = 32, WP = 32, P = 1024;
constexpr int HI = 448, WI = 448;
constexpr int HM = 128;
constexpr int NSEG = 64;

// ws layout (float units)
constexpr size_t OFF_AVG  = 0;          // B*64*384
constexpr size_t OFF_SEMT = 49152;      // f32 semT[B][1024][384]
constexpr size_t OFF_HSHT = 835584;     // ushort hshT[B][1024][384] (uses half region)
constexpr size_t OFF_OUT0 = 1622016;    // f32 [B][1536][1024]
constexpr size_t OFF_P6   = 4767744;    // f32 [B][24][8][1024]
constexpr size_t OFF_H1A  = 5160960;
constexpr size_t OFF_OUT1 = 5177344;
constexpr size_t OFF_H2A  = 5193728;
constexpr size_t OFF_OUT2 = 5226496;
constexpr size_t OFF_STATS= 5259264;    // 16 floats
constexpr size_t OFF_PACK = 5259280;    // bf16 packed weights (2469888 floats)

// packed-weight element offsets (ushort units)
constexpr size_t PK0 = 0;           // [12ct][12kc][9tap][32co][32ci]
constexpr size_t PK1 = 1327104;     // [96ct][4kc][9tap][32co][32ci]
constexpr size_t PK2 = 4866048;     // [4kc][9tap][32co][32ci] (rows 8-15,24-31 zero)
constexpr size_t PK3 = 4902912;     // [4kc][9tap][32co][32ci]
constexpr int    PK_CHUNKS = 617472; // total/8

typedef __attribute__((ext_vector_type(8))) short s16x8;
typedef __attribute__((ext_vector_type(4))) float f32x4;

DEV float softplus_f(float x) {
    return fmaxf(x, 0.f) + log1pf(expf(-fabsf(x)));
}
DEV ushort f2bf(float f) {
    union { float f; unsigned u; } x; x.f = f;
    unsigned r = x.u + 0x7fffu + ((x.u >> 16) & 1u);
    return (ushort)(r >> 16);
}

// -------------------- 1. segment averages --------------------
__global__ __launch_bounds__(256) void k_seg_avg(const float* __restrict__ f_sem,
                                                 const int* __restrict__ segmap,
                                                 float* __restrict__ ws) {
    int b = blockIdx.y, cc = blockIdx.x;
    __shared__ float sums[NSEG][64];
    __shared__ float cnt[NSEG];
    __shared__ int   segs[P];
    int t = threadIdx.x;
    for (int i = t; i < NSEG * 64; i += 256) sums[i / 64][i % 64] = 0.f;
    if (t < NSEG) cnt[t] = 0.f;
    __syncthreads();
    for (int p = t; p < P; p += 256) {
        int i = p >> 5, j = p & 31;
        int s = segmap[(b * HI + i * 14) * WI + j * 14];
        s = min(max(s, 0), NSEG - 1);
        segs[p] = s;
        atomicAdd(&cnt[s], 1.f);
    }
    __syncthreads();
    int c = cc * 64 + (t & 63);
    int g = t >> 6;
    const float* fp = f_sem + ((size_t)b * CS + c) * P;
    for (int p = g; p < P; p += 4) {
        atomicAdd(&sums[segs[p]][t & 63], fp[p]);
    }
    __syncthreads();
    for (int i = t; i < NSEG * 64; i += 256) {
        int s = i / 64, cl = i % 64;
        float cv = cnt[s];
        ws[OFF_AVG + ((size_t)(b * NSEG + s)) * CS + cc * 64 + cl] =
            cv > 0.f ? sums[s][cl] / cv : 0.f;
    }
}

// -------------------- 2. paint + bilinear -> semT[pix][ch] ------------------
__global__ __launch_bounds__(256) void k_paint(const int* __restrict__ segmap,
                                               float* __restrict__ ws) {
    int pixb = blockIdx.x;
    int b = pixb >> 10, op = pixb & 1023;
    int oy = op >> 5, ox = op & 31;
    __shared__ float Wb[NSEG];
    __shared__ float normv;
    int t = threadIdx.x;
    if (t < NSEG) Wb[t] = 0.f;
    __syncthreads();
    float cy = 14.f * oy + 6.5f, cx = 14.f * ox + 6.5f;
    int y0 = 14 * oy - 7, x0 = 14 * ox - 7;
    for (int k = t; k < 28 * 28; k += 256) {
        int jy = y0 + k / 28, jx = x0 + k % 28;
        if (jy < 0 || jy >= HI || jx < 0 || jx >= WI) continue;
        float wy = 1.f - fabsf(cy - (float)jy) * (1.f / 14.f);
        float wx = 1.f - fabsf(cx - (float)jx) * (1.f / 14.f);
        int s = segmap[(b * HI + jy) * WI + jx];
        s = min(max(s, 0), NSEG - 1);
        atomicAdd(&Wb[s], wy * wx);
    }
    if (t == 0) {
        float sy = 0.f, sx = 0.f;
        for (int d = 0; d < 28; d++) {
            int jy = y0 + d;
            if (jy >= 0 && jy < HI) sy += 1.f - fabsf(cy - (float)jy) * (1.f / 14.f);
            int jx = x0 + d;
            if (jx >= 0 && jx < WI) sx += 1.f - fabsf(cx - (float)jx) * (1.f / 14.f);
        }
        normv = 1.f / (sy * sx);
    }
    __syncthreads();
    float nv = normv;
    for (int c = t; c < CS; c += 256) {
        float acc = 0.f;
        const float* ap = ws + OFF_AVG + ((size_t)b * NSEG) * CS + c;
        #pragma unroll
        for (int s = 0; s < NSEG; s++) acc += Wb[s] * ap[(size_t)s * CS];
        ws[OFF_SEMT + ((size_t)b * P + op) * CS + c] = acc * nv;   // transposed
    }
}

// -------------------- 3. LN0 stats --------------------
__global__ __launch_bounds__(256) void k_ln0_stats(const float* __restrict__ x,
                                                   float* __restrict__ stats) {
    int b = blockIdx.y;
    const float4* xp = (const float4*)(x + (size_t)b * CM * P);
    int n4 = CM * P / 4;
    float s = 0.f, q = 0.f;
    for (int i = blockIdx.x * 256 + threadIdx.x; i < n4; i += 64 * 256) {
        float4 v = xp[i];
        s += v.x + v.y + v.z + v.w;
        q += v.x * v.x + v.y * v.y + v.z * v.z + v.w * v.w;
    }
    for (int o = 32; o > 0; o >>= 1) { s += __shfl_down(s, o); q += __shfl_down(q, o); }
    __shared__ float ls[4], lq[4];
    int w = threadIdx.x >> 6;
    if ((threadIdx.x & 63) == 0) { ls[w] = s; lq[w] = q; }
    __syncthreads();
    if (threadIdx.x == 0) {
        atomicAdd(&stats[b * 2],     ls[0] + ls[1] + ls[2] + ls[3]);
        atomicAdd(&stats[b * 2 + 1], lq[0] + lq[1] + lq[2] + lq[3]);
    }
}

// -------------------- 4. weight pre-pack to bf16, LDS tile order ------------
__global__ __launch_bounds__(256) void k_wpack(
    const float* __restrict__ w_sh0, const float* __restrict__ w_sh1, const float* __restrict__ w_sh2,
    const float* __restrict__ w_g0,  const float* __restrict__ w_be0,
    const float* __restrict__ w_g1,  const float* __restrict__ w_be1,
    const float* __restrict__ w_g2,  const float* __restrict__ w_be2,
    ushort* __restrict__ packU)
{
    for (int c8 = blockIdx.x * 256 + threadIdx.x; c8 < PK_CHUNKS; c8 += gridDim.x * 256) {
        size_t e = (size_t)c8 * 8;
        float vals[8];
        const float* s0 = nullptr;
        bool zero = false;
        if (e < PK1) {                         // mode0
            size_t r = e;
            int ci0 = (int)(r & 31), co2 = (int)((r >> 5) & 31);
            int tap = (int)((r >> 10) % 9);
            int kct = (int)((r / 9216) % 12), ct = (int)(r / 110592);
            int coG = ct * 32 + co2, sel = coG >> 7, cow = coG & 127;
            const float* wp = sel == 0 ? w_sh0 : (sel == 1 ? w_sh1 : w_sh2);
            s0 = &wp[((size_t)cow * CS + kct * 32 + ci0) * 9 + tap];
        } else if (e < PK2) {                  // mode1
            size_t r = e - PK1;
            int ci0 = (int)(r & 31), co2 = (int)((r >> 5) & 31);
            int tap = (int)((r >> 10) % 9);
            int kct = (int)((r / 9216) % 4), ct = (int)(r / 36864);
            int cog = ct * 16 + (co2 & 15);
            const float* wp = co2 < 16 ? w_g0 : w_be0;
            s0 = &wp[((size_t)cog * HM + kct * 32 + ci0) * 9 + tap];
        } else if (e < PK3) {                  // mode2 (8 gamma + 8 beta, padded)
            size_t r = e - PK2;
            int ci0 = (int)(r & 31), co2 = (int)((r >> 5) & 31);
            int tap = (int)((r >> 10) % 9);
            int kct = (int)(r / 9216);
            zero = ((co2 & 15) >= 8);
            int cog = co2 & 7;
            const float* wp = co2 < 16 ? w_g1 : w_be1;
            if (!zero) s0 = &wp[((size_t)cog * HM + kct * 32 + ci0) * 9 + tap];
        } else {                               // mode3 (16 gamma + 16 beta)
            size_t r = e - PK3;
            int ci0 = (int)(r & 31), co2 = (int)((r >> 5) & 31);
            int tap = (int)((r >> 10) % 9);
            int kct = (int)(r / 9216);
            int cog = co2 & 15;
            const float* wp = co2 < 16 ? w_g2 : w_be2;
            s0 = &wp[((size_t)cog * HM + kct * 32 + ci0) * 9 + tap];
        }
        s16x8 o;
        #pragma unroll
        for (int i = 0; i < 8; ++i) {
            float v = zero ? 0.f : s0[(size_t)i * 9];
            o[i] = (short)f2bf(v);
        }
        *(s16x8*)&packU[e] = o;
    }
}

// -------------------- 5. MFMA 3x3 conv (9 shifted GEMMs) --------------------
// MODE0: semT f32 Cin=384 -> relu -> hshT bf16 [pix][384]
// MODE1: hshT ch0..127  -> 16g+16b, LN0 -> out0 f32 [1536][1024]
// MODE2: hshT ch128..255 -> 8g+8b (padded tile), LN1 -> out1 f32 [8][1024]
// MODE3: hshT ch256..383 -> 16g+16b, LN2 -> out2 f32 [16][1024]
template<int MODE>
__global__ __launch_bounds__(256) void k_conv_mfma(
    const float* __restrict__ semT, const ushort* __restrict__ hshTin,
    const ushort* __restrict__ packW,
    const float* __restrict__ bb0, const float* __restrict__ bb1, const float* __restrict__ bb2,
    const float* __restrict__ xsrc, const float* __restrict__ st, float Ninv,
    float* __restrict__ outF, ushort* __restrict__ outH)
{
    constexpr int CIN = (MODE == 0) ? 384 : 128;
    constexpr int KT  = CIN / 32;
    constexpr int CBASE = (MODE == 2) ? 128 : (MODE == 3) ? 256 : 0;
    constexpr int NP = (MODE == 1) ? 1536 : (MODE == 2) ? 8 : 16;

    int pt = blockIdx.x, ctile = blockIdx.y, b = blockIdx.z;
    int t = threadIdx.x, l = t & 63, wv = t >> 6;
    int y0 = pt * 8;

    __shared__ __align__(16) ushort Wl[9][32][40];
    __shared__ __align__(16) ushort Xl[10][34][40];

    f32x4 acc[2][4] = {};

    for (int kc = 0; kc < CIN; kc += 32) {
        __syncthreads();
        // ---- X stage: contiguous vector loads from [pix][ch] layout ----
        for (int j = t; j < 1360; j += 256) {
            int slot = j >> 2, part = j & 3;
            int r = slot / 34, c = slot % 34;
            int gy = y0 - 1 + r, gx = c - 1;
            s16x8 v = {};
            if (gy >= 0 && gy < HP && gx >= 0 && gx < WP) {
                int pix = gy * WP + gx;
                if constexpr (MODE == 0) {
                    const float4* sp = (const float4*)&semT[((size_t)b * P + pix) * CS + kc + part * 8];
                    float4 x0 = sp[0], x1 = sp[1];
                    v[0] = (short)f2bf(x0.x); v[1] = (short)f2bf(x0.y);
                    v[2] = (short)f2bf(x0.z); v[3] = (short)f2bf(x0.w);
                    v[4] = (short)f2bf(x1.x); v[5] = (short)f2bf(x1.y);
                    v[6] = (short)f2bf(x1.z); v[7] = (short)f2bf(x1.w);
                } else {
                    v = *(const s16x8*)&hshTin[((size_t)b * P + pix) * 384 + CBASE + kc + part * 8];
                }
            }
            *(s16x8*)&Xl[r][c][part * 8] = v;
        }
        // ---- W stage: straight vector copy from packed ----
        const ushort* wsrc = packW + (size_t)(ctile * KT + (kc >> 5)) * 9216;
        for (int j = t; j < 1152; j += 256) {
            int tap = j >> 7, co2 = (j >> 2) & 31, part = j & 3;
            *(s16x8*)&Wl[tap][co2][part * 8] = *(const s16x8*)&wsrc[(size_t)j * 8];
        }
        __syncthreads();
        // ---- 9 shifted MFMA GEMMs (validated core) ----
        #pragma unroll
        for (int tap = 0; tap < 9; ++tap) {
            int dy = tap / 3, dx = tap % 3;
            s16x8 a0 = *(const s16x8*)&Wl[tap][l & 15][(l >> 4) * 8];
            s16x8 a1 = *(const s16x8*)&Wl[tap][16 + (l & 15)][(l >> 4) * 8];
            #pragma unroll
            for (int nt = 0; nt < 4; ++nt) {
                int q = wv * 64 + nt * 16 + (l & 15);
                int ry = (q >> 5) + dy, rx = (q & 31) + dx;
                s16x8 bf = *(const s16x8*)&Xl[ry][rx][(l >> 4) * 8];
                acc[0][nt] = __builtin_amdgcn_mfma_f32_16x16x32_bf16(a0, bf, acc[0][nt], 0, 0, 0);
                acc[1][nt] = __builtin_amdgcn_mfma_f32_16x16x32_bf16(a1, bf, acc[1][nt], 0, 0, 0);
            }
        }
    }

    if constexpr (MODE == 0) {
        // bias+relu -> LDS transpose -> hshT[pix][ch] coalesced-ish rows
        __syncthreads();
        ushort (*T)[36] = (ushort(*)[36])(&Xl[0][0][0]);   // 256x36 fits in Xl
        #pragma unroll
        for (int mt = 0; mt < 2; ++mt)
            #pragma unroll
            for (int nt = 0; nt < 4; ++nt)
                #pragma unroll
                for (int r = 0; r < 4; ++r) {
                    int m = mt * 16 + (l >> 4) * 4 + r;
                    int pl = wv * 64 + nt * 16 + (l & 15);
                    int coG = ctile * 32 + m;
                    int sel = coG >> 7, cow = coG & 127;
                    const float* bp = sel == 0 ? bb0 : (sel == 1 ? bb1 : bb2);
                    T[pl][m] = f2bf(fmaxf(acc[mt][nt][r] + bp[cow], 0.f));
                }
        __syncthreads();
        ushort* dst = outH + ((size_t)b * P + pt * 256 + t) * 384 + ctile * 32;
        #pragma unroll
        for (int k = 0; k < 8; ++k) {
            uint2 v = *(const uint2*)&T[t][k * 4];
            *(uint2*)&dst[k * 4] = v;
        }
    } else {
        float mu = st[b * 2] * Ninv;
        float var = st[b * 2 + 1] * Ninv - mu * mu;
        float rs = rsqrtf(var + 1e-12f);
        #pragma unroll
        for (int nt = 0; nt < 4; ++nt)
            #pragma unroll
            for (int r = 0; r < 4; ++r) {
                int m = (l >> 4) * 4 + r;
                if (MODE == 2 && m >= 8) continue;
                int cog = (MODE == 1) ? ctile * 16 + m : m;
                int px = pt * 256 + wv * 64 + nt * 16 + (l & 15);
                float gam = acc[0][nt][r] + bb0[cog];
                float bet = acc[1][nt][r] + bb1[cog];
                float xv = xsrc[((size_t)b * NP + cog) * P + px];
                outF[((size_t)b * NP + cog) * P + px] = (xv - mu) * rs * (1.f + gam) + bet;
            }
    }
}

// -------------------- 1x1 conv 1536->8 split-K ------------------------------
__global__ __launch_bounds__(256) void k_c1x1_a(const float* __restrict__ out0,
                                                const float* __restrict__ w,
                                                float* __restrict__ part) {
    int b = blockIdx.z, ks = blockIdx.y, pg = blockIdx.x;
    int t = threadIdx.x, lp = t & 63, g = t >> 6;
    int pix = pg * 64 + lp;
    float acc[8] = {};
    int ci0 = ks * 64 + g * 16;
    for (int i = 0; i < 16; i++) {
        int ci = ci0 + i;
        float v = out0[((size_t)b * CM + ci) * P + pix];
        #pragma unroll
        for (int o = 0; o < 8; o++) acc[o] += w[o * CM + ci] * v;
    }
    __shared__ float red[4][64][8];
    #pragma unroll
    for (int o = 0; o < 8; o++) red[g][lp][o] = acc[o];
    __syncthreads();
    for (int idx = t; idx < 512; idx += 256) {
        int pp = idx >> 3, o = idx & 7;
        float s = red[0][pp][o] + red[1][pp][o] + red[2][pp][o] + red[3][pp][o];
        part[(((size_t)b * 24 + ks) * 8 + o) * P + pg * 64 + pp] = s;
    }
}

__global__ __launch_bounds__(256) void k_c1x1_a_fin(const float* __restrict__ part,
                                                    const float* __restrict__ bias,
                                                    float* __restrict__ h1a,
                                                    float* __restrict__ stats) {
    int b = blockIdx.x, t = threadIdx.x;
    float s = 0.f, q = 0.f;
    for (int idx = t; idx < 8 * P; idx += 256) {
        int o = idx >> 10, pix = idx & 1023;
        float v = 0.f;
        for (int ks = 0; ks < 24; ks++) v += part[(((size_t)b * 24 + ks) * 8 + o) * P + pix];
        v += bias[o];
        v = softplus_f(v);
        h1a[((size_t)b * 8 + o) * P + pix] = v;
        s += v; q += v * v;
    }
    for (int o2 = 32; o2 > 0; o2 >>= 1) { s += __shfl_down(s, o2); q += __shfl_down(q, o2); }
    __shared__ float ls[4], lq[4];
    int w = t >> 6;
    if ((t & 63) == 0) { ls[w] = s; lq[w] = q; }
    __syncthreads();
    if (t == 0) {
        stats[(B + b) * 2]     = ls[0] + ls[1] + ls[2] + ls[3];
        stats[(B + b) * 2 + 1] = lq[0] + lq[1] + lq[2] + lq[3];
    }
}

// -------------------- 1x1 conv 8->16 + softplus + LN2 stats ----------------
__global__ __launch_bounds__(256) void k_c1x1_b(const float* __restrict__ out1,
                                                const float* __restrict__ w,
                                                const float* __restrict__ bias,
                                                float* __restrict__ h2a,
                                                float* __restrict__ stats) {
    int b = blockIdx.y, t = threadIdx.x;
    int pix = blockIdx.x * 256 + t;
    float vin[8];
    #pragma unroll
    for (int ci = 0; ci < 8; ci++) vin[ci] = out1[((size_t)b * 8 + ci) * P + pix];
    float s = 0.f, q = 0.f;
    #pragma unroll
    for (int o = 0; o < 16; o++) {
        float a = bias[o];
        #pragma unroll
        for (int ci = 0; ci < 8; ci++) a += w[o * 8 + ci] * vin[ci];
        a = softplus_f(a);
        h2a[((size_t)b * 16 + o) * P + pix] = a;
        s += a; q += a * a;
    }
    for (int o2 = 32; o2 > 0; o2 >>= 1) { s += __shfl_down(s, o2); q += __shfl_down(q, o2); }
    __shared__ float ls[4], lq[4];
    int w2 = t >> 6;
    if ((t & 63) == 0) { ls[w2] = s; lq[w2] = q; }
    __syncthreads();
    if (t == 0) {
        atomicAdd(&stats[(2 * B + b) * 2],     ls[0] + ls[1] + ls[2] + ls[3]);
        atomicAdd(&stats[(2 * B + b) * 2 + 1], lq[0] + lq[1] + lq[2] + lq[3]);
    }
}

// -------------------- final 1x1 conv 16->1 + softplus -> f32 ---------------
__global__ __launch_bounds__(256) void k_final(const float* __restrict__ out2,
                                               const float* __restrict__ w,
                                               const float* __restrict__ bias,
                                               float* __restrict__ out) {
    int b = blockIdx.y, t = threadIdx.x;
    int pix = blockIdx.x * 256 + t;
    float a = bias[0];
    #pragma unroll
    for (int ci = 0; ci < 16; ci++) a += w[ci] * out2[((size_t)b * 16 + ci) * P + pix];
    a = softplus_f(a);
    out[(size_t)b * P + pix] = a;
}

extern "C" void kernel_launch(void* const* d_in, const int* in_sizes, int n_in,
                              void* d_out, int out_size, void* d_ws, size_t ws_size,
                              hipStream_t stream) {
    const float* x_main = (const float*)d_in[0];
    const float* f_sem  = (const float*)d_in[1];
    const float* w_sh0 = (const float*)d_in[2];  const float* b_sh0 = (const float*)d_in[3];
    const float* w_g0  = (const float*)d_in[4];  const float* b_g0  = (const float*)d_in[5];
    const float* w_be0 = (const float*)d_in[6];  const float* b_be0 = (const float*)d_in[7];
    const float* w_sh1 = (const float*)d_in[8];  const float* b_sh1 = (const float*)d_in[9];
    const float* w_g1  = (const float*)d_in[10]; const float* b_g1  = (const float*)d_in[11];
    const float* w_be1 = (const float*)d_in[12]; const float* b_be1 = (const float*)d_in[13];
    const float* w_sh2 = (const float*)d_in[14]; const float* b_sh2 = (const float*)d_in[15];
    const float* w_g2  = (const float*)d_in[16]; const float* b_g2  = (const float*)d_in[17];
    const float* w_be2 = (const float*)d_in[18]; const float* b_be2 = (const float*)d_in[19];
    const float* w_c0  = (const float*)d_in[20]; const float* bias0 = (const float*)d_in[21];
    const float* w_c1  = (const float*)d_in[22]; const float* bias1 = (const float*)d_in[23];
    const float* w_c2  = (const float*)d_in[24]; const float* bias2 = (const float*)d_in[25];
    const int*   segmap = (const int*)d_in[26];

    float* ws = (float*)d_ws;
    float* out = (float*)d_out;
    float* stats = ws + OFF_STATS;
    ushort* hshU = (ushort*)(ws + OFF_HSHT);
    ushort* packU = (ushort*)(ws + OFF_PACK);

    hipMemsetAsync((void*)stats, 0, 16 * sizeof(float), stream);

    k_wpack<<<dim3(2412), 256, 0, stream>>>(w_sh0, w_sh1, w_sh2, w_g0, w_be0,
                                            w_g1, w_be1, w_g2, w_be2, packU);
    k_seg_avg<<<dim3(6, B), 256, 0, stream>>>(f_sem, segmap, ws);
    k_ln0_stats<<<dim3(64, B), 256, 0, stream>>>(x_main, stats);
    k_paint<<<dim3(B * P), 256, 0, stream>>>(segmap, ws);

    k_conv_mfma<0><<<dim3(4, 12, B), 256, 0, stream>>>(
        ws + OFF_SEMT, nullptr, packU + PK0,
        b_sh0, b_sh1, b_sh2, nullptr, nullptr, 0.f, nullptr, hshU);

    k_conv_mfma<1><<<dim3(4, 96, B), 256, 0, stream>>>(
        nullptr, hshU, packU + PK1,
        b_g0, b_be0, nullptr, x_main, stats, 1.f / (float)(CM * P),
        ws + OFF_OUT0, nullptr);

    k_c1x1_a<<<dim3(16, 24, B), 256, 0, stream>>>(ws + OFF_OUT0, w_c0, ws + OFF_P6);
    k_c1x1_a_fin<<<dim3(B), 256, 0, stream>>>(ws + OFF_P6, bias0, ws + OFF_H1A, stats);

    k_conv_mfma<2><<<dim3(4, 1, B), 256, 0, stream>>>(
        nullptr, hshU, packU + PK2,
        b_g1, b_be1, nullptr, ws + OFF_H1A, stats + 2 * B, 1.f / (float)(8 * P),
        ws + OFF_OUT1, nullptr);

    k_c1x1_b<<<dim3(4, B), 256, 0, stream>>>(ws + OFF_OUT1, w_c1, bias1, ws + OFF_H2A, stats);

    k_conv_mfma<3><<<dim3(4, 1, B), 256, 0, stream>>>(
        nullptr, hshU, packU + PK3,
        b_g2, b_be2, nullptr, ws + OFF_H2A, stats + 4 * B, 1.f / (float)(16 * P),
        ws + OFF_OUT2, nullptr);

    k_final<<<dim3(4, B), 256, 0, stream>>>(ws + OFF_OUT2, w_c2, bias2, out);
}

// Round 8
// 359.925 us; speedup vs baseline: 3.2192x; 1.2703x over previous
//
#include <hip/hip_runtime.h>
#include <hip/hip_bf16.h>

#define DEV __device__ __forceinline__

constexpr int B = 2;
constexpr int CM = 1536;
constexpr int CS = 384;
constexpr int HP = 32, WP = 32, P = 1024;
constexpr int HI = 448, WI = 448;
constexpr int HM = 128;
constexpr int NSEG = 64;

// ws layout (float units)
constexpr size_t OFF_AVG  = 0;          // B*64*384
constexpr size_t OFF_SEMT = 49152;      // f32 semT[B][1024][384]
constexpr size_t OFF_HSHT = 835584;     // ushort hshT[B][1024][384] (uses half region)
constexpr size_t OFF_OUT0 = 1622016;    // f32 [B][1536][1024]
constexpr size_t OFF_P6   = 4767744;    // f32 [B][24][8][1024]
constexpr size_t OFF_H1A  = 5160960;
constexpr size_t OFF_OUT1 = 5177344;
constexpr size_t OFF_H2A  = 5193728;
constexpr size_t OFF_OUT2 = 5226496;
constexpr size_t OFF_STATS= 5259264;    // 16 floats
constexpr size_t OFF_PACK = 5259280;    // bf16 packed weights (2469888 floats)

// packed-weight element offsets (ushort units)
constexpr size_t PK0 = 0;           // [12ct][12kc][9tap][32co][32ci]
constexpr size_t PK1 = 1327104;     // [96ct][4kc][9tap][32co][32ci]
constexpr size_t PK2 = 4866048;     // [4kc][9tap][32co][32ci] (rows 8-15,24-31 zero)
constexpr size_t PK3 = 4902912;     // [4kc][9tap][32co][32ci]
constexpr int    PK_CHUNKS = 617472; // total/8

typedef __attribute__((ext_vector_type(8))) short s16x8;
typedef __attribute__((ext_vector_type(4))) float f32x4;

DEV float softplus_f(float x) {
    return fmaxf(x, 0.f) + log1pf(expf(-fabsf(x)));
}
DEV ushort f2bf(float f) {
    union { float f; unsigned u; } x; x.f = f;
    unsigned r = x.u + 0x7fffu + ((x.u >> 16) & 1u);
    return (ushort)(r >> 16);
}

// -------------------- 1. segment averages (coalesced, 96 blocks) ------------
__global__ __launch_bounds__(256) void k_seg_avg(const float* __restrict__ f_sem,
                                                 const int* __restrict__ segmap,
                                                 float* __restrict__ ws) {
    int b = blockIdx.y;
    int c0 = blockIdx.x * 8;              // 48 x 8 channels
    __shared__ int   segs[P];
    __shared__ float sums[NSEG][9];       // +1 pad: spread banks
    __shared__ float cnt[NSEG];
    int t = threadIdx.x;
    for (int i = t; i < NSEG * 9; i += 256) (&sums[0][0])[i] = 0.f;
    if (t < NSEG) cnt[t] = 0.f;
    __syncthreads();
    for (int p = t; p < P; p += 256) {
        int i = p >> 5, j = p & 31;
        int s = segmap[(b * HI + i * 14) * WI + j * 14];
        s = min(max(s, 0), NSEG - 1);
        segs[p] = s;
        atomicAdd(&cnt[s], 1.f);
    }
    __syncthreads();
    #pragma unroll
    for (int ch = 0; ch < 8; ++ch) {
        const float* fp = f_sem + ((size_t)b * CS + c0 + ch) * P;
        #pragma unroll
        for (int pb = 0; pb < 4; ++pb) {
            int p = pb * 256 + t;
            float v = fp[p];              // coalesced: lanes sweep p
            atomicAdd(&sums[segs[p]][ch], v);
        }
    }
    __syncthreads();
    for (int i = t; i < NSEG * 8; i += 256) {
        int s = i >> 3, ch = i & 7;
        float cv = cnt[s];
        ws[OFF_AVG + ((size_t)(b * NSEG + s)) * CS + c0 + ch] =
            cv > 0.f ? sums[s][ch] / cv : 0.f;
    }
}

// -------------------- 2. paint + bilinear -> semT[pix][ch] ------------------
__global__ __launch_bounds__(256) void k_paint(const int* __restrict__ segmap,
                                               float* __restrict__ ws) {
    int pixb = blockIdx.x;
    int b = pixb >> 10, op = pixb & 1023;
    int oy = op >> 5, ox = op & 31;
    __shared__ float Wb[NSEG];
    __shared__ float normv;
    int t = threadIdx.x;
    if (t < NSEG) Wb[t] = 0.f;
    __syncthreads();
    float cy = 14.f * oy + 6.5f, cx = 14.f * ox + 6.5f;
    int y0 = 14 * oy - 7, x0 = 14 * ox - 7;
    for (int k = t; k < 28 * 28; k += 256) {
        int jy = y0 + k / 28, jx = x0 + k % 28;
        if (jy < 0 || jy >= HI || jx < 0 || jx >= WI) continue;
        float wy = 1.f - fabsf(cy - (float)jy) * (1.f / 14.f);
        float wx = 1.f - fabsf(cx - (float)jx) * (1.f / 14.f);
        int s = segmap[(b * HI + jy) * WI + jx];
        s = min(max(s, 0), NSEG - 1);
        atomicAdd(&Wb[s], wy * wx);
    }
    if (t == 0) {
        float sy = 0.f, sx = 0.f;
        for (int d = 0; d < 28; d++) {
            int jy = y0 + d;
            if (jy >= 0 && jy < HI) sy += 1.f - fabsf(cy - (float)jy) * (1.f / 14.f);
            int jx = x0 + d;
            if (jx >= 0 && jx < WI) sx += 1.f - fabsf(cx - (float)jx) * (1.f / 14.f);
        }
        normv = 1.f / (sy * sx);
    }
    __syncthreads();
    float nv = normv;
    for (int c = t; c < CS; c += 256) {
        float acc = 0.f;
        const float* ap = ws + OFF_AVG + ((size_t)b * NSEG) * CS + c;
        #pragma unroll
        for (int s = 0; s < NSEG; s++) acc += Wb[s] * ap[(size_t)s * CS];
        ws[OFF_SEMT + ((size_t)b * P + op) * CS + c] = acc * nv;   // transposed
    }
}

// -------------------- 3. LN0 stats --------------------
__global__ __launch_bounds__(256) void k_ln0_stats(const float* __restrict__ x,
                                                   float* __restrict__ stats) {
    int b = blockIdx.y;
    const float4* xp = (const float4*)(x + (size_t)b * CM * P);
    int n4 = CM * P / 4;
    float s = 0.f, q = 0.f;
    for (int i = blockIdx.x * 256 + threadIdx.x; i < n4; i += 64 * 256) {
        float4 v = xp[i];
        s += v.x + v.y + v.z + v.w;
        q += v.x * v.x + v.y * v.y + v.z * v.z + v.w * v.w;
    }
    for (int o = 32; o > 0; o >>= 1) { s += __shfl_down(s, o); q += __shfl_down(q, o); }
    __shared__ float ls[4], lq[4];
    int w = threadIdx.x >> 6;
    if ((threadIdx.x & 63) == 0) { ls[w] = s; lq[w] = q; }
    __syncthreads();
    if (threadIdx.x == 0) {
        atomicAdd(&stats[b * 2],     ls[0] + ls[1] + ls[2] + ls[3]);
        atomicAdd(&stats[b * 2 + 1], lq[0] + lq[1] + lq[2] + lq[3]);
    }
}

// -------------------- 4. weight pre-pack to bf16, LDS tile order ------------
__global__ __launch_bounds__(256) void k_wpack(
    const float* __restrict__ w_sh0, const float* __restrict__ w_sh1, const float* __restrict__ w_sh2,
    const float* __restrict__ w_g0,  const float* __restrict__ w_be0,
    const float* __restrict__ w_g1,  const float* __restrict__ w_be1,
    const float* __restrict__ w_g2,  const float* __restrict__ w_be2,
    ushort* __restrict__ packU)
{
    for (int c8 = blockIdx.x * 256 + threadIdx.x; c8 < PK_CHUNKS; c8 += gridDim.x * 256) {
        size_t e = (size_t)c8 * 8;
        const float* s0 = nullptr;
        bool zero = false;
        if (e < PK1) {                         // mode0
            size_t r = e;
            int ci0 = (int)(r & 31), co2 = (int)((r >> 5) & 31);
            int tap = (int)((r >> 10) % 9);
            int kct = (int)((r / 9216) % 12), ct = (int)(r / 110592);
            int coG = ct * 32 + co2, sel = coG >> 7, cow = coG & 127;
            const float* wp = sel == 0 ? w_sh0 : (sel == 1 ? w_sh1 : w_sh2);
            s0 = &wp[((size_t)cow * CS + kct * 32 + ci0) * 9 + tap];
        } else if (e < PK2) {                  // mode1
            size_t r = e - PK1;
            int ci0 = (int)(r & 31), co2 = (int)((r >> 5) & 31);
            int tap = (int)((r >> 10) % 9);
            int kct = (int)((r / 9216) % 4), ct = (int)(r / 36864);
            int cog = ct * 16 + (co2 & 15);
            const float* wp = co2 < 16 ? w_g0 : w_be0;
            s0 = &wp[((size_t)cog * HM + kct * 32 + ci0) * 9 + tap];
        } else if (e < PK3) {                  // mode2 (8 gamma + 8 beta, padded)
            size_t r = e - PK2;
            int ci0 = (int)(r & 31), co2 = (int)((r >> 5) & 31);
            int tap = (int)((r >> 10) % 9);
            int kct = (int)(r / 9216);
            zero = ((co2 & 15) >= 8);
            int cog = co2 & 7;
            const float* wp = co2 < 16 ? w_g1 : w_be1;
            if (!zero) s0 = &wp[((size_t)cog * HM + kct * 32 + ci0) * 9 + tap];
        } else {                               // mode3 (16 gamma + 16 beta)
            size_t r = e - PK3;
            int ci0 = (int)(r & 31), co2 = (int)((r >> 5) & 31);
            int tap = (int)((r >> 10) % 9);
            int kct = (int)(r / 9216);
            int cog = co2 & 15;
            const float* wp = co2 < 16 ? w_g2 : w_be2;
            s0 = &wp[((size_t)cog * HM + kct * 32 + ci0) * 9 + tap];
        }
        s16x8 o;
        #pragma unroll
        for (int i = 0; i < 8; ++i) {
            float v = zero ? 0.f : s0[(size_t)i * 9];
            o[i] = (short)f2bf(v);
        }
        *(s16x8*)&packU[e] = o;
    }
}

// -------------------- 5. MFMA 3x3 conv (9 shifted GEMMs) --------------------
template<int MODE>
__global__ __launch_bounds__(256) void k_conv_mfma(
    const float* __restrict__ semT, const ushort* __restrict__ hshTin,
    const ushort* __restrict__ packW,
    const float* __restrict__ bb0, const float* __restrict__ bb1, const float* __restrict__ bb2,
    const float* __restrict__ xsrc, const float* __restrict__ st, float Ninv,
    float* __restrict__ outF, ushort* __restrict__ outH)
{
    constexpr int CIN = (MODE == 0) ? 384 : 128;
    constexpr int KT  = CIN / 32;
    constexpr int CBASE = (MODE == 2) ? 128 : (MODE == 3) ? 256 : 0;
    constexpr int NP = (MODE == 1) ? 1536 : (MODE == 2) ? 8 : 16;

    int pt = blockIdx.x, ctile = blockIdx.y, b = blockIdx.z;
    int t = threadIdx.x, l = t & 63, wv = t >> 6;
    int y0 = pt * 8;

    __shared__ __align__(16) ushort Wl[9][32][40];
    __shared__ __align__(16) ushort Xl[10][34][40];

    f32x4 acc[2][4] = {};

    for (int kc = 0; kc < CIN; kc += 32) {
        __syncthreads();
        // ---- X stage: contiguous vector loads from [pix][ch] layout ----
        for (int j = t; j < 1360; j += 256) {
            int slot = j >> 2, part = j & 3;
            int r = slot / 34, c = slot % 34;
            int gy = y0 - 1 + r, gx = c - 1;
            s16x8 v = {};
            if (gy >= 0 && gy < HP && gx >= 0 && gx < WP) {
                int pix = gy * WP + gx;
                if constexpr (MODE == 0) {
                    const float4* sp = (const float4*)&semT[((size_t)b * P + pix) * CS + kc + part * 8];
                    float4 x0 = sp[0], x1 = sp[1];
                    v[0] = (short)f2bf(x0.x); v[1] = (short)f2bf(x0.y);
                    v[2] = (short)f2bf(x0.z); v[3] = (short)f2bf(x0.w);
                    v[4] = (short)f2bf(x1.x); v[5] = (short)f2bf(x1.y);
                    v[6] = (short)f2bf(x1.z); v[7] = (short)f2bf(x1.w);
                } else {
                    v = *(const s16x8*)&hshTin[((size_t)b * P + pix) * 384 + CBASE + kc + part * 8];
                }
            }
            *(s16x8*)&Xl[r][c][part * 8] = v;
        }
        // ---- W stage: straight vector copy from packed ----
        const ushort* wsrc = packW + (size_t)(ctile * KT + (kc >> 5)) * 9216;
        for (int j = t; j < 1152; j += 256) {
            int tap = j >> 7, co2 = (j >> 2) & 31, part = j & 3;
            *(s16x8*)&Wl[tap][co2][part * 8] = *(const s16x8*)&wsrc[(size_t)j * 8];
        }
        __syncthreads();
        // ---- 9 shifted MFMA GEMMs (validated core) ----
        #pragma unroll
        for (int tap = 0; tap < 9; ++tap) {
            int dy = tap / 3, dx = tap % 3;
            s16x8 a0 = *(const s16x8*)&Wl[tap][l & 15][(l >> 4) * 8];
            s16x8 a1 = *(const s16x8*)&Wl[tap][16 + (l & 15)][(l >> 4) * 8];
            #pragma unroll
            for (int nt = 0; nt < 4; ++nt) {
                int q = wv * 64 + nt * 16 + (l & 15);
                int ry = (q >> 5) + dy, rx = (q & 31) + dx;
                s16x8 bf = *(const s16x8*)&Xl[ry][rx][(l >> 4) * 8];
                acc[0][nt] = __builtin_amdgcn_mfma_f32_16x16x32_bf16(a0, bf, acc[0][nt], 0, 0, 0);
                acc[1][nt] = __builtin_amdgcn_mfma_f32_16x16x32_bf16(a1, bf, acc[1][nt], 0, 0, 0);
            }
        }
    }

    if constexpr (MODE == 0) {
        __syncthreads();
        ushort (*T)[36] = (ushort(*)[36])(&Xl[0][0][0]);
        #pragma unroll
        for (int mt = 0; mt < 2; ++mt)
            #pragma unroll
            for (int nt = 0; nt < 4; ++nt)
                #pragma unroll
                for (int r = 0; r < 4; ++r) {
                    int m = mt * 16 + (l >> 4) * 4 + r;
                    int pl = wv * 64 + nt * 16 + (l & 15);
                    int coG = ctile * 32 + m;
                    int sel = coG >> 7, cow = coG & 127;
                    const float* bp = sel == 0 ? bb0 : (sel == 1 ? bb1 : bb2);
                    T[pl][m] = f2bf(fmaxf(acc[mt][nt][r] + bp[cow], 0.f));
                }
        __syncthreads();
        ushort* dst = outH + ((size_t)b * P + pt * 256 + t) * 384 + ctile * 32;
        #pragma unroll
        for (int k = 0; k < 8; ++k) {
            uint2 v = *(const uint2*)&T[t][k * 4];
            *(uint2*)&dst[k * 4] = v;
        }
    } else {
        float mu = st[b * 2] * Ninv;
        float var = st[b * 2 + 1] * Ninv - mu * mu;
        float rs = rsqrtf(var + 1e-12f);
        #pragma unroll
        for (int nt = 0; nt < 4; ++nt)
            #pragma unroll
            for (int r = 0; r < 4; ++r) {
                int m = (l >> 4) * 4 + r;
                if (MODE == 2 && m >= 8) continue;
                int cog = (MODE == 1) ? ctile * 16 + m : m;
                int px = pt * 256 + wv * 64 + nt * 16 + (l & 15);
                float gam = acc[0][nt][r] + bb0[cog];
                float bet = acc[1][nt][r] + bb1[cog];
                float xv = xsrc[((size_t)b * NP + cog) * P + px];
                outF[((size_t)b * NP + cog) * P + px] = (xv - mu) * rs * (1.f + gam) + bet;
            }
    }
}

// -------------------- 1x1 conv 1536->8 split-K ------------------------------
__global__ __launch_bounds__(256) void k_c1x1_a(const float* __restrict__ out0,
                                                const float* __restrict__ w,
                                                float* __restrict__ part) {
    int b = blockIdx.z, ks = blockIdx.y, pg = blockIdx.x;
    int t = threadIdx.x, lp = t & 63, g = t >> 6;
    int pix = pg * 64 + lp;
    float acc[8] = {};
    int ci0 = ks * 64 + g * 16;
    for (int i = 0; i < 16; i++) {
        int ci = ci0 + i;
        float v = out0[((size_t)b * CM + ci) * P + pix];
        #pragma unroll
        for (int o = 0; o < 8; o++) acc[o] += w[o * CM + ci] * v;
    }
    __shared__ float red[4][64][8];
    #pragma unroll
    for (int o = 0; o < 8; o++) red[g][lp][o] = acc[o];
    __syncthreads();
    for (int idx = t; idx < 512; idx += 256) {
        int pp = idx >> 3, o = idx & 7;
        float s = red[0][pp][o] + red[1][pp][o] + red[2][pp][o] + red[3][pp][o];
        part[(((size_t)b * 24 + ks) * 8 + o) * P + pg * 64 + pp] = s;
    }
}

// finalize: 8 blocks per batch, atomic stats
__global__ __launch_bounds__(256) void k_c1x1_a_fin(const float* __restrict__ part,
                                                    const float* __restrict__ bias,
                                                    float* __restrict__ h1a,
                                                    float* __restrict__ stats) {
    int b = blockIdx.y, t = threadIdx.x;
    int idx = blockIdx.x * 1024 + t;          // 8 blocks x 1024 idx
    float s = 0.f, q = 0.f;
    for (int k = 0; k < 4; ++k, idx += 256) {
        int o = idx >> 10, pix = idx & 1023;
        float v = 0.f;
        for (int ks = 0; ks < 24; ks++) v += part[(((size_t)b * 24 + ks) * 8 + o) * P + pix];
        v += bias[o];
        v = softplus_f(v);
        h1a[((size_t)b * 8 + o) * P + pix] = v;
        s += v; q += v * v;
    }
    for (int o2 = 32; o2 > 0; o2 >>= 1) { s += __shfl_down(s, o2); q += __shfl_down(q, o2); }
    __shared__ float ls[4], lq[4];
    int w = t >> 6;
    if ((t & 63) == 0) { ls[w] = s; lq[w] = q; }
    __syncthreads();
    if (t == 0) {
        atomicAdd(&stats[(B + b) * 2],     ls[0] + ls[1] + ls[2] + ls[3]);
        atomicAdd(&stats[(B + b) * 2 + 1], lq[0] + lq[1] + lq[2] + lq[3]);
    }
}

// -------------------- 1x1 conv 8->16 + softplus + LN2 stats ----------------
__global__ __launch_bounds__(256) void k_c1x1_b(const float* __restrict__ out1,
                                                const float* __restrict__ w,
                                                const float* __restrict__ bias,
                                                float* __restrict__ h2a,
                                                float* __restrict__ stats) {
    int b = blockIdx.y, t = threadIdx.x;
    int pix = blockIdx.x * 256 + t;
    float vin[8];
    #pragma unroll
    for (int ci = 0; ci < 8; ci++) vin[ci] = out1[((size_t)b * 8 + ci) * P + pix];
    float s = 0.f, q = 0.f;
    #pragma unroll
    for (int o = 0; o < 16; o++) {
        float a = bias[o];
        #pragma unroll
        for (int ci = 0; ci < 8; ci++) a += w[o * 8 + ci] * vin[ci];
        a = softplus_f(a);
        h2a[((size_t)b * 16 + o) * P + pix] = a;
        s += a; q += a * a;
    }
    for (int o2 = 32; o2 > 0; o2 >>= 1) { s += __shfl_down(s, o2); q += __shfl_down(q, o2); }
    __shared__ float ls[4], lq[4];
    int w2 = t >> 6;
    if ((t & 63) == 0) { ls[w2] = s; lq[w2] = q; }
    __syncthreads();
    if (t == 0) {
        atomicAdd(&stats[(2 * B + b) * 2],     ls[0] + ls[1] + ls[2] + ls[3]);
        atomicAdd(&stats[(2 * B + b) * 2 + 1], lq[0] + lq[1] + lq[2] + lq[3]);
    }
}

// -------------------- final 1x1 conv 16->1 + softplus -> f32 ---------------
__global__ __launch_bounds__(256) void k_final(const float* __restrict__ out2,
                                               const float* __restrict__ w,
                                               const float* __restrict__ bias,
                                               float* __restrict__ out) {
    int b = blockIdx.y, t = threadIdx.x;
    int pix = blockIdx.x * 256 + t;
    float a = bias[0];
    #pragma unroll
    for (int ci = 0; ci < 16; ci++) a += w[ci] * out2[((size_t)b * 16 + ci) * P + pix];
    a = softplus_f(a);
    out[(size_t)b * P + pix] = a;
}

extern "C" void kernel_launch(void* const* d_in, const int* in_sizes, int n_in,
                              void* d_out, int out_size, void* d_ws, size_t ws_size,
                              hipStream_t stream) {
    const float* x_main = (const float*)d_in[0];
    const float* f_sem  = (const float*)d_in[1];
    const float* w_sh0 = (const float*)d_in[2];  const float* b_sh0 = (const float*)d_in[3];
    const float* w_g0  = (const float*)d_in[4];  const float* b_g0  = (const float*)d_in[5];
    const float* w_be0 = (const float*)d_in[6];  const float* b_be0 = (const float*)d_in[7];
    const float* w_sh1 = (const float*)d_in[8];  const float* b_sh1 = (const float*)d_in[9];
    const float* w_g1  = (const float*)d_in[10]; const float* b_g1  = (const float*)d_in[11];
    const float* w_be1 = (const float*)d_in[12]; const float* b_be1 = (const float*)d_in[13];
    const float* w_sh2 = (const float*)d_in[14]; const float* b_sh2 = (const float*)d_in[15];
    const float* w_g2  = (const float*)d_in[16]; const float* b_g2  = (const float*)d_in[17];
    const float* w_be2 = (const float*)d_in[18]; const float* b_be2 = (const float*)d_in[19];
    const float* w_c0  = (const float*)d_in[20]; const float* bias0 = (const float*)d_in[21];
    const float* w_c1  = (const float*)d_in[22]; const float* bias1 = (const float*)d_in[23];
    const float* w_c2  = (const float*)d_in[24]; const float* bias2 = (const float*)d_in[25];
    const int*   segmap = (const int*)d_in[26];

    float* ws = (float*)d_ws;
    float* out = (float*)d_out;
    float* stats = ws + OFF_STATS;
    ushort* hshU = (ushort*)(ws + OFF_HSHT);
    ushort* packU = (ushort*)(ws + OFF_PACK);

    hipMemsetAsync((void*)stats, 0, 16 * sizeof(float), stream);

    k_wpack<<<dim3(2412), 256, 0, stream>>>(w_sh0, w_sh1, w_sh2, w_g0, w_be0,
                                            w_g1, w_be1, w_g2, w_be2, packU);
    k_seg_avg<<<dim3(48, B), 256, 0, stream>>>(f_sem, segmap, ws);
    k_ln0_stats<<<dim3(64, B), 256, 0, stream>>>(x_main, stats);
    k_paint<<<dim3(B * P), 256, 0, stream>>>(segmap, ws);

    k_conv_mfma<0><<<dim3(4, 12, B), 256, 0, stream>>>(
        ws + OFF_SEMT, nullptr, packU + PK0,
        b_sh0, b_sh1, b_sh2, nullptr, nullptr, 0.f, nullptr, hshU);

    k_conv_mfma<1><<<dim3(4, 96, B), 256, 0, stream>>>(
        nullptr, hshU, packU + PK1,
        b_g0, b_be0, nullptr, x_main, stats, 1.f / (float)(CM * P),
        ws + OFF_OUT0, nullptr);

    k_c1x1_a<<<dim3(16, 24, B), 256, 0, stream>>>(ws + OFF_OUT0, w_c0, ws + OFF_P6);
    k_c1x1_a_fin<<<dim3(8, B), 256, 0, stream>>>(ws + OFF_P6, bias0, ws + OFF_H1A, stats);

    k_conv_mfma<2><<<dim3(4, 1, B), 256, 0, stream>>>(
        nullptr, hshU, packU + PK2,
        b_g1, b_be1, nullptr, ws + OFF_H1A, stats + 2 * B, 1.f / (float)(8 * P),
        ws + OFF_OUT1, nullptr);

    k_c1x1_b<<<dim3(4, B), 256, 0, stream>>>(ws + OFF_OUT1, w_c1, bias1, ws + OFF_H2A, stats);

    k_conv_mfma<3><<<dim3(4, 1, B), 256, 0, stream>>>(
        nullptr, hshU, packU + PK3,
        b_g2, b_be2, nullptr, ws + OFF_H2A, stats + 4 * B, 1.f / (float)(16 * P),
        ws + OFF_OUT2, nullptr);

    k_final<<<dim3(4, B), 256, 0, stream>>>(ws + OFF_OUT2, w_c2, bias2, out);
}

// Round 9
// 320.622 us; speedup vs baseline: 3.6138x; 1.1226x over previous
//
#include <hip/hip_runtime.h>
#include <hip/hip_bf16.h>

#define DEV __device__ __forceinline__

constexpr int B = 2;
constexpr int CM = 1536;
constexpr int CS = 384;
constexpr int HP = 32, WP = 32, P = 1024;
constexpr int HI = 448, WI = 448;
constexpr int HM = 128;
constexpr int NSEG = 64;

// ws layout (float units)
constexpr size_t OFF_AVG  = 0;          // B*64*384
constexpr size_t OFF_SEMT = 49152;      // f32 semT[B][1024][384]
constexpr size_t OFF_HSHT = 835584;     // ushort hshT[B][1024][384]
constexpr size_t OFF_OUT0 = 1622016;    // f32 [B][1536][1024]; also conv<0> partial scratch
constexpr size_t OFF_P6   = 4767744;    // f32 [B][24][8][1024]
constexpr size_t OFF_H1A  = 5160960;
constexpr size_t OFF_OUT1 = 5177344;
constexpr size_t OFF_H2A  = 5193728;
constexpr size_t OFF_OUT2 = 5226496;
constexpr size_t OFF_STATS= 5259264;    // 16 floats
constexpr size_t OFF_PACK = 5259280;    // bf16 packed weights

// packed-weight element offsets (ushort units)
constexpr size_t PK0 = 0;           // [12ct][12kc][9tap][32co][32ci]
constexpr size_t PK1 = 1327104;     // [96ct][4kc][9tap][32co][32ci]
constexpr size_t PK2 = 4866048;     // [4kc][9tap][32co][32ci] (rows 8-15,24-31 zero)
constexpr size_t PK3 = 4902912;     // [4kc][9tap][32co][32ci]
constexpr int    PK_CHUNKS = 617472;

typedef __attribute__((ext_vector_type(8))) short s16x8;
typedef __attribute__((ext_vector_type(4))) float f32x4;

DEV float softplus_f(float x) {
    return fmaxf(x, 0.f) + log1pf(expf(-fabsf(x)));
}
DEV ushort f2bf(float f) {
    union { float f; unsigned u; } x; x.f = f;
    unsigned r = x.u + 0x7fffu + ((x.u >> 16) & 1u);
    return (ushort)(r >> 16);
}
DEV float bf2f(ushort u) {
    union { unsigned u; float f; } x; x.u = ((unsigned)u) << 16;
    return x.f;
}

// -------------------- 1. segment averages (coalesced, 96 blocks) ------------
__global__ __launch_bounds__(256) void k_seg_avg(const float* __restrict__ f_sem,
                                                 const int* __restrict__ segmap,
                                                 float* __restrict__ ws) {
    int b = blockIdx.y;
    int c0 = blockIdx.x * 8;
    __shared__ int   segs[P];
    __shared__ float sums[NSEG][9];
    __shared__ float cnt[NSEG];
    int t = threadIdx.x;
    for (int i = t; i < NSEG * 9; i += 256) (&sums[0][0])[i] = 0.f;
    if (t < NSEG) cnt[t] = 0.f;
    __syncthreads();
    for (int p = t; p < P; p += 256) {
        int i = p >> 5, j = p & 31;
        int s = segmap[(b * HI + i * 14) * WI + j * 14];
        s = min(max(s, 0), NSEG - 1);
        segs[p] = s;
        atomicAdd(&cnt[s], 1.f);
    }
    __syncthreads();
    #pragma unroll
    for (int ch = 0; ch < 8; ++ch) {
        const float* fp = f_sem + ((size_t)b * CS + c0 + ch) * P;
        #pragma unroll
        for (int pb = 0; pb < 4; ++pb) {
            int p = pb * 256 + t;
            float v = fp[p];
            atomicAdd(&sums[segs[p]][ch], v);
        }
    }
    __syncthreads();
    for (int i = t; i < NSEG * 8; i += 256) {
        int s = i >> 3, ch = i & 7;
        float cv = cnt[s];
        ws[OFF_AVG + ((size_t)(b * NSEG + s)) * CS + c0 + ch] =
            cv > 0.f ? sums[s][ch] / cv : 0.f;
    }
}

// -------------------- 2. paint + bilinear -> semT[pix][ch] ------------------
__global__ __launch_bounds__(256) void k_paint(const int* __restrict__ segmap,
                                               float* __restrict__ ws) {
    int pixb = blockIdx.x;
    int b = pixb >> 10, op = pixb & 1023;
    int oy = op >> 5, ox = op & 31;
    __shared__ float Wb[NSEG];
    __shared__ float normv;
    int t = threadIdx.x;
    if (t < NSEG) Wb[t] = 0.f;
    __syncthreads();
    float cy = 14.f * oy + 6.5f, cx = 14.f * ox + 6.5f;
    int y0 = 14 * oy - 7, x0 = 14 * ox - 7;
    for (int k = t; k < 28 * 28; k += 256) {
        int jy = y0 + k / 28, jx = x0 + k % 28;
        if (jy < 0 || jy >= HI || jx < 0 || jx >= WI) continue;
        float wy = 1.f - fabsf(cy - (float)jy) * (1.f / 14.f);
        float wx = 1.f - fabsf(cx - (float)jx) * (1.f / 14.f);
        int s = segmap[(b * HI + jy) * WI + jx];
        s = min(max(s, 0), NSEG - 1);
        atomicAdd(&Wb[s], wy * wx);
    }
    if (t == 0) {
        float sy = 0.f, sx = 0.f;
        for (int d = 0; d < 28; d++) {
            int jy = y0 + d;
            if (jy >= 0 && jy < HI) sy += 1.f - fabsf(cy - (float)jy) * (1.f / 14.f);
            int jx = x0 + d;
            if (jx >= 0 && jx < WI) sx += 1.f - fabsf(cx - (float)jx) * (1.f / 14.f);
        }
        normv = 1.f / (sy * sx);
    }
    __syncthreads();
    float nv = normv;
    for (int c = t; c < CS; c += 256) {
        float acc = 0.f;
        const float* ap = ws + OFF_AVG + ((size_t)b * NSEG) * CS + c;
        #pragma unroll
        for (int s = 0; s < NSEG; s++) acc += Wb[s] * ap[(size_t)s * CS];
        ws[OFF_SEMT + ((size_t)b * P + op) * CS + c] = acc * nv;
    }
}

// -------------------- 3. LN0 stats --------------------
__global__ __launch_bounds__(256) void k_ln0_stats(const float* __restrict__ x,
                                                   float* __restrict__ stats) {
    int b = blockIdx.y;
    const float4* xp = (const float4*)(x + (size_t)b * CM * P);
    int n4 = CM * P / 4;
    float s = 0.f, q = 0.f;
    for (int i = blockIdx.x * 256 + threadIdx.x; i < n4; i += 64 * 256) {
        float4 v = xp[i];
        s += v.x + v.y + v.z + v.w;
        q += v.x * v.x + v.y * v.y + v.z * v.z + v.w * v.w;
    }
    for (int o = 32; o > 0; o >>= 1) { s += __shfl_down(s, o); q += __shfl_down(q, o); }
    __shared__ float ls[4], lq[4];
    int w = threadIdx.x >> 6;
    if ((threadIdx.x & 63) == 0) { ls[w] = s; lq[w] = q; }
    __syncthreads();
    if (threadIdx.x == 0) {
        atomicAdd(&stats[b * 2],     ls[0] + ls[1] + ls[2] + ls[3]);
        atomicAdd(&stats[b * 2 + 1], lq[0] + lq[1] + lq[2] + lq[3]);
    }
}

// -------------------- 4. weight pre-pack to bf16, LDS tile order ------------
__global__ __launch_bounds__(256) void k_wpack(
    const float* __restrict__ w_sh0, const float* __restrict__ w_sh1, const float* __restrict__ w_sh2,
    const float* __restrict__ w_g0,  const float* __restrict__ w_be0,
    const float* __restrict__ w_g1,  const float* __restrict__ w_be1,
    const float* __restrict__ w_g2,  const float* __restrict__ w_be2,
    ushort* __restrict__ packU)
{
    for (int c8 = blockIdx.x * 256 + threadIdx.x; c8 < PK_CHUNKS; c8 += gridDim.x * 256) {
        size_t e = (size_t)c8 * 8;
        const float* s0 = nullptr;
        bool zero = false;
        if (e < PK1) {                         // mode0
            size_t r = e;
            int ci0 = (int)(r & 31), co2 = (int)((r >> 5) & 31);
            int tap = (int)((r >> 10) % 9);
            int kct = (int)((r / 9216) % 12), ct = (int)(r / 110592);
            int coG = ct * 32 + co2, sel = coG >> 7, cow = coG & 127;
            const float* wp = sel == 0 ? w_sh0 : (sel == 1 ? w_sh1 : w_sh2);
            s0 = &wp[((size_t)cow * CS + kct * 32 + ci0) * 9 + tap];
        } else if (e < PK2) {                  // mode1
            size_t r = e - PK1;
            int ci0 = (int)(r & 31), co2 = (int)((r >> 5) & 31);
            int tap = (int)((r >> 10) % 9);
            int kct = (int)((r / 9216) % 4), ct = (int)(r / 36864);
            int cog = ct * 16 + (co2 & 15);
            const float* wp = co2 < 16 ? w_g0 : w_be0;
            s0 = &wp[((size_t)cog * HM + kct * 32 + ci0) * 9 + tap];
        } else if (e < PK3) {                  // mode2
            size_t r = e - PK2;
            int ci0 = (int)(r & 31), co2 = (int)((r >> 5) & 31);
            int tap = (int)((r >> 10) % 9);
            int kct = (int)(r / 9216);
            zero = ((co2 & 15) >= 8);
            int cog = co2 & 7;
            const float* wp = co2 < 16 ? w_g1 : w_be1;
            if (!zero) s0 = &wp[((size_t)cog * HM + kct * 32 + ci0) * 9 + tap];
        } else {                               // mode3
            size_t r = e - PK3;
            int ci0 = (int)(r & 31), co2 = (int)((r >> 5) & 31);
            int tap = (int)((r >> 10) % 9);
            int kct = (int)(r / 9216);
            int cog = co2 & 15;
            const float* wp = co2 < 16 ? w_g2 : w_be2;
            s0 = &wp[((size_t)cog * HM + kct * 32 + ci0) * 9 + tap];
        }
        s16x8 o;
        #pragma unroll
        for (int i = 0; i < 8; ++i) {
            float v = zero ? 0.f : s0[(size_t)i * 9];
            o[i] = (short)f2bf(v);
        }
        *(s16x8*)&packU[e] = o;
    }
}

// -------------------- 5. MFMA 3x3 conv (9 shifted GEMMs) --------------------
// MODE0: semT f32, K-chunk of 128 (ks=blockIdx.z/B), 4-row tiles -> bf16 PARTIAL (no bias)
// MODE1: hshT ch0..127  -> 16g+16b, LN0 -> out0 f32
// MODE2: hshT ch128..255 -> 8g+8b (padded), LN1 -> out1 f32
// MODE3: hshT ch256..383 -> 16g+16b, LN2 -> out2 f32
template<int MODE>
__global__ __launch_bounds__(256) void k_conv_mfma(
    const float* __restrict__ semT, const ushort* __restrict__ hshTin,
    const ushort* __restrict__ packW,
    const float* __restrict__ bb0, const float* __restrict__ bb1, const float* __restrict__ bb2,
    const float* __restrict__ xsrc, const float* __restrict__ st, float Ninv,
    float* __restrict__ outF, ushort* __restrict__ outH)
{
    constexpr int ROWS = (MODE == 0) ? 4 : 8;        // output rows per block
    constexpr int NT   = ROWS / 2;                   // 16-pixel groups per wave
    constexpr int XR   = ROWS + 2;                   // halo rows
    constexpr int KTOT = (MODE == 0) ? 12 : 4;       // kc-tiles per ctile in pack
    constexpr int CBASE = (MODE == 2) ? 128 : (MODE == 3) ? 256 : 0;
    constexpr int NP = (MODE == 1) ? 1536 : (MODE == 2) ? 8 : 16;

    int pt = blockIdx.x, ctile = blockIdx.y;
    int zz = blockIdx.z;
    int b  = (MODE == 0) ? (zz % B) : zz;
    int ks = (MODE == 0) ? (zz / B) : 0;
    int t = threadIdx.x, l = t & 63, wv = t >> 6;
    int y0 = pt * ROWS;

    __shared__ __align__(16) ushort Wl[9][32][40];
    __shared__ __align__(16) ushort Xl[XR][34][40];

    f32x4 acc[2][NT] = {};

    for (int kc = 0; kc < 128; kc += 32) {
        __syncthreads();
        // ---- X stage ----
        for (int j = t; j < XR * 34 * 4; j += 256) {
            int slot = j >> 2, part = j & 3;
            int r = slot / 34, c = slot % 34;
            int gy = y0 - 1 + r, gx = c - 1;
            s16x8 v = {};
            if (gy >= 0 && gy < HP && gx >= 0 && gx < WP) {
                int pix = gy * WP + gx;
                if constexpr (MODE == 0) {
                    const float4* sp = (const float4*)&semT[((size_t)b * P + pix) * CS + ks * 128 + kc + part * 8];
                    float4 x0 = sp[0], x1 = sp[1];
                    v[0] = (short)f2bf(x0.x); v[1] = (short)f2bf(x0.y);
                    v[2] = (short)f2bf(x0.z); v[3] = (short)f2bf(x0.w);
                    v[4] = (short)f2bf(x1.x); v[5] = (short)f2bf(x1.y);
                    v[6] = (short)f2bf(x1.z); v[7] = (short)f2bf(x1.w);
                } else {
                    v = *(const s16x8*)&hshTin[((size_t)b * P + pix) * 384 + CBASE + kc + part * 8];
                }
            }
            *(s16x8*)&Xl[r][c][part * 8] = v;
        }
        // ---- W stage ----
        const ushort* wsrc = packW + (size_t)(ctile * KTOT + ks * 4 + (kc >> 5)) * 9216;
        for (int j = t; j < 1152; j += 256) {
            int tap = j >> 7, co2 = (j >> 2) & 31, part = j & 3;
            *(s16x8*)&Wl[tap][co2][part * 8] = *(const s16x8*)&wsrc[(size_t)j * 8];
        }
        __syncthreads();
        // ---- 9 shifted MFMA GEMMs ----
        #pragma unroll
        for (int tap = 0; tap < 9; ++tap) {
            int dy = tap / 3, dx = tap % 3;
            s16x8 a0 = *(const s16x8*)&Wl[tap][l & 15][(l >> 4) * 8];
            s16x8 a1 = *(const s16x8*)&Wl[tap][16 + (l & 15)][(l >> 4) * 8];
            #pragma unroll
            for (int nt = 0; nt < NT; ++nt) {
                int q = wv * (16 * NT) + nt * 16 + (l & 15);
                int ry = (q >> 5) + dy, rx = (q & 31) + dx;
                s16x8 bf = *(const s16x8*)&Xl[ry][rx][(l >> 4) * 8];
                acc[0][nt] = __builtin_amdgcn_mfma_f32_16x16x32_bf16(a0, bf, acc[0][nt], 0, 0, 0);
                acc[1][nt] = __builtin_amdgcn_mfma_f32_16x16x32_bf16(a1, bf, acc[1][nt], 0, 0, 0);
            }
        }
    }

    if constexpr (MODE == 0) {
        // raw bf16 partial (no bias/relu) -> scratch[(ks*B+b)][pix][384]
        __syncthreads();
        ushort (*T)[36] = (ushort(*)[36])(&Xl[0][0][0]);   // [128][36] fits
        #pragma unroll
        for (int mt = 0; mt < 2; ++mt)
            #pragma unroll
            for (int nt = 0; nt < NT; ++nt)
                #pragma unroll
                for (int r = 0; r < 4; ++r) {
                    int m = mt * 16 + (l >> 4) * 4 + r;
                    int pl = wv * (16 * NT) + nt * 16 + (l & 15);
                    T[pl][m] = f2bf(acc[mt][nt][r]);
                }
        __syncthreads();
        int row = t >> 1, half = t & 1;
        ushort* dst = outH + ((size_t)((ks * B + b) * P) + pt * 128 + row) * 384 + ctile * 32 + half * 16;
        *(s16x8*)dst = *(const s16x8*)&T[row][half * 16];
    } else {
        float mu = st[b * 2] * Ninv;
        float var = st[b * 2 + 1] * Ninv - mu * mu;
        float rs = rsqrtf(var + 1e-12f);
        #pragma unroll
        for (int nt = 0; nt < NT; ++nt)
            #pragma unroll
            for (int r = 0; r < 4; ++r) {
                int m = (l >> 4) * 4 + r;
                if (MODE == 2 && m >= 8) continue;
                int cog = (MODE == 1) ? ctile * 16 + m : m;
                int px = pt * 256 + wv * 64 + nt * 16 + (l & 15);
                float gam = acc[0][nt][r] + bb0[cog];
                float bet = acc[1][nt][r] + bb1[cog];
                float xv = xsrc[((size_t)b * NP + cog) * P + px];
                outF[((size_t)b * NP + cog) * P + px] = (xv - mu) * rs * (1.f + gam) + bet;
            }
    }
}

// -------------------- 5b. sum partials + bias + relu -> hshT ----------------
__global__ __launch_bounds__(256) void k_hsh_fin(const ushort* __restrict__ part,
                                                 const float* __restrict__ b0,
                                                 const float* __restrict__ b1,
                                                 const float* __restrict__ b2,
                                                 ushort* __restrict__ hsh) {
    int gid = blockIdx.x * 256 + threadIdx.x;      // 98304 threads
    int grp = gid % 48, pixg = gid / 48;
    int ch0 = grp * 8;
    size_t base = (size_t)pixg * 384 + ch0;
    s16x8 p0 = *(const s16x8*)&part[(size_t)0 * B * P * 384 + base];
    s16x8 p1 = *(const s16x8*)&part[(size_t)1 * B * P * 384 + base];
    s16x8 p2 = *(const s16x8*)&part[(size_t)2 * B * P * 384 + base];
    int sel = ch0 >> 7;
    const float* bp = sel == 0 ? b0 : (sel == 1 ? b1 : b2);
    int cb = ch0 & 127;
    s16x8 o;
    #pragma unroll
    for (int i = 0; i < 8; ++i) {
        float v = bf2f((ushort)p0[i]) + bf2f((ushort)p1[i]) + bf2f((ushort)p2[i]) + bp[cb + i];
        o[i] = (short)f2bf(fmaxf(v, 0.f));
    }
    *(s16x8*)&hsh[base] = o;
}

// -------------------- 1x1 conv 1536->8 split-K ------------------------------
__global__ __launch_bounds__(256) void k_c1x1_a(const float* __restrict__ out0,
                                                const float* __restrict__ w,
                                                float* __restrict__ part) {
    int b = blockIdx.z, ks = blockIdx.y, pg = blockIdx.x;
    int t = threadIdx.x, lp = t & 63, g = t >> 6;
    int pix = pg * 64 + lp;
    float acc[8] = {};
    int ci0 = ks * 64 + g * 16;
    for (int i = 0; i < 16; i++) {
        int ci = ci0 + i;
        float v = out0[((size_t)b * CM + ci) * P + pix];
        #pragma unroll
        for (int o = 0; o < 8; o++) acc[o] += w[o * CM + ci] * v;
    }
    __shared__ float red[4][64][8];
    #pragma unroll
    for (int o = 0; o < 8; o++) red[g][lp][o] = acc[o];
    __syncthreads();
    for (int idx = t; idx < 512; idx += 256) {
        int pp = idx >> 3, o = idx & 7;
        float s = red[0][pp][o] + red[1][pp][o] + red[2][pp][o] + red[3][pp][o];
        part[(((size_t)b * 24 + ks) * 8 + o) * P + pg * 64 + pp] = s;
    }
}

__global__ __launch_bounds__(256) void k_c1x1_a_fin(const float* __restrict__ part,
                                                    const float* __restrict__ bias,
                                                    float* __restrict__ h1a,
                                                    float* __restrict__ stats) {
    int b = blockIdx.y, t = threadIdx.x;
    int idx = blockIdx.x * 1024 + t;
    float s = 0.f, q = 0.f;
    for (int k = 0; k < 4; ++k, idx += 256) {
        int o = idx >> 10, pix = idx & 1023;
        float v = 0.f;
        for (int ks = 0; ks < 24; ks++) v += part[(((size_t)b * 24 + ks) * 8 + o) * P + pix];
        v += bias[o];
        v = softplus_f(v);
        h1a[((size_t)b * 8 + o) * P + pix] = v;
        s += v; q += v * v;
    }
    for (int o2 = 32; o2 > 0; o2 >>= 1) { s += __shfl_down(s, o2); q += __shfl_down(q, o2); }
    __shared__ float ls[4], lq[4];
    int w = t >> 6;
    if ((t & 63) == 0) { ls[w] = s; lq[w] = q; }
    __syncthreads();
    if (t == 0) {
        atomicAdd(&stats[(B + b) * 2],     ls[0] + ls[1] + ls[2] + ls[3]);
        atomicAdd(&stats[(B + b) * 2 + 1], lq[0] + lq[1] + lq[2] + lq[3]);
    }
}

// -------------------- 1x1 conv 8->16 + softplus + LN2 stats ----------------
__global__ __launch_bounds__(256) void k_c1x1_b(const float* __restrict__ out1,
                                                const float* __restrict__ w,
                                                const float* __restrict__ bias,
                                                float* __restrict__ h2a,
                                                float* __restrict__ stats) {
    int b = blockIdx.y, t = threadIdx.x;
    int pix = blockIdx.x * 256 + t;
    float vin[8];
    #pragma unroll
    for (int ci = 0; ci < 8; ci++) vin[ci] = out1[((size_t)b * 8 + ci) * P + pix];
    float s = 0.f, q = 0.f;
    #pragma unroll
    for (int o = 0; o < 16; o++) {
        float a = bias[o];
        #pragma unroll
        for (int ci = 0; ci < 8; ci++) a += w[o * 8 + ci] * vin[ci];
        a = softplus_f(a);
        h2a[((size_t)b * 16 + o) * P + pix] = a;
        s += a; q += a * a;
    }
    for (int o2 = 32; o2 > 0; o2 >>= 1) { s += __shfl_down(s, o2); q += __shfl_down(q, o2); }
    __shared__ float ls[4], lq[4];
    int w2 = t >> 6;
    if ((t & 63) == 0) { ls[w2] = s; lq[w2] = q; }
    __syncthreads();
    if (t == 0) {
        atomicAdd(&stats[(2 * B + b) * 2],     ls[0] + ls[1] + ls[2] + ls[3]);
        atomicAdd(&stats[(2 * B + b) * 2 + 1], lq[0] + lq[1] + lq[2] + lq[3]);
    }
}

// -------------------- final 1x1 conv 16->1 + softplus -> f32 ---------------
__global__ __launch_bounds__(256) void k_final(const float* __restrict__ out2,
                                               const float* __restrict__ w,
                                               const float* __restrict__ bias,
                                               float* __restrict__ out) {
    int b = blockIdx.y, t = threadIdx.x;
    int pix = blockIdx.x * 256 + t;
    float a = bias[0];
    #pragma unroll
    for (int ci = 0; ci < 16; ci++) a += w[ci] * out2[((size_t)b * 16 + ci) * P + pix];
    a = softplus_f(a);
    out[(size_t)b * P + pix] = a;
}

extern "C" void kernel_launch(void* const* d_in, const int* in_sizes, int n_in,
                              void* d_out, int out_size, void* d_ws, size_t ws_size,
                              hipStream_t stream) {
    const float* x_main = (const float*)d_in[0];
    const float* f_sem  = (const float*)d_in[1];
    const float* w_sh0 = (const float*)d_in[2];  const float* b_sh0 = (const float*)d_in[3];
    const float* w_g0  = (const float*)d_in[4];  const float* b_g0  = (const float*)d_in[5];
    const float* w_be0 = (const float*)d_in[6];  const float* b_be0 = (const float*)d_in[7];
    const float* w_sh1 = (const float*)d_in[8];  const float* b_sh1 = (const float*)d_in[9];
    const float* w_g1  = (const float*)d_in[10]; const float* b_g1  = (const float*)d_in[11];
    const float* w_be1 = (const float*)d_in[12]; const float* b_be1 = (const float*)d_in[13];
    const float* w_sh2 = (const float*)d_in[14]; const float* b_sh2 = (const float*)d_in[15];
    const float* w_g2  = (const float*)d_in[16]; const float* b_g2  = (const float*)d_in[17];
    const float* w_be2 = (const float*)d_in[18]; const float* b_be2 = (const float*)d_in[19];
    const float* w_c0  = (const float*)d_in[20]; const float* bias0 = (const float*)d_in[21];
    const float* w_c1  = (const float*)d_in[22]; const float* bias1 = (const float*)d_in[23];
    const float* w_c2  = (const float*)d_in[24]; const float* bias2 = (const float*)d_in[25];
    const int*   segmap = (const int*)d_in[26];

    float* ws = (float*)d_ws;
    float* out = (float*)d_out;
    float* stats = ws + OFF_STATS;
    ushort* hshU = (ushort*)(ws + OFF_HSHT);
    ushort* partU = (ushort*)(ws + OFF_OUT0);    // conv<0> partial scratch (dead until conv<1>)
    ushort* packU = (ushort*)(ws + OFF_PACK);

    hipMemsetAsync((void*)stats, 0, 16 * sizeof(float), stream);

    k_wpack<<<dim3(2412), 256, 0, stream>>>(w_sh0, w_sh1, w_sh2, w_g0, w_be0,
                                            w_g1, w_be1, w_g2, w_be2, packU);
    k_seg_avg<<<dim3(48, B), 256, 0, stream>>>(f_sem, segmap, ws);
    k_ln0_stats<<<dim3(64, B), 256, 0, stream>>>(x_main, stats);
    k_paint<<<dim3(B * P), 256, 0, stream>>>(segmap, ws);

    // conv_sh: K-split x3, 4-row tiles -> partials, then finalize
    k_conv_mfma<0><<<dim3(8, 12, 3 * B), 256, 0, stream>>>(
        ws + OFF_SEMT, nullptr, packU + PK0,
        nullptr, nullptr, nullptr, nullptr, nullptr, 0.f, nullptr, partU);
    k_hsh_fin<<<dim3(384), 256, 0, stream>>>(partU, b_sh0, b_sh1, b_sh2, hshU);

    k_conv_mfma<1><<<dim3(4, 96, B), 256, 0, stream>>>(
        nullptr, hshU, packU + PK1,
        b_g0, b_be0, nullptr, x_main, stats, 1.f / (float)(CM * P),
        ws + OFF_OUT0, nullptr);

    k_c1x1_a<<<dim3(16, 24, B), 256, 0, stream>>>(ws + OFF_OUT0, w_c0, ws + OFF_P6);
    k_c1x1_a_fin<<<dim3(8, B), 256, 0, stream>>>(ws + OFF_P6, bias0, ws + OFF_H1A, stats);

    k_conv_mfma<2><<<dim3(4, 1, B), 256, 0, stream>>>(
        nullptr, hshU, packU + PK2,
        b_g1, b_be1, nullptr, ws + OFF_H1A, stats + 2 * B, 1.f / (float)(8 * P),
        ws + OFF_OUT1, nullptr);

    k_c1x1_b<<<dim3(4, B), 256, 0, stream>>>(ws + OFF_OUT1, w_c1, bias1, ws + OFF_H2A, stats);

    k_conv_mfma<3><<<dim3(4, 1, B), 256, 0, stream>>>(
        nullptr, hshU, packU + PK3,
        b_g2, b_be2, nullptr, ws + OFF_H2A, stats + 4 * B, 1.f / (float)(16 * P),
        ws + OFF_OUT2, nullptr);

    k_final<<<dim3(4, B), 256, 0, stream>>>(ws + OFF_OUT2, w_c2, bias2, out);
}

// Round 10
// 319.377 us; speedup vs baseline: 3.6279x; 1.0039x over previous
//
#include <hip/hip_runtime.h>
#include <hip/hip_bf16.h>

#define DEV __device__ __forceinline__

constexpr int B = 2;
constexpr int CM = 1536;
constexpr int CS = 384;
constexpr int HP = 32, WP = 32, P = 1024;
constexpr int HI = 448, WI = 448;
constexpr int HM = 128;
constexpr int NSEG = 64;

// ws layout (float units)
constexpr size_t OFF_AVG  = 0;          // B*64*384
constexpr size_t OFF_SEMT = 49152;      // f32 semT[B][1024][384]
constexpr size_t OFF_HSHT = 835584;     // ushort hshT[B][1024][384]
constexpr size_t OFF_OUT0 = 1622016;    // f32 [B][1536][1024]; also conv<0> partial scratch
constexpr size_t OFF_P6   = 4767744;    // f32 [B][24][8][1024]
constexpr size_t OFF_H1A  = 5160960;
constexpr size_t OFF_OUT1 = 5177344;
constexpr size_t OFF_H2A  = 5193728;
constexpr size_t OFF_OUT2 = 5226496;
constexpr size_t OFF_STATS= 5259264;    // 16 floats
constexpr size_t OFF_PACK = 5259280;    // bf16 packed weights

// packed-weight element offsets (ushort units)
constexpr size_t PK0 = 0;           // [12ct][12kc][9tap][32co][32ci]
constexpr size_t PK1 = 1327104;     // [96ct][4kc][9tap][32co][32ci]
constexpr size_t PK2 = 4866048;     // [4kc][9tap][32co][32ci] (rows 8-15,24-31 zero)
constexpr size_t PK3 = 4902912;     // [4kc][9tap][32co][32ci]
constexpr int    PK_CHUNKS = 617472;

typedef __attribute__((ext_vector_type(8))) short s16x8;
typedef __attribute__((ext_vector_type(4))) float f32x4;

DEV float softplus_f(float x) {
    return fmaxf(x, 0.f) + log1pf(expf(-fabsf(x)));
}
DEV ushort f2bf(float f) {
    union { float f; unsigned u; } x; x.f = f;
    unsigned r = x.u + 0x7fffu + ((x.u >> 16) & 1u);
    return (ushort)(r >> 16);
}
DEV float bf2f(ushort u) {
    union { unsigned u; float f; } x; x.u = ((unsigned)u) << 16;
    return x.f;
}

// -------------------- 1. segment averages (coalesced, 96 blocks) ------------
__global__ __launch_bounds__(256) void k_seg_avg(const float* __restrict__ f_sem,
                                                 const int* __restrict__ segmap,
                                                 float* __restrict__ ws) {
    int b = blockIdx.y;
    int c0 = blockIdx.x * 8;
    __shared__ int   segs[P];
    __shared__ float sums[NSEG][9];
    __shared__ float cnt[NSEG];
    int t = threadIdx.x;
    for (int i = t; i < NSEG * 9; i += 256) (&sums[0][0])[i] = 0.f;
    if (t < NSEG) cnt[t] = 0.f;
    __syncthreads();
    for (int p = t; p < P; p += 256) {
        int i = p >> 5, j = p & 31;
        int s = segmap[(b * HI + i * 14) * WI + j * 14];
        s = min(max(s, 0), NSEG - 1);
        segs[p] = s;
        atomicAdd(&cnt[s], 1.f);
    }
    __syncthreads();
    #pragma unroll
    for (int ch = 0; ch < 8; ++ch) {
        const float* fp = f_sem + ((size_t)b * CS + c0 + ch) * P;
        #pragma unroll
        for (int pb = 0; pb < 4; ++pb) {
            int p = pb * 256 + t;
            float v = fp[p];
            atomicAdd(&sums[segs[p]][ch], v);
        }
    }
    __syncthreads();
    for (int i = t; i < NSEG * 8; i += 256) {
        int s = i >> 3, ch = i & 7;
        float cv = cnt[s];
        ws[OFF_AVG + ((size_t)(b * NSEG + s)) * CS + c0 + ch] =
            cv > 0.f ? sums[s][ch] / cv : 0.f;
    }
}

// -------------------- 2. paint: ox-tiled windows + seg-GEMV -> semT ---------
// grid (4 oxt, 32 oy, B). Each block: 8 output pixels sharing a 28x126 window.
__global__ __launch_bounds__(256) void k_paint(const int* __restrict__ segmap,
                                               float* __restrict__ ws) {
    int oxt = blockIdx.x, oy = blockIdx.y, b = blockIdx.z;
    int ox0 = oxt * 8;
    __shared__ float WbT[8][65];     // [ox][seg] +pad
    __shared__ float norm[8];
    int t = threadIdx.x;
    for (int i = t; i < 8 * 65; i += 256) (&WbT[0][0])[i] = 0.f;
    __syncthreads();

    float cy = 14.f * oy + 6.5f;
    int y0 = 14 * oy - 7;
    int x0 = 14 * ox0 - 7;
    // 28 rows x 126 cols covers all 8 windows
    for (int k = t; k < 28 * 126; k += 256) {
        int r = k / 126, cix = k % 126;
        int jy = y0 + r, jx = x0 + cix;
        if (jy < 0 || jy >= HI || jx < 0 || jx >= WI) continue;
        float wy = 1.f - fabsf(cy - (float)jy) * (1.f / 14.f);
        int s = segmap[(b * HI + jy) * WI + jx];
        s = min(max(s, 0), NSEG - 1);
        int oxhi = (jx + 7) / 14;            // exactly {oxhi, oxhi-1} are candidates
        #pragma unroll
        for (int d = 0; d < 2; ++d) {
            int ox = oxhi - d;
            if (ox < ox0 || ox >= ox0 + 8) continue;
            float wx = 1.f - fabsf(14.f * ox + 6.5f - (float)jx) * (1.f / 14.f);
            if (wx > 0.f) atomicAdd(&WbT[ox - ox0][s], wy * wx);
        }
    }
    __syncthreads();
    // normalizer: sum over s equals sy*sx exactly
    if (t < 8) {
        float sm = 0.f;
        #pragma unroll
        for (int s = 0; s < NSEG; ++s) sm += WbT[t][s];
        norm[t] = 1.f / sm;
    }
    __syncthreads();

    const float* ap0 = ws + OFF_AVG + (size_t)b * NSEG * CS;
    for (int c = t; c < CS; c += 256) {
        float acc[8] = {};
        const float* ap = ap0 + c;
        #pragma unroll
        for (int s = 0; s < NSEG; ++s) {
            float a = ap[(size_t)s * CS];
            #pragma unroll
            for (int ox = 0; ox < 8; ++ox) acc[ox] += WbT[ox][s] * a;
        }
        #pragma unroll
        for (int ox = 0; ox < 8; ++ox) {
            int op = oy * 32 + ox0 + ox;
            ws[OFF_SEMT + ((size_t)b * P + op) * CS + c] = acc[ox] * norm[ox];
        }
    }
}

// -------------------- 3. LN0 stats --------------------
__global__ __launch_bounds__(256) void k_ln0_stats(const float* __restrict__ x,
                                                   float* __restrict__ stats) {
    int b = blockIdx.y;
    const float4* xp = (const float4*)(x + (size_t)b * CM * P);
    int n4 = CM * P / 4;
    float s = 0.f, q = 0.f;
    for (int i = blockIdx.x * 256 + threadIdx.x; i < n4; i += 64 * 256) {
        float4 v = xp[i];
        s += v.x + v.y + v.z + v.w;
        q += v.x * v.x + v.y * v.y + v.z * v.z + v.w * v.w;
    }
    for (int o = 32; o > 0; o >>= 1) { s += __shfl_down(s, o); q += __shfl_down(q, o); }
    __shared__ float ls[4], lq[4];
    int w = threadIdx.x >> 6;
    if ((threadIdx.x & 63) == 0) { ls[w] = s; lq[w] = q; }
    __syncthreads();
    if (threadIdx.x == 0) {
        atomicAdd(&stats[b * 2],     ls[0] + ls[1] + ls[2] + ls[3]);
        atomicAdd(&stats[b * 2 + 1], lq[0] + lq[1] + lq[2] + lq[3]);
    }
}

// -------------------- 4. weight pre-pack to bf16, LDS tile order ------------
__global__ __launch_bounds__(256) void k_wpack(
    const float* __restrict__ w_sh0, const float* __restrict__ w_sh1, const float* __restrict__ w_sh2,
    const float* __restrict__ w_g0,  const float* __restrict__ w_be0,
    const float* __restrict__ w_g1,  const float* __restrict__ w_be1,
    const float* __restrict__ w_g2,  const float* __restrict__ w_be2,
    ushort* __restrict__ packU)
{
    for (int c8 = blockIdx.x * 256 + threadIdx.x; c8 < PK_CHUNKS; c8 += gridDim.x * 256) {
        size_t e = (size_t)c8 * 8;
        const float* s0 = nullptr;
        bool zero = false;
        if (e < PK1) {                         // mode0
            size_t r = e;
            int ci0 = (int)(r & 31), co2 = (int)((r >> 5) & 31);
            int tap = (int)((r >> 10) % 9);
            int kct = (int)((r / 9216) % 12), ct = (int)(r / 110592);
            int coG = ct * 32 + co2, sel = coG >> 7, cow = coG & 127;
            const float* wp = sel == 0 ? w_sh0 : (sel == 1 ? w_sh1 : w_sh2);
            s0 = &wp[((size_t)cow * CS + kct * 32 + ci0) * 9 + tap];
        } else if (e < PK2) {                  // mode1
            size_t r = e - PK1;
            int ci0 = (int)(r & 31), co2 = (int)((r >> 5) & 31);
            int tap = (int)((r >> 10) % 9);
            int kct = (int)((r / 9216) % 4), ct = (int)(r / 36864);
            int cog = ct * 16 + (co2 & 15);
            const float* wp = co2 < 16 ? w_g0 : w_be0;
            s0 = &wp[((size_t)cog * HM + kct * 32 + ci0) * 9 + tap];
        } else if (e < PK3) {                  // mode2
            size_t r = e - PK2;
            int ci0 = (int)(r & 31), co2 = (int)((r >> 5) & 31);
            int tap = (int)((r >> 10) % 9);
            int kct = (int)(r / 9216);
            zero = ((co2 & 15) >= 8);
            int cog = co2 & 7;
            const float* wp = co2 < 16 ? w_g1 : w_be1;
            if (!zero) s0 = &wp[((size_t)cog * HM + kct * 32 + ci0) * 9 + tap];
        } else {                               // mode3
            size_t r = e - PK3;
            int ci0 = (int)(r & 31), co2 = (int)((r >> 5) & 31);
            int tap = (int)((r >> 10) % 9);
            int kct = (int)(r / 9216);
            int cog = co2 & 15;
            const float* wp = co2 < 16 ? w_g2 : w_be2;
            s0 = &wp[((size_t)cog * HM + kct * 32 + ci0) * 9 + tap];
        }
        s16x8 o;
        #pragma unroll
        for (int i = 0; i < 8; ++i) {
            float v = zero ? 0.f : s0[(size_t)i * 9];
            o[i] = (short)f2bf(v);
        }
        *(s16x8*)&packU[e] = o;
    }
}

// -------------------- 5. MFMA 3x3 conv (9 shifted GEMMs) --------------------
template<int MODE>
__global__ __launch_bounds__(256) void k_conv_mfma(
    const float* __restrict__ semT, const ushort* __restrict__ hshTin,
    const ushort* __restrict__ packW,
    const float* __restrict__ bb0, const float* __restrict__ bb1, const float* __restrict__ bb2,
    const float* __restrict__ xsrc, const float* __restrict__ st, float Ninv,
    float* __restrict__ outF, ushort* __restrict__ outH)
{
    constexpr int ROWS = (MODE == 0) ? 4 : 8;
    constexpr int NT   = ROWS / 2;
    constexpr int XR   = ROWS + 2;
    constexpr int KTOT = (MODE == 0) ? 12 : 4;
    constexpr int CBASE = (MODE == 2) ? 128 : (MODE == 3) ? 256 : 0;
    constexpr int NP = (MODE == 1) ? 1536 : (MODE == 2) ? 8 : 16;

    int pt = blockIdx.x, ctile = blockIdx.y;
    int zz = blockIdx.z;
    int b  = (MODE == 0) ? (zz % B) : zz;
    int ks = (MODE == 0) ? (zz / B) : 0;
    int t = threadIdx.x, l = t & 63, wv = t >> 6;
    int y0 = pt * ROWS;

    __shared__ __align__(16) ushort Wl[9][32][40];
    __shared__ __align__(16) ushort Xl[XR][34][40];

    f32x4 acc[2][NT] = {};

    for (int kc = 0; kc < 128; kc += 32) {
        __syncthreads();
        for (int j = t; j < XR * 34 * 4; j += 256) {
            int slot = j >> 2, part = j & 3;
            int r = slot / 34, c = slot % 34;
            int gy = y0 - 1 + r, gx = c - 1;
            s16x8 v = {};
            if (gy >= 0 && gy < HP && gx >= 0 && gx < WP) {
                int pix = gy * WP + gx;
                if constexpr (MODE == 0) {
                    const float4* sp = (const float4*)&semT[((size_t)b * P + pix) * CS + ks * 128 + kc + part * 8];
                    float4 x0 = sp[0], x1 = sp[1];
                    v[0] = (short)f2bf(x0.x); v[1] = (short)f2bf(x0.y);
                    v[2] = (short)f2bf(x0.z); v[3] = (short)f2bf(x0.w);
                    v[4] = (short)f2bf(x1.x); v[5] = (short)f2bf(x1.y);
                    v[6] = (short)f2bf(x1.z); v[7] = (short)f2bf(x1.w);
                } else {
                    v = *(const s16x8*)&hshTin[((size_t)b * P + pix) * 384 + CBASE + kc + part * 8];
                }
            }
            *(s16x8*)&Xl[r][c][part * 8] = v;
        }
        const ushort* wsrc = packW + (size_t)(ctile * KTOT + ks * 4 + (kc >> 5)) * 9216;
        for (int j = t; j < 1152; j += 256) {
            int tap = j >> 7, co2 = (j >> 2) & 31, part = j & 3;
            *(s16x8*)&Wl[tap][co2][part * 8] = *(const s16x8*)&wsrc[(size_t)j * 8];
        }
        __syncthreads();
        #pragma unroll
        for (int tap = 0; tap < 9; ++tap) {
            int dy = tap / 3, dx = tap % 3;
            s16x8 a0 = *(const s16x8*)&Wl[tap][l & 15][(l >> 4) * 8];
            s16x8 a1 = *(const s16x8*)&Wl[tap][16 + (l & 15)][(l >> 4) * 8];
            #pragma unroll
            for (int nt = 0; nt < NT; ++nt) {
                int q = wv * (16 * NT) + nt * 16 + (l & 15);
                int ry = (q >> 5) + dy, rx = (q & 31) + dx;
                s16x8 bf = *(const s16x8*)&Xl[ry][rx][(l >> 4) * 8];
                acc[0][nt] = __builtin_amdgcn_mfma_f32_16x16x32_bf16(a0, bf, acc[0][nt], 0, 0, 0);
                acc[1][nt] = __builtin_amdgcn_mfma_f32_16x16x32_bf16(a1, bf, acc[1][nt], 0, 0, 0);
            }
        }
    }

    if constexpr (MODE == 0) {
        __syncthreads();
        ushort (*T)[36] = (ushort(*)[36])(&Xl[0][0][0]);
        #pragma unroll
        for (int mt = 0; mt < 2; ++mt)
            #pragma unroll
            for (int nt = 0; nt < NT; ++nt)
                #pragma unroll
                for (int r = 0; r < 4; ++r) {
                    int m = mt * 16 + (l >> 4) * 4 + r;
                    int pl = wv * (16 * NT) + nt * 16 + (l & 15);
                    T[pl][m] = f2bf(acc[mt][nt][r]);
                }
        __syncthreads();
        int row = t >> 1, half = t & 1;
        ushort* dst = outH + ((size_t)((ks * B + b) * P) + pt * 128 + row) * 384 + ctile * 32 + half * 16;
        *(s16x8*)dst = *(const s16x8*)&T[row][half * 16];
    } else {
        float mu = st[b * 2] * Ninv;
        float var = st[b * 2 + 1] * Ninv - mu * mu;
        float rs = rsqrtf(var + 1e-12f);
        #pragma unroll
        for (int nt = 0; nt < NT; ++nt)
            #pragma unroll
            for (int r = 0; r < 4; ++r) {
                int m = (l >> 4) * 4 + r;
                if (MODE == 2 && m >= 8) continue;
                int cog = (MODE == 1) ? ctile * 16 + m : m;
                int px = pt * 256 + wv * 64 + nt * 16 + (l & 15);
                float gam = acc[0][nt][r] + bb0[cog];
                float bet = acc[1][nt][r] + bb1[cog];
                float xv = xsrc[((size_t)b * NP + cog) * P + px];
                outF[((size_t)b * NP + cog) * P + px] = (xv - mu) * rs * (1.f + gam) + bet;
            }
    }
}

// -------------------- 5b. sum partials + bias + relu -> hshT ----------------
__global__ __launch_bounds__(256) void k_hsh_fin(const ushort* __restrict__ part,
                                                 const float* __restrict__ b0,
                                                 const float* __restrict__ b1,
                                                 const float* __restrict__ b2,
                                                 ushort* __restrict__ hsh) {
    int gid = blockIdx.x * 256 + threadIdx.x;
    int grp = gid % 48, pixg = gid / 48;
    int ch0 = grp * 8;
    size_t base = (size_t)pixg * 384 + ch0;
    s16x8 p0 = *(const s16x8*)&part[(size_t)0 * B * P * 384 + base];
    s16x8 p1 = *(const s16x8*)&part[(size_t)1 * B * P * 384 + base];
    s16x8 p2 = *(const s16x8*)&part[(size_t)2 * B * P * 384 + base];
    int sel = ch0 >> 7;
    const float* bp = sel == 0 ? b0 : (sel == 1 ? b1 : b2);
    int cb = ch0 & 127;
    s16x8 o;
    #pragma unroll
    for (int i = 0; i < 8; ++i) {
        float v = bf2f((ushort)p0[i]) + bf2f((ushort)p1[i]) + bf2f((ushort)p2[i]) + bp[cb + i];
        o[i] = (short)f2bf(fmaxf(v, 0.f));
    }
    *(s16x8*)&hsh[base] = o;
}

// -------------------- 1x1 conv 1536->8 split-K ------------------------------
__global__ __launch_bounds__(256) void k_c1x1_a(const float* __restrict__ out0,
                                                const float* __restrict__ w,
                                                float* __restrict__ part) {
    int b = blockIdx.z, ks = blockIdx.y, pg = blockIdx.x;
    int t = threadIdx.x, lp = t & 63, g = t >> 6;
    int pix = pg * 64 + lp;
    float acc[8] = {};
    int ci0 = ks * 64 + g * 16;
    for (int i = 0; i < 16; i++) {
        int ci = ci0 + i;
        float v = out0[((size_t)b * CM + ci) * P + pix];
        #pragma unroll
        for (int o = 0; o < 8; o++) acc[o] += w[o * CM + ci] * v;
    }
    __shared__ float red[4][64][8];
    #pragma unroll
    for (int o = 0; o < 8; o++) red[g][lp][o] = acc[o];
    __syncthreads();
    for (int idx = t; idx < 512; idx += 256) {
        int pp = idx >> 3, o = idx & 7;
        float s = red[0][pp][o] + red[1][pp][o] + red[2][pp][o] + red[3][pp][o];
        part[(((size_t)b * 24 + ks) * 8 + o) * P + pg * 64 + pp] = s;
    }
}

__global__ __launch_bounds__(256) void k_c1x1_a_fin(const float* __restrict__ part,
                                                    const float* __restrict__ bias,
                                                    float* __restrict__ h1a,
                                                    float* __restrict__ stats) {
    int b = blockIdx.y, t = threadIdx.x;
    int idx = blockIdx.x * 1024 + t;
    float s = 0.f, q = 0.f;
    for (int k = 0; k < 4; ++k, idx += 256) {
        int o = idx >> 10, pix = idx & 1023;
        float v = 0.f;
        for (int ks = 0; ks < 24; ks++) v += part[(((size_t)b * 24 + ks) * 8 + o) * P + pix];
        v += bias[o];
        v = softplus_f(v);
        h1a[((size_t)b * 8 + o) * P + pix] = v;
        s += v; q += v * v;
    }
    for (int o2 = 32; o2 > 0; o2 >>= 1) { s += __shfl_down(s, o2); q += __shfl_down(q, o2); }
    __shared__ float ls[4], lq[4];
    int w = t >> 6;
    if ((t & 63) == 0) { ls[w] = s; lq[w] = q; }
    __syncthreads();
    if (t == 0) {
        atomicAdd(&stats[(B + b) * 2],     ls[0] + ls[1] + ls[2] + ls[3]);
        atomicAdd(&stats[(B + b) * 2 + 1], lq[0] + lq[1] + lq[2] + lq[3]);
    }
}

// -------------------- 1x1 conv 8->16 + softplus + LN2 stats ----------------
__global__ __launch_bounds__(256) void k_c1x1_b(const float* __restrict__ out1,
                                                const float* __restrict__ w,
                                                const float* __restrict__ bias,
                                                float* __restrict__ h2a,
                                                float* __restrict__ stats) {
    int b = blockIdx.y, t = threadIdx.x;
    int pix = blockIdx.x * 256 + t;
    float vin[8];
    #pragma unroll
    for (int ci = 0; ci < 8; ci++) vin[ci] = out1[((size_t)b * 8 + ci) * P + pix];
    float s = 0.f, q = 0.f;
    #pragma unroll
    for (int o = 0; o < 16; o++) {
        float a = bias[o];
        #pragma unroll
        for (int ci = 0; ci < 8; ci++) a += w[o * 8 + ci] * vin[ci];
        a = softplus_f(a);
        h2a[((size_t)b * 16 + o) * P + pix] = a;
        s += a; q += a * a;
    }
    for (int o2 = 32; o2 > 0; o2 >>= 1) { s += __shfl_down(s, o2); q += __shfl_down(q, o2); }
    __shared__ float ls[4], lq[4];
    int w2 = t >> 6;
    if ((t & 63) == 0) { ls[w2] = s; lq[w2] = q; }
    __syncthreads();
    if (t == 0) {
        atomicAdd(&stats[(2 * B + b) * 2],     ls[0] + ls[1] + ls[2] + ls[3]);
        atomicAdd(&stats[(2 * B + b) * 2 + 1], lq[0] + lq[1] + lq[2] + lq[3]);
    }
}

// -------------------- final 1x1 conv 16->1 + softplus -> f32 ---------------
__global__ __launch_bounds__(256) void k_final(const float* __restrict__ out2,
                                               const float* __restrict__ w,
                                               const float* __restrict__ bias,
                                               float* __restrict__ out) {
    int b = blockIdx.y, t = threadIdx.x;
    int pix = blockIdx.x * 256 + t;
    float a = bias[0];
    #pragma unroll
    for (int ci = 0; ci < 16; ci++) a += w[ci] * out2[((size_t)b * 16 + ci) * P + pix];
    a = softplus_f(a);
    out[(size_t)b * P + pix] = a;
}

extern "C" void kernel_launch(void* const* d_in, const int* in_sizes, int n_in,
                              void* d_out, int out_size, void* d_ws, size_t ws_size,
                              hipStream_t stream) {
    const float* x_main = (const float*)d_in[0];
    const float* f_sem  = (const float*)d_in[1];
    const float* w_sh0 = (const float*)d_in[2];  const float* b_sh0 = (const float*)d_in[3];
    const float* w_g0  = (const float*)d_in[4];  const float* b_g0  = (const float*)d_in[5];
    const float* w_be0 = (const float*)d_in[6];  const float* b_be0 = (const float*)d_in[7];
    const float* w_sh1 = (const float*)d_in[8];  const float* b_sh1 = (const float*)d_in[9];
    const float* w_g1  = (const float*)d_in[10]; const float* b_g1  = (const float*)d_in[11];
    const float* w_be1 = (const float*)d_in[12]; const float* b_be1 = (const float*)d_in[13];
    const float* w_sh2 = (const float*)d_in[14]; const float* b_sh2 = (const float*)d_in[15];
    const float* w_g2  = (const float*)d_in[16]; const float* b_g2  = (const float*)d_in[17];
    const float* w_be2 = (const float*)d_in[18]; const float* b_be2 = (const float*)d_in[19];
    const float* w_c0  = (const float*)d_in[20]; const float* bias0 = (const float*)d_in[21];
    const float* w_c1  = (const float*)d_in[22]; const float* bias1 = (const float*)d_in[23];
    const float* w_c2  = (const float*)d_in[24]; const float* bias2 = (const float*)d_in[25];
    const int*   segmap = (const int*)d_in[26];

    float* ws = (float*)d_ws;
    float* out = (float*)d_out;
    float* stats = ws + OFF_STATS;
    ushort* hshU = (ushort*)(ws + OFF_HSHT);
    ushort* partU = (ushort*)(ws + OFF_OUT0);
    ushort* packU = (ushort*)(ws + OFF_PACK);

    hipMemsetAsync((void*)stats, 0, 16 * sizeof(float), stream);

    k_wpack<<<dim3(2412), 256, 0, stream>>>(w_sh0, w_sh1, w_sh2, w_g0, w_be0,
                                            w_g1, w_be1, w_g2, w_be2, packU);
    k_seg_avg<<<dim3(48, B), 256, 0, stream>>>(f_sem, segmap, ws);
    k_ln0_stats<<<dim3(64, B), 256, 0, stream>>>(x_main, stats);
    k_paint<<<dim3(4, 32, B), 256, 0, stream>>>(segmap, ws);

    k_conv_mfma<0><<<dim3(8, 12, 3 * B), 256, 0, stream>>>(
        ws + OFF_SEMT, nullptr, packU + PK0,
        nullptr, nullptr, nullptr, nullptr, nullptr, 0.f, nullptr, partU);
    k_hsh_fin<<<dim3(384), 256, 0, stream>>>(partU, b_sh0, b_sh1, b_sh2, hshU);

    k_conv_mfma<1><<<dim3(4, 96, B), 256, 0, stream>>>(
        nullptr, hshU, packU + PK1,
        b_g0, b_be0, nullptr, x_main, stats, 1.f / (float)(CM * P),
        ws + OFF_OUT0, nullptr);

    k_c1x1_a<<<dim3(16, 24, B), 256, 0, stream>>>(ws + OFF_OUT0, w_c0, ws + OFF_P6);
    k_c1x1_a_fin<<<dim3(8, B), 256, 0, stream>>>(ws + OFF_P6, bias0, ws + OFF_H1A, stats);

    k_conv_mfma<2><<<dim3(4, 1, B), 256, 0, stream>>>(
        nullptr, hshU, packU + PK2,
        b_g1, b_be1, nullptr, ws + OFF_H1A, stats + 2 * B, 1.f / (float)(8 * P),
        ws + OFF_OUT1, nullptr);

    k_c1x1_b<<<dim3(4, B), 256, 0, stream>>>(ws + OFF_OUT1, w_c1, bias1, ws + OFF_H2A, stats);

    k_conv_mfma<3><<<dim3(4, 1, B), 256, 0, stream>>>(
        nullptr, hshU, packU + PK3,
        b_g2, b_be2, nullptr, ws + OFF_H2A, stats + 4 * B, 1.f / (float)(16 * P),
        ws + OFF_OUT2, nullptr);

    k_final<<<dim3(4, B), 256, 0, stream>>>(ws + OFF_OUT2, w_c2, bias2, out);
}

// Round 11
// 306.373 us; speedup vs baseline: 3.7819x; 1.0424x over previous
//
#include <hip/hip_runtime.h>
#include <hip/hip_bf16.h>

#define DEV __device__ __forceinline__

constexpr int B = 2;
constexpr int CM = 1536;
constexpr int CS = 384;
constexpr int HP = 32, WP = 32, P = 1024;
constexpr int HI = 448, WI = 448;
constexpr int HM = 128;
constexpr int NSEG = 64;

// ws layout (float units)
constexpr size_t OFF_AVG  = 0;          // B*64*384
constexpr size_t OFF_SEMT = 49152;      // f32 semT[B][1024][384]
constexpr size_t OFF_HSHT = 835584;     // ushort hshT[B][1024][384]
constexpr size_t OFF_OUT0 = 1622016;    // scratch: conv<0> bf16 partials, then c1x1a f32 partials
constexpr size_t OFF_P6   = 4767744;    // (unused now)
constexpr size_t OFF_H1A  = 5160960;
constexpr size_t OFF_OUT1 = 5177344;    // (unused now)
constexpr size_t OFF_H2A  = 5193728;
constexpr size_t OFF_OUT2 = 5226496;    // (unused now)
constexpr size_t OFF_STATS= 5259264;    // 16 floats
constexpr size_t OFF_PACK = 5259280;    // bf16 packed weights

// packed-weight element offsets (ushort units)
constexpr size_t PK0 = 0;           // [12ct][12kc][9tap][32co][32ci]
constexpr size_t PK1 = 1327104;     // [96ct][4kc][9tap][32co][32ci]
constexpr size_t PK2 = 4866048;     // [4kc][9tap][32co][32ci] (rows 8-15,24-31 zero)
constexpr size_t PK3 = 4902912;     // [4kc][9tap][32co][32ci]
constexpr int    PK_CHUNKS = 617472;

typedef __attribute__((ext_vector_type(8))) short s16x8;
typedef __attribute__((ext_vector_type(4))) float f32x4;

DEV float softplus_f(float x) {
    return fmaxf(x, 0.f) + log1pf(expf(-fabsf(x)));
}
DEV ushort f2bf(float f) {
    union { float f; unsigned u; } x; x.f = f;
    unsigned r = x.u + 0x7fffu + ((x.u >> 16) & 1u);
    return (ushort)(r >> 16);
}
DEV float bf2f(ushort u) {
    union { unsigned u; float f; } x; x.u = ((unsigned)u) << 16;
    return x.f;
}

// -------------------- 1. segment averages (coalesced, 96 blocks) ------------
__global__ __launch_bounds__(256) void k_seg_avg(const float* __restrict__ f_sem,
                                                 const int* __restrict__ segmap,
                                                 float* __restrict__ ws) {
    int b = blockIdx.y;
    int c0 = blockIdx.x * 8;
    __shared__ int   segs[P];
    __shared__ float sums[NSEG][9];
    __shared__ float cnt[NSEG];
    int t = threadIdx.x;
    for (int i = t; i < NSEG * 9; i += 256) (&sums[0][0])[i] = 0.f;
    if (t < NSEG) cnt[t] = 0.f;
    __syncthreads();
    for (int p = t; p < P; p += 256) {
        int i = p >> 5, j = p & 31;
        int s = segmap[(b * HI + i * 14) * WI + j * 14];
        s = min(max(s, 0), NSEG - 1);
        segs[p] = s;
        atomicAdd(&cnt[s], 1.f);
    }
    __syncthreads();
    #pragma unroll
    for (int ch = 0; ch < 8; ++ch) {
        const float* fp = f_sem + ((size_t)b * CS + c0 + ch) * P;
        #pragma unroll
        for (int pb = 0; pb < 4; ++pb) {
            int p = pb * 256 + t;
            float v = fp[p];
            atomicAdd(&sums[segs[p]][ch], v);
        }
    }
    __syncthreads();
    for (int i = t; i < NSEG * 8; i += 256) {
        int s = i >> 3, ch = i & 7;
        float cv = cnt[s];
        ws[OFF_AVG + ((size_t)(b * NSEG + s)) * CS + c0 + ch] =
            cv > 0.f ? sums[s][ch] / cv : 0.f;
    }
}

// -------------------- 2. paint: ox-tiled windows + seg-GEMV -> semT ---------
__global__ __launch_bounds__(256) void k_paint(const int* __restrict__ segmap,
                                               float* __restrict__ ws) {
    int oxt = blockIdx.x, oy = blockIdx.y, b = blockIdx.z;
    int ox0 = oxt * 8;
    __shared__ float WbT[8][65];
    __shared__ float norm[8];
    int t = threadIdx.x;
    for (int i = t; i < 8 * 65; i += 256) (&WbT[0][0])[i] = 0.f;
    __syncthreads();

    float cy = 14.f * oy + 6.5f;
    int y0 = 14 * oy - 7;
    int x0 = 14 * ox0 - 7;
    for (int k = t; k < 28 * 126; k += 256) {
        int r = k / 126, cix = k % 126;
        int jy = y0 + r, jx = x0 + cix;
        if (jy < 0 || jy >= HI || jx < 0 || jx >= WI) continue;
        float wy = 1.f - fabsf(cy - (float)jy) * (1.f / 14.f);
        int s = segmap[(b * HI + jy) * WI + jx];
        s = min(max(s, 0), NSEG - 1);
        int oxhi = (jx + 7) / 14;
        #pragma unroll
        for (int d = 0; d < 2; ++d) {
            int ox = oxhi - d;
            if (ox < ox0 || ox >= ox0 + 8) continue;
            float wx = 1.f - fabsf(14.f * ox + 6.5f - (float)jx) * (1.f / 14.f);
            if (wx > 0.f) atomicAdd(&WbT[ox - ox0][s], wy * wx);
        }
    }
    __syncthreads();
    if (t < 8) {
        float sm = 0.f;
        #pragma unroll
        for (int s = 0; s < NSEG; ++s) sm += WbT[t][s];
        norm[t] = 1.f / sm;
    }
    __syncthreads();

    const float* ap0 = ws + OFF_AVG + (size_t)b * NSEG * CS;
    for (int c = t; c < CS; c += 256) {
        float acc[8] = {};
        const float* ap = ap0 + c;
        #pragma unroll
        for (int s = 0; s < NSEG; ++s) {
            float a = ap[(size_t)s * CS];
            #pragma unroll
            for (int ox = 0; ox < 8; ++ox) acc[ox] += WbT[ox][s] * a;
        }
        #pragma unroll
        for (int ox = 0; ox < 8; ++ox) {
            int op = oy * 32 + ox0 + ox;
            ws[OFF_SEMT + ((size_t)b * P + op) * CS + c] = acc[ox] * norm[ox];
        }
    }
}

// -------------------- 3. LN0 stats --------------------
__global__ __launch_bounds__(256) void k_ln0_stats(const float* __restrict__ x,
                                                   float* __restrict__ stats) {
    int b = blockIdx.y;
    const float4* xp = (const float4*)(x + (size_t)b * CM * P);
    int n4 = CM * P / 4;
    float s = 0.f, q = 0.f;
    for (int i = blockIdx.x * 256 + threadIdx.x; i < n4; i += 64 * 256) {
        float4 v = xp[i];
        s += v.x + v.y + v.z + v.w;
        q += v.x * v.x + v.y * v.y + v.z * v.z + v.w * v.w;
    }
    for (int o = 32; o > 0; o >>= 1) { s += __shfl_down(s, o); q += __shfl_down(q, o); }
    __shared__ float ls[4], lq[4];
    int w = threadIdx.x >> 6;
    if ((threadIdx.x & 63) == 0) { ls[w] = s; lq[w] = q; }
    __syncthreads();
    if (threadIdx.x == 0) {
        atomicAdd(&stats[b * 2],     ls[0] + ls[1] + ls[2] + ls[3]);
        atomicAdd(&stats[b * 2 + 1], lq[0] + lq[1] + lq[2] + lq[3]);
    }
}

// -------------------- 4. weight pre-pack to bf16, LDS tile order ------------
__global__ __launch_bounds__(256) void k_wpack(
    const float* __restrict__ w_sh0, const float* __restrict__ w_sh1, const float* __restrict__ w_sh2,
    const float* __restrict__ w_g0,  const float* __restrict__ w_be0,
    const float* __restrict__ w_g1,  const float* __restrict__ w_be1,
    const float* __restrict__ w_g2,  const float* __restrict__ w_be2,
    ushort* __restrict__ packU)
{
    for (int c8 = blockIdx.x * 256 + threadIdx.x; c8 < PK_CHUNKS; c8 += gridDim.x * 256) {
        size_t e = (size_t)c8 * 8;
        const float* s0 = nullptr;
        bool zero = false;
        if (e < PK1) {
            size_t r = e;
            int ci0 = (int)(r & 31), co2 = (int)((r >> 5) & 31);
            int tap = (int)((r >> 10) % 9);
            int kct = (int)((r / 9216) % 12), ct = (int)(r / 110592);
            int coG = ct * 32 + co2, sel = coG >> 7, cow = coG & 127;
            const float* wp = sel == 0 ? w_sh0 : (sel == 1 ? w_sh1 : w_sh2);
            s0 = &wp[((size_t)cow * CS + kct * 32 + ci0) * 9 + tap];
        } else if (e < PK2) {
            size_t r = e - PK1;
            int ci0 = (int)(r & 31), co2 = (int)((r >> 5) & 31);
            int tap = (int)((r >> 10) % 9);
            int kct = (int)((r / 9216) % 4), ct = (int)(r / 36864);
            int cog = ct * 16 + (co2 & 15);
            const float* wp = co2 < 16 ? w_g0 : w_be0;
            s0 = &wp[((size_t)cog * HM + kct * 32 + ci0) * 9 + tap];
        } else if (e < PK3) {
            size_t r = e - PK2;
            int ci0 = (int)(r & 31), co2 = (int)((r >> 5) & 31);
            int tap = (int)((r >> 10) % 9);
            int kct = (int)(r / 9216);
            zero = ((co2 & 15) >= 8);
            int cog = co2 & 7;
            const float* wp = co2 < 16 ? w_g1 : w_be1;
            if (!zero) s0 = &wp[((size_t)cog * HM + kct * 32 + ci0) * 9 + tap];
        } else {
            size_t r = e - PK3;
            int ci0 = (int)(r & 31), co2 = (int)((r >> 5) & 31);
            int tap = (int)((r >> 10) % 9);
            int kct = (int)(r / 9216);
            int cog = co2 & 15;
            const float* wp = co2 < 16 ? w_g2 : w_be2;
            s0 = &wp[((size_t)cog * HM + kct * 32 + ci0) * 9 + tap];
        }
        s16x8 o;
        #pragma unroll
        for (int i = 0; i < 8; ++i) {
            float v = zero ? 0.f : s0[(size_t)i * 9];
            o[i] = (short)f2bf(v);
        }
        *(s16x8*)&packU[e] = o;
    }
}

// -------------------- 5. MFMA 3x3 conv (9 shifted GEMMs) --------------------
// MODE0: semT f32, K-split x3, 4-row tiles -> bf16 PARTIAL
// MODE1: hshT ch0..127 -> LN0-combine -> FUSED c1x1_a partial (w_c0) -> fout
// MODE2: hshT ch128..255 -> LN1-combine -> FUSED c1x1_b+softplus -> h2a + LN2 stats
// MODE3: hshT ch256..383 -> LN2-combine -> FUSED final 1x1+softplus -> d_out
template<int MODE>
__global__ __launch_bounds__(256) void k_conv_mfma(
    const float* __restrict__ semT, const ushort* __restrict__ hshTin,
    const ushort* __restrict__ packW,
    const float* __restrict__ bb0, const float* __restrict__ bb1,
    const float* __restrict__ xsrc, const float* __restrict__ st, float Ninv,
    const float* __restrict__ wcf, const float* __restrict__ bcf,
    float* __restrict__ fout, float* __restrict__ statsOut,
    ushort* __restrict__ outH)
{
    constexpr int ROWS = (MODE == 0) ? 4 : 8;
    constexpr int NT   = ROWS / 2;
    constexpr int XR   = ROWS + 2;
    constexpr int KTOT = (MODE == 0) ? 12 : 4;
    constexpr int CBASE = (MODE == 2) ? 128 : (MODE == 3) ? 256 : 0;
    constexpr int NP = (MODE == 1) ? 1536 : (MODE == 2) ? 8 : 16;

    int pt = blockIdx.x, ctile = blockIdx.y;
    int zz = blockIdx.z;
    int b  = (MODE == 0) ? (zz % B) : zz;
    int ks = (MODE == 0) ? (zz / B) : 0;
    int t = threadIdx.x, l = t & 63, wv = t >> 6;
    int y0 = pt * ROWS;

    __shared__ __align__(16) ushort Wl[9][32][40];
    __shared__ __align__(16) ushort Xl[XR][34][40];

    f32x4 acc[2][NT] = {};

    for (int kc = 0; kc < 128; kc += 32) {
        __syncthreads();
        for (int j = t; j < XR * 34 * 4; j += 256) {
            int slot = j >> 2, part = j & 3;
            int r = slot / 34, c = slot % 34;
            int gy = y0 - 1 + r, gx = c - 1;
            s16x8 v = {};
            if (gy >= 0 && gy < HP && gx >= 0 && gx < WP) {
                int pix = gy * WP + gx;
                if constexpr (MODE == 0) {
                    const float4* sp = (const float4*)&semT[((size_t)b * P + pix) * CS + ks * 128 + kc + part * 8];
                    float4 x0 = sp[0], x1 = sp[1];
                    v[0] = (short)f2bf(x0.x); v[1] = (short)f2bf(x0.y);
                    v[2] = (short)f2bf(x0.z); v[3] = (short)f2bf(x0.w);
                    v[4] = (short)f2bf(x1.x); v[5] = (short)f2bf(x1.y);
                    v[6] = (short)f2bf(x1.z); v[7] = (short)f2bf(x1.w);
                } else {
                    v = *(const s16x8*)&hshTin[((size_t)b * P + pix) * 384 + CBASE + kc + part * 8];
                }
            }
            *(s16x8*)&Xl[r][c][part * 8] = v;
        }
        const ushort* wsrc = packW + (size_t)(ctile * KTOT + ks * 4 + (kc >> 5)) * 9216;
        for (int j = t; j < 1152; j += 256) {
            int tap = j >> 7, co2 = (j >> 2) & 31, part = j & 3;
            *(s16x8*)&Wl[tap][co2][part * 8] = *(const s16x8*)&wsrc[(size_t)j * 8];
        }
        __syncthreads();
        #pragma unroll
        for (int tap = 0; tap < 9; ++tap) {
            int dy = tap / 3, dx = tap % 3;
            s16x8 a0 = *(const s16x8*)&Wl[tap][l & 15][(l >> 4) * 8];
            s16x8 a1 = *(const s16x8*)&Wl[tap][16 + (l & 15)][(l >> 4) * 8];
            #pragma unroll
            for (int nt = 0; nt < NT; ++nt) {
                int q = wv * (16 * NT) + nt * 16 + (l & 15);
                int ry = (q >> 5) + dy, rx = (q & 31) + dx;
                s16x8 bf = *(const s16x8*)&Xl[ry][rx][(l >> 4) * 8];
                acc[0][nt] = __builtin_amdgcn_mfma_f32_16x16x32_bf16(a0, bf, acc[0][nt], 0, 0, 0);
                acc[1][nt] = __builtin_amdgcn_mfma_f32_16x16x32_bf16(a1, bf, acc[1][nt], 0, 0, 0);
            }
        }
    }

    if constexpr (MODE == 0) {
        __syncthreads();
        ushort (*T)[36] = (ushort(*)[36])(&Xl[0][0][0]);
        #pragma unroll
        for (int mt = 0; mt < 2; ++mt)
            #pragma unroll
            for (int nt = 0; nt < NT; ++nt)
                #pragma unroll
                for (int r = 0; r < 4; ++r) {
                    int m = mt * 16 + (l >> 4) * 4 + r;
                    int pl = wv * (16 * NT) + nt * 16 + (l & 15);
                    T[pl][m] = f2bf(acc[mt][nt][r]);
                }
        __syncthreads();
        int row = t >> 1, half = t & 1;
        ushort* dst = outH + ((size_t)((ks * B + b) * P) + pt * 128 + row) * 384 + ctile * 32 + half * 16;
        *(s16x8*)dst = *(const s16x8*)&T[row][half * 16];
    } else if constexpr (MODE == 1) {
        float mu = st[b * 2] * Ninv;
        float var = st[b * 2 + 1] * Ninv - mu * mu;
        float rs = rsqrtf(var + 1e-12f);
        // stage w_c0 slice [8o][16m] into Wl region
        __syncthreads();
        float (*WC)[17] = (float(*)[17])(&Wl[0][0][0]);
        if (t < 128) WC[t >> 4][t & 15] = wcf[(size_t)(t >> 4) * CM + ctile * 16 + (t & 15)];
        __syncthreads();
        float pacc[8][4] = {};
        #pragma unroll
        for (int nt = 0; nt < NT; ++nt)
            #pragma unroll
            for (int r = 0; r < 4; ++r) {
                int m = (l >> 4) * 4 + r;
                int cog = ctile * 16 + m;
                int px = pt * 256 + wv * 64 + nt * 16 + (l & 15);
                float gam = acc[0][nt][r] + bb0[cog];
                float bet = acc[1][nt][r] + bb1[cog];
                float xv = xsrc[((size_t)b * NP + cog) * P + px];
                float o0 = (xv - mu) * rs * (1.f + gam) + bet;
                #pragma unroll
                for (int o = 0; o < 8; ++o) pacc[o][nt] += WC[o][m] * o0;
            }
        #pragma unroll
        for (int o = 0; o < 8; ++o)
            #pragma unroll
            for (int nt = 0; nt < NT; ++nt) {
                float v = pacc[o][nt];
                v += __shfl_xor(v, 16);
                v += __shfl_xor(v, 32);
                if ((l >> 4) == 0)
                    fout[(((size_t)b * 96 + ctile) * 8 + o) * P + pt * 256 + wv * 64 + nt * 16 + l] = v;
            }
    } else if constexpr (MODE == 2) {
        float mu = st[b * 2] * Ninv;
        float var = st[b * 2 + 1] * Ninv - mu * mu;
        float rs = rsqrtf(var + 1e-12f);
        __syncthreads();
        float (*O1)[9] = (float(*)[9])(&Xl[0][0][0]);
        #pragma unroll
        for (int nt = 0; nt < NT; ++nt)
            #pragma unroll
            for (int r = 0; r < 4; ++r) {
                int m = (l >> 4) * 4 + r;
                if (m < 8) {
                    int pxl = wv * 64 + nt * 16 + (l & 15);
                    int px = pt * 256 + pxl;
                    float gam = acc[0][nt][r] + bb0[m];
                    float bet = acc[1][nt][r] + bb1[m];
                    float xv = xsrc[((size_t)b * NP + m) * P + px];
                    O1[pxl][m] = (xv - mu) * rs * (1.f + gam) + bet;
                }
            }
        __syncthreads();
        float vin[8];
        #pragma unroll
        for (int ci = 0; ci < 8; ++ci) vin[ci] = O1[t][ci];
        float s = 0.f, q = 0.f;
        #pragma unroll
        for (int o = 0; o < 16; ++o) {
            float a = bcf[o];
            #pragma unroll
            for (int ci = 0; ci < 8; ++ci) a += wcf[o * 8 + ci] * vin[ci];
            a = softplus_f(a);
            fout[((size_t)b * 16 + o) * P + pt * 256 + t] = a;
            s += a; q += a * a;
        }
        for (int o2 = 32; o2 > 0; o2 >>= 1) { s += __shfl_down(s, o2); q += __shfl_down(q, o2); }
        float* red = (float*)&Wl[0][0][0];
        if ((t & 63) == 0) { red[wv] = s; red[4 + wv] = q; }
        __syncthreads();
        if (t == 0) {
            atomicAdd(&statsOut[b * 2],     red[0] + red[1] + red[2] + red[3]);
            atomicAdd(&statsOut[b * 2 + 1], red[4] + red[5] + red[6] + red[7]);
        }
    } else {
        float mu = st[b * 2] * Ninv;
        float var = st[b * 2 + 1] * Ninv - mu * mu;
        float rs = rsqrtf(var + 1e-12f);
        __syncthreads();
        float (*O2)[17] = (float(*)[17])(&Xl[0][0][0]);
        #pragma unroll
        for (int nt = 0; nt < NT; ++nt)
            #pragma unroll
            for (int r = 0; r < 4; ++r) {
                int m = (l >> 4) * 4 + r;
                int pxl = wv * 64 + nt * 16 + (l & 15);
                int px = pt * 256 + pxl;
                float gam = acc[0][nt][r] + bb0[m];
                float bet = acc[1][nt][r] + bb1[m];
                float xv = xsrc[((size_t)b * NP + m) * P + px];
                O2[pxl][m] = (xv - mu) * rs * (1.f + gam) + bet;
            }
        __syncthreads();
        float a = bcf[0];
        #pragma unroll
        for (int ci = 0; ci < 16; ++ci) a += wcf[ci] * O2[t][ci];
        fout[(size_t)b * P + pt * 256 + t] = softplus_f(a);
    }
}

// -------------------- 5b. sum partials + bias + relu -> hshT ----------------
__global__ __launch_bounds__(256) void k_hsh_fin(const ushort* __restrict__ part,
                                                 const float* __restrict__ b0,
                                                 const float* __restrict__ b1,
                                                 const float* __restrict__ b2,
                                                 ushort* __restrict__ hsh) {
    int gid = blockIdx.x * 256 + threadIdx.x;
    int grp = gid % 48, pixg = gid / 48;
    int ch0 = grp * 8;
    size_t base = (size_t)pixg * 384 + ch0;
    s16x8 p0 = *(const s16x8*)&part[(size_t)0 * B * P * 384 + base];
    s16x8 p1 = *(const s16x8*)&part[(size_t)1 * B * P * 384 + base];
    s16x8 p2 = *(const s16x8*)&part[(size_t)2 * B * P * 384 + base];
    int sel = ch0 >> 7;
    const float* bp = sel == 0 ? b0 : (sel == 1 ? b1 : b2);
    int cb = ch0 & 127;
    s16x8 o;
    #pragma unroll
    for (int i = 0; i < 8; ++i) {
        float v = bf2f((ushort)p0[i]) + bf2f((ushort)p1[i]) + bf2f((ushort)p2[i]) + bp[cb + i];
        o[i] = (short)f2bf(fmaxf(v, 0.f));
    }
    *(s16x8*)&hsh[base] = o;
}

// -------------------- 6. c1x1_a finalize: sum 96 partials + softplus + LN1 --
__global__ __launch_bounds__(256) void k_c1a_fin(const float* __restrict__ part,
                                                 const float* __restrict__ bias,
                                                 float* __restrict__ h1a,
                                                 float* __restrict__ stats) {
    int b = blockIdx.y, t = threadIdx.x;
    int idx = blockIdx.x * 256 + t;              // 32 blocks x 256 = 8192
    int o = idx >> 10, pix = idx & 1023;
    float v = 0.f;
    #pragma unroll 8
    for (int ct = 0; ct < 96; ++ct)
        v += part[(((size_t)b * 96 + ct) * 8 + o) * P + pix];
    v += bias[o];
    v = softplus_f(v);
    h1a[((size_t)b * 8 + o) * P + pix] = v;
    float s = v, q = v * v;
    for (int o2 = 32; o2 > 0; o2 >>= 1) { s += __shfl_down(s, o2); q += __shfl_down(q, o2); }
    __shared__ float ls[4], lq[4];
    int w = t >> 6;
    if ((t & 63) == 0) { ls[w] = s; lq[w] = q; }
    __syncthreads();
    if (t == 0) {
        atomicAdd(&stats[(B + b) * 2],     ls[0] + ls[1] + ls[2] + ls[3]);
        atomicAdd(&stats[(B + b) * 2 + 1], lq[0] + lq[1] + lq[2] + lq[3]);
    }
}

extern "C" void kernel_launch(void* const* d_in, const int* in_sizes, int n_in,
                              void* d_out, int out_size, void* d_ws, size_t ws_size,
                              hipStream_t stream) {
    const float* x_main = (const float*)d_in[0];
    const float* f_sem  = (const float*)d_in[1];
    const float* w_sh0 = (const float*)d_in[2];  const float* b_sh0 = (const float*)d_in[3];
    const float* w_g0  = (const float*)d_in[4];  const float* b_g0  = (const float*)d_in[5];
    const float* w_be0 = (const float*)d_in[6];  const float* b_be0 = (const float*)d_in[7];
    const float* w_sh1 = (const float*)d_in[8];  const float* b_sh1 = (const float*)d_in[9];
    const float* w_g1  = (const float*)d_in[10]; const float* b_g1  = (const float*)d_in[11];
    const float* w_be1 = (const float*)d_in[12]; const float* b_be1 = (const float*)d_in[13];
    const float* w_sh2 = (const float*)d_in[14]; const float* b_sh2 = (const float*)d_in[15];
    const float* w_g2  = (const float*)d_in[16]; const float* b_g2  = (const float*)d_in[17];
    const float* w_be2 = (const float*)d_in[18]; const float* b_be2 = (const float*)d_in[19];
    const float* w_c0  = (const float*)d_in[20]; const float* bias0 = (const float*)d_in[21];
    const float* w_c1  = (const float*)d_in[22]; const float* bias1 = (const float*)d_in[23];
    const float* w_c2  = (const float*)d_in[24]; const float* bias2 = (const float*)d_in[25];
    const int*   segmap = (const int*)d_in[26];

    float* ws = (float*)d_ws;
    float* out = (float*)d_out;
    float* stats = ws + OFF_STATS;
    ushort* hshU = (ushort*)(ws + OFF_HSHT);
    ushort* partU = (ushort*)(ws + OFF_OUT0);        // conv<0> bf16 partials
    float*  partA = ws + OFF_OUT0;                   // c1x1_a f32 partials (after hsh_fin)
    ushort* packU = (ushort*)(ws + OFF_PACK);

    hipMemsetAsync((void*)stats, 0, 16 * sizeof(float), stream);

    k_wpack<<<dim3(2412), 256, 0, stream>>>(w_sh0, w_sh1, w_sh2, w_g0, w_be0,
                                            w_g1, w_be1, w_g2, w_be2, packU);
    k_seg_avg<<<dim3(48, B), 256, 0, stream>>>(f_sem, segmap, ws);
    k_ln0_stats<<<dim3(64, B), 256, 0, stream>>>(x_main, stats);
    k_paint<<<dim3(4, 32, B), 256, 0, stream>>>(segmap, ws);

    k_conv_mfma<0><<<dim3(8, 12, 3 * B), 256, 0, stream>>>(
        ws + OFF_SEMT, nullptr, packU + PK0,
        nullptr, nullptr, nullptr, nullptr, 0.f,
        nullptr, nullptr, nullptr, nullptr, partU);
    k_hsh_fin<<<dim3(384), 256, 0, stream>>>(partU, b_sh0, b_sh1, b_sh2, hshU);

    // SPADE0 conv + LN0 combine + fused c1x1_a split-K partials
    k_conv_mfma<1><<<dim3(4, 96, B), 256, 0, stream>>>(
        nullptr, hshU, packU + PK1,
        b_g0, b_be0, x_main, stats, 1.f / (float)(CM * P),
        w_c0, nullptr, partA, nullptr, nullptr);
    k_c1a_fin<<<dim3(32, B), 256, 0, stream>>>(partA, bias0, ws + OFF_H1A, stats);

    // SPADE1 conv + LN1 combine + fused c1x1_b + softplus + LN2 stats
    k_conv_mfma<2><<<dim3(4, 1, B), 256, 0, stream>>>(
        nullptr, hshU, packU + PK2,
        b_g1, b_be1, ws + OFF_H1A, stats + 2 * B, 1.f / (float)(8 * P),
        w_c1, bias1, ws + OFF_H2A, stats + 4 * B, nullptr);

    // SPADE2 conv + LN2 combine + fused final 1x1 + softplus -> d_out
    k_conv_mfma<3><<<dim3(4, 1, B), 256, 0, stream>>>(
        nullptr, hshU, packU + PK3,
        b_g2, b_be2, ws + OFF_H2A, stats + 4 * B, 1.f / (float)(16 * P),
        w_c2, bias2, out, nullptr, nullptr);
}

// Round 12
// 282.489 us; speedup vs baseline: 4.1017x; 1.0846x over previous
//
#include <hip/hip_runtime.h>
#include <hip/hip_bf16.h>

#define DEV __device__ __forceinline__

constexpr int B = 2;
constexpr int CM = 1536;
constexpr int CS = 384;
constexpr int HP = 32, WP = 32, P = 1024;
constexpr int HI = 448, WI = 448;
constexpr int HM = 128;
constexpr int NSEG = 64;

// ws layout (float units)
constexpr size_t OFF_AVG  = 0;          // B*64*384
constexpr size_t OFF_SEMT = 49152;      // ushort semB[B][1024][384] (bf16, half region)
constexpr size_t OFF_HSHT = 835584;     // ushort hshT[B][1024][384]
constexpr size_t OFF_OUT0 = 1622016;    // scratch: conv<0> bf16 partials, then c1x1a f32 partials
constexpr size_t OFF_WTBL = 4767744;    // f32 W[b][1024][64] = 131072 floats
constexpr size_t OFF_H1A  = 5160960;
constexpr size_t OFF_H2A  = 5193728;
constexpr size_t OFF_STATS= 5259264;    // 16 floats
constexpr size_t OFF_PACK = 5259280;    // bf16 packed weights

// packed-weight element offsets (ushort units)
constexpr size_t PK0 = 0;           // [12ct][12kc][9tap][32co][32ci]
constexpr size_t PK1 = 1327104;     // [96ct][4kc][9tap][32co][32ci]
constexpr size_t PK2 = 4866048;     // [4kc][9tap][32co][32ci] (rows 8-15,24-31 zero)
constexpr size_t PK3 = 4902912;     // [4kc][9tap][32co][32ci]

typedef __attribute__((ext_vector_type(8))) short s16x8;
typedef __attribute__((ext_vector_type(4))) float f32x4;

DEV float softplus_f(float x) {
    return fmaxf(x, 0.f) + log1pf(expf(-fabsf(x)));
}
DEV ushort f2bf(float f) {
    union { float f; unsigned u; } x; x.f = f;
    unsigned r = x.u + 0x7fffu + ((x.u >> 16) & 1u);
    return (ushort)(r >> 16);
}
DEV float bf2f(ushort u) {
    union { unsigned u; float f; } x; x.u = ((unsigned)u) << 16;
    return x.f;
}

// -------------------- 1. segment averages (coalesced, 96 blocks) ------------
__global__ __launch_bounds__(256) void k_seg_avg(const float* __restrict__ f_sem,
                                                 const int* __restrict__ segmap,
                                                 float* __restrict__ ws) {
    int b = blockIdx.y;
    int c0 = blockIdx.x * 8;
    __shared__ int   segs[P];
    __shared__ float sums[NSEG][9];
    __shared__ float cnt[NSEG];
    int t = threadIdx.x;
    for (int i = t; i < NSEG * 9; i += 256) (&sums[0][0])[i] = 0.f;
    if (t < NSEG) cnt[t] = 0.f;
    __syncthreads();
    for (int p = t; p < P; p += 256) {
        int i = p >> 5, j = p & 31;
        int s = segmap[(b * HI + i * 14) * WI + j * 14];
        s = min(max(s, 0), NSEG - 1);
        segs[p] = s;
        atomicAdd(&cnt[s], 1.f);
    }
    __syncthreads();
    #pragma unroll
    for (int ch = 0; ch < 8; ++ch) {
        const float* fp = f_sem + ((size_t)b * CS + c0 + ch) * P;
        #pragma unroll
        for (int pb = 0; pb < 4; ++pb) {
            int p = pb * 256 + t;
            float v = fp[p];
            atomicAdd(&sums[segs[p]][ch], v);
        }
    }
    __syncthreads();
    for (int i = t; i < NSEG * 8; i += 256) {
        int s = i >> 3, ch = i & 7;
        float cv = cnt[s];
        ws[OFF_AVG + ((size_t)(b * NSEG + s)) * CS + c0 + ch] =
            cv > 0.f ? sums[s][ch] / cv : 0.f;
    }
}

// -------------------- 2a. paint phase 1: per-pixel seg weights --------------
__global__ __launch_bounds__(256) void k_paint_w(const int* __restrict__ segmap,
                                                 float* __restrict__ Wt) {
    int oxt = blockIdx.x, oy = blockIdx.y, b = blockIdx.z;
    int ox0 = oxt * 8;
    __shared__ float WbT[8][65];
    __shared__ float norm[8];
    int t = threadIdx.x;
    for (int i = t; i < 8 * 65; i += 256) (&WbT[0][0])[i] = 0.f;
    __syncthreads();

    float cy = 14.f * oy + 6.5f;
    int y0 = 14 * oy - 7;
    int x0 = 14 * ox0 - 7;
    for (int k = t; k < 28 * 126; k += 256) {
        int r = k / 126, cix = k % 126;
        int jy = y0 + r, jx = x0 + cix;
        if (jy < 0 || jy >= HI || jx < 0 || jx >= WI) continue;
        float wy = 1.f - fabsf(cy - (float)jy) * (1.f / 14.f);
        int s = segmap[(b * HI + jy) * WI + jx];
        s = min(max(s, 0), NSEG - 1);
        int oxhi = (jx + 7) / 14;
        #pragma unroll
        for (int d = 0; d < 2; ++d) {
            int ox = oxhi - d;
            if (ox < ox0 || ox >= ox0 + 8) continue;
            float wx = 1.f - fabsf(14.f * ox + 6.5f - (float)jx) * (1.f / 14.f);
            if (wx > 0.f) atomicAdd(&WbT[ox - ox0][s], wy * wx);
        }
    }
    __syncthreads();
    if (t < 8) {
        float sm = 0.f;
        #pragma unroll
        for (int s = 0; s < NSEG; ++s) sm += WbT[t][s];
        norm[t] = 1.f / sm;
    }
    __syncthreads();
    for (int i = t; i < 8 * 64; i += 256) {
        int ox = i >> 6, s = i & 63;
        int op = oy * 32 + ox0 + ox;
        Wt[((size_t)b * P + op) * 64 + s] = WbT[ox][s] * norm[ox];
    }
}

// -------------------- 2b. paint phase 2: [1024x64]x[64x384] -> bf16 semB ----
__global__ __launch_bounds__(256) void k_paint_gemv(const float* __restrict__ Wt,
                                                    const float* __restrict__ avg,
                                                    ushort* __restrict__ semB) {
    int pt = blockIdx.x, ctb = blockIdx.y, b = blockIdx.z;   // 32 x 12 x B
    __shared__ float WL[32][65];
    __shared__ float AL[64][33];
    int t = threadIdx.x;
    for (int i = t; i < 2048; i += 256) {
        int p = i >> 6, s = i & 63;
        WL[p][s] = Wt[((size_t)b * P + pt * 32 + p) * 64 + s];
    }
    for (int i = t; i < 2048; i += 256) {
        int s = i >> 5, c = i & 31;
        AL[s][c] = avg[((size_t)b * NSEG + s) * CS + ctb * 32 + c];
    }
    __syncthreads();
    int c = t & 31, pg = t >> 5;    // 8 pixel groups
    float acc[4] = {};
    #pragma unroll 16
    for (int s = 0; s < 64; ++s) {
        float a = AL[s][c];
        #pragma unroll
        for (int k = 0; k < 4; ++k) acc[k] += WL[pg + 8 * k][s] * a;
    }
    #pragma unroll
    for (int k = 0; k < 4; ++k) {
        int pix = pt * 32 + pg + 8 * k;
        semB[((size_t)b * P + pix) * 384 + ctb * 32 + c] = f2bf(acc[k]);
    }
}

// -------------------- 3. LN0 stats --------------------
__global__ __launch_bounds__(256) void k_ln0_stats(const float* __restrict__ x,
                                                   float* __restrict__ stats) {
    int b = blockIdx.y;
    const float4* xp = (const float4*)(x + (size_t)b * CM * P);
    int n4 = CM * P / 4;
    float s = 0.f, q = 0.f;
    for (int i = blockIdx.x * 256 + threadIdx.x; i < n4; i += 64 * 256) {
        float4 v = xp[i];
        s += v.x + v.y + v.z + v.w;
        q += v.x * v.x + v.y * v.y + v.z * v.z + v.w * v.w;
    }
    for (int o = 32; o > 0; o >>= 1) { s += __shfl_down(s, o); q += __shfl_down(q, o); }
    __shared__ float ls[4], lq[4];
    int w = threadIdx.x >> 6;
    if ((threadIdx.x & 63) == 0) { ls[w] = s; lq[w] = q; }
    __syncthreads();
    if (threadIdx.x == 0) {
        atomicAdd(&stats[b * 2],     ls[0] + ls[1] + ls[2] + ls[3]);
        atomicAdd(&stats[b * 2 + 1], lq[0] + lq[1] + lq[2] + lq[3]);
    }
}

// -------------------- 4. weight pre-pack v2: slice-per-block LDS transpose --
// slices: 144 mode0 | 384 mode1 | 4 mode2 | 4 mode3  (total 536)
__global__ __launch_bounds__(256) void k_wpack(
    const float* __restrict__ w_sh0, const float* __restrict__ w_sh1, const float* __restrict__ w_sh2,
    const float* __restrict__ w_g0,  const float* __restrict__ w_be0,
    const float* __restrict__ w_g1,  const float* __restrict__ w_be1,
    const float* __restrict__ w_g2,  const float* __restrict__ w_be2,
    ushort* __restrict__ packU)
{
    int sl = blockIdx.x;
    __shared__ float buf[32][289];
    __shared__ const float* sp[32];
    __shared__ size_t pbase_s;
    int t = threadIdx.x;
    if (t < 32) {
        int co2 = t;
        const float* p = nullptr;
        size_t pbase;
        if (sl < 144) {
            int ct = sl / 12, kct = sl % 12;
            int coG = ct * 32 + co2, sel = coG >> 7, cow = coG & 127;
            const float* wp = sel == 0 ? w_sh0 : (sel == 1 ? w_sh1 : w_sh2);
            p = wp + ((size_t)cow * CS + kct * 32) * 9;
            pbase = PK0 + (size_t)sl * 9216;
        } else if (sl < 528) {
            int s2 = sl - 144;
            int ct = s2 / 4, kct = s2 % 4;
            int cog = ct * 16 + (co2 & 15);
            const float* wp = co2 < 16 ? w_g0 : w_be0;
            p = wp + ((size_t)cog * HM + kct * 32) * 9;
            pbase = PK1 + (size_t)s2 * 9216;
        } else if (sl < 532) {
            int kct = sl - 528;
            int cog = co2 & 7;
            const float* wp = co2 < 16 ? w_g1 : w_be1;
            p = ((co2 & 15) >= 8) ? nullptr : wp + ((size_t)cog * HM + kct * 32) * 9;
            pbase = PK2 + (size_t)kct * 9216;
        } else {
            int kct = sl - 532;
            int cog = co2 & 15;
            const float* wp = co2 < 16 ? w_g2 : w_be2;
            p = wp + ((size_t)cog * HM + kct * 32) * 9;
            pbase = PK3 + (size_t)kct * 9216;
        }
        sp[co2] = p;
        if (t == 0) pbase_s = pbase;
    }
    __syncthreads();
    // stage: 32 rows x 288 consecutive floats, coalesced
    for (int j = t; j < 9216; j += 256) {
        int co2 = j / 288, idx = j % 288;
        const float* p = sp[co2];
        buf[co2][idx] = p ? p[idx] : 0.f;
    }
    __syncthreads();
    // emit packed [tap][co2][ci], stride-9 LDS reads (conflict-free), coalesced writes
    size_t pbase = pbase_s;
    for (int j = t; j < 9216; j += 256) {
        int tap = j >> 10, co2 = (j >> 5) & 31, ci = j & 31;
        packU[pbase + j] = f2bf(buf[co2][ci * 9 + tap]);
    }
}

// -------------------- 5. MFMA 3x3 conv (9 shifted GEMMs) --------------------
// MODE0: semB bf16, K-split x3, 4-row tiles -> bf16 PARTIAL
// MODE1: hshT ch0..127 -> LN0-combine -> FUSED c1x1_a partial (w_c0) -> fout
// MODE2: hshT ch128..255 -> LN1-combine -> FUSED c1x1_b+softplus -> h2a + LN2 stats
// MODE3: hshT ch256..383 -> LN2-combine -> FUSED final 1x1+softplus -> d_out
template<int MODE>
__global__ __launch_bounds__(256) void k_conv_mfma(
    const ushort* __restrict__ hshTin,
    const ushort* __restrict__ packW,
    const float* __restrict__ bb0, const float* __restrict__ bb1,
    const float* __restrict__ xsrc, const float* __restrict__ st, float Ninv,
    const float* __restrict__ wcf, const float* __restrict__ bcf,
    float* __restrict__ fout, float* __restrict__ statsOut,
    ushort* __restrict__ outH)
{
    constexpr int ROWS = (MODE == 0) ? 4 : 8;
    constexpr int NT   = ROWS / 2;
    constexpr int XR   = ROWS + 2;
    constexpr int KTOT = (MODE == 0) ? 12 : 4;
    constexpr int CBASE = (MODE == 2) ? 128 : (MODE == 3) ? 256 : 0;
    constexpr int NP = (MODE == 1) ? 1536 : (MODE == 2) ? 8 : 16;

    int pt = blockIdx.x, ctile = blockIdx.y;
    int zz = blockIdx.z;
    int b  = (MODE == 0) ? (zz % B) : zz;
    int ks = (MODE == 0) ? (zz / B) : 0;
    int t = threadIdx.x, l = t & 63, wv = t >> 6;
    int y0 = pt * ROWS;

    __shared__ __align__(16) ushort Wl[9][32][40];
    __shared__ __align__(16) ushort Xl[XR][34][40];

    f32x4 acc[2][NT] = {};

    for (int kc = 0; kc < 128; kc += 32) {
        __syncthreads();
        for (int j = t; j < XR * 34 * 4; j += 256) {
            int slot = j >> 2, part = j & 3;
            int r = slot / 34, c = slot % 34;
            int gy = y0 - 1 + r, gx = c - 1;
            s16x8 v = {};
            if (gy >= 0 && gy < HP && gx >= 0 && gx < WP) {
                int pix = gy * WP + gx;
                v = *(const s16x8*)&hshTin[((size_t)b * P + pix) * 384 + CBASE
                                           + (MODE == 0 ? ks * 128 : 0) + kc + part * 8];
            }
            *(s16x8*)&Xl[r][c][part * 8] = v;
        }
        const ushort* wsrc = packW + (size_t)(ctile * KTOT + ks * 4 + (kc >> 5)) * 9216;
        for (int j = t; j < 1152; j += 256) {
            int tap = j >> 7, co2 = (j >> 2) & 31, part = j & 3;
            *(s16x8*)&Wl[tap][co2][part * 8] = *(const s16x8*)&wsrc[(size_t)j * 8];
        }
        __syncthreads();
        #pragma unroll
        for (int tap = 0; tap < 9; ++tap) {
            int dy = tap / 3, dx = tap % 3;
            s16x8 a0 = *(const s16x8*)&Wl[tap][l & 15][(l >> 4) * 8];
            s16x8 a1 = *(const s16x8*)&Wl[tap][16 + (l & 15)][(l >> 4) * 8];
            #pragma unroll
            for (int nt = 0; nt < NT; ++nt) {
                int q = wv * (16 * NT) + nt * 16 + (l & 15);
                int ry = (q >> 5) + dy, rx = (q & 31) + dx;
                s16x8 bf = *(const s16x8*)&Xl[ry][rx][(l >> 4) * 8];
                acc[0][nt] = __builtin_amdgcn_mfma_f32_16x16x32_bf16(a0, bf, acc[0][nt], 0, 0, 0);
                acc[1][nt] = __builtin_amdgcn_mfma_f32_16x16x32_bf16(a1, bf, acc[1][nt], 0, 0, 0);
            }
        }
    }

    if constexpr (MODE == 0) {
        __syncthreads();
        ushort (*T)[36] = (ushort(*)[36])(&Xl[0][0][0]);
        #pragma unroll
        for (int mt = 0; mt < 2; ++mt)
            #pragma unroll
            for (int nt = 0; nt < NT; ++nt)
                #pragma unroll
                for (int r = 0; r < 4; ++r) {
                    int m = mt * 16 + (l >> 4) * 4 + r;
                    int pl = wv * (16 * NT) + nt * 16 + (l & 15);
                    T[pl][m] = f2bf(acc[mt][nt][r]);
                }
        __syncthreads();
        int row = t >> 1, half = t & 1;
        ushort* dst = outH + ((size_t)((ks * B + b) * P) + pt * 128 + row) * 384 + ctile * 32 + half * 16;
        *(s16x8*)dst = *(const s16x8*)&T[row][half * 16];
    } else if constexpr (MODE == 1) {
        float mu = st[b * 2] * Ninv;
        float var = st[b * 2 + 1] * Ninv - mu * mu;
        float rs = rsqrtf(var + 1e-12f);
        __syncthreads();
        float (*WC)[17] = (float(*)[17])(&Wl[0][0][0]);
        if (t < 128) WC[t >> 4][t & 15] = wcf[(size_t)(t >> 4) * CM + ctile * 16 + (t & 15)];
        __syncthreads();
        float pacc[8][4] = {};
        #pragma unroll
        for (int nt = 0; nt < NT; ++nt)
            #pragma unroll
            for (int r = 0; r < 4; ++r) {
                int m = (l >> 4) * 4 + r;
                int cog = ctile * 16 + m;
                int px = pt * 256 + wv * 64 + nt * 16 + (l & 15);
                float gam = acc[0][nt][r] + bb0[cog];
                float bet = acc[1][nt][r] + bb1[cog];
                float xv = xsrc[((size_t)b * NP + cog) * P + px];
                float o0 = (xv - mu) * rs * (1.f + gam) + bet;
                #pragma unroll
                for (int o = 0; o < 8; ++o) pacc[o][nt] += WC[o][m] * o0;
            }
        #pragma unroll
        for (int o = 0; o < 8; ++o)
            #pragma unroll
            for (int nt = 0; nt < NT; ++nt) {
                float v = pacc[o][nt];
                v += __shfl_xor(v, 16);
                v += __shfl_xor(v, 32);
                if ((l >> 4) == 0)
                    fout[(((size_t)b * 96 + ctile) * 8 + o) * P + pt * 256 + wv * 64 + nt * 16 + l] = v;
            }
    } else if constexpr (MODE == 2) {
        float mu = st[b * 2] * Ninv;
        float var = st[b * 2 + 1] * Ninv - mu * mu;
        float rs = rsqrtf(var + 1e-12f);
        __syncthreads();
        float (*O1)[9] = (float(*)[9])(&Xl[0][0][0]);
        #pragma unroll
        for (int nt = 0; nt < NT; ++nt)
            #pragma unroll
            for (int r = 0; r < 4; ++r) {
                int m = (l >> 4) * 4 + r;
                if (m < 8) {
                    int pxl = wv * 64 + nt * 16 + (l & 15);
                    int px = pt * 256 + pxl;
                    float gam = acc[0][nt][r] + bb0[m];
                    float bet = acc[1][nt][r] + bb1[m];
                    float xv = xsrc[((size_t)b * NP + m) * P + px];
                    O1[pxl][m] = (xv - mu) * rs * (1.f + gam) + bet;
                }
            }
        __syncthreads();
        float vin[8];
        #pragma unroll
        for (int ci = 0; ci < 8; ++ci) vin[ci] = O1[t][ci];
        float s = 0.f, q = 0.f;
        #pragma unroll
        for (int o = 0; o < 16; ++o) {
            float a = bcf[o];
            #pragma unroll
            for (int ci = 0; ci < 8; ++ci) a += wcf[o * 8 + ci] * vin[ci];
            a = softplus_f(a);
            fout[((size_t)b * 16 + o) * P + pt * 256 + t] = a;
            s += a; q += a * a;
        }
        for (int o2 = 32; o2 > 0; o2 >>= 1) { s += __shfl_down(s, o2); q += __shfl_down(q, o2); }
        float* red = (float*)&Wl[0][0][0];
        if ((t & 63) == 0) { red[wv] = s; red[4 + wv] = q; }
        __syncthreads();
        if (t == 0) {
            atomicAdd(&statsOut[b * 2],     red[0] + red[1] + red[2] + red[3]);
            atomicAdd(&statsOut[b * 2 + 1], red[4] + red[5] + red[6] + red[7]);
        }
    } else {
        float mu = st[b * 2] * Ninv;
        float var = st[b * 2 + 1] * Ninv - mu * mu;
        float rs = rsqrtf(var + 1e-12f);
        __syncthreads();
        float (*O2)[17] = (float(*)[17])(&Xl[0][0][0]);
        #pragma unroll
        for (int nt = 0; nt < NT; ++nt)
            #pragma unroll
            for (int r = 0; r < 4; ++r) {
                int m = (l >> 4) * 4 + r;
                int pxl = wv * 64 + nt * 16 + (l & 15);
                int px = pt * 256 + pxl;
                float gam = acc[0][nt][r] + bb0[m];
                float bet = acc[1][nt][r] + bb1[m];
                float xv = xsrc[((size_t)b * NP + m) * P + px];
                O2[pxl][m] = (xv - mu) * rs * (1.f + gam) + bet;
            }
        __syncthreads();
        float a = bcf[0];
        #pragma unroll
        for (int ci = 0; ci < 16; ++ci) a += wcf[ci] * O2[t][ci];
        fout[(size_t)b * P + pt * 256 + t] = softplus_f(a);
    }
}

// -------------------- 5b. sum partials + bias + relu -> hshT ----------------
__global__ __launch_bounds__(256) void k_hsh_fin(const ushort* __restrict__ part,
                                                 const float* __restrict__ b0,
                                                 const float* __restrict__ b1,
                                                 const float* __restrict__ b2,
                                                 ushort* __restrict__ hsh) {
    int gid = blockIdx.x * 256 + threadIdx.x;
    int grp = gid % 48, pixg = gid / 48;
    int ch0 = grp * 8;
    size_t base = (size_t)pixg * 384 + ch0;
    s16x8 p0 = *(const s16x8*)&part[(size_t)0 * B * P * 384 + base];
    s16x8 p1 = *(const s16x8*)&part[(size_t)1 * B * P * 384 + base];
    s16x8 p2 = *(const s16x8*)&part[(size_t)2 * B * P * 384 + base];
    int sel = ch0 >> 7;
    const float* bp = sel == 0 ? b0 : (sel == 1 ? b1 : b2);
    int cb = ch0 & 127;
    s16x8 o;
    #pragma unroll
    for (int i = 0; i < 8; ++i) {
        float v = bf2f((ushort)p0[i]) + bf2f((ushort)p1[i]) + bf2f((ushort)p2[i]) + bp[cb + i];
        o[i] = (short)f2bf(fmaxf(v, 0.f));
    }
    *(s16x8*)&hsh[base] = o;
}

// -------------------- 6. c1x1_a finalize: sum 96 partials + softplus + LN1 --
__global__ __launch_bounds__(256) void k_c1a_fin(const float* __restrict__ part,
                                                 const float* __restrict__ bias,
                                                 float* __restrict__ h1a,
                                                 float* __restrict__ stats) {
    int b = blockIdx.y, t = threadIdx.x;
    int idx = blockIdx.x * 256 + t;
    int o = idx >> 10, pix = idx & 1023;
    float v = 0.f;
    #pragma unroll 8
    for (int ct = 0; ct < 96; ++ct)
        v += part[(((size_t)b * 96 + ct) * 8 + o) * P + pix];
    v += bias[o];
    v = softplus_f(v);
    h1a[((size_t)b * 8 + o) * P + pix] = v;
    float s = v, q = v * v;
    for (int o2 = 32; o2 > 0; o2 >>= 1) { s += __shfl_down(s, o2); q += __shfl_down(q, o2); }
    __shared__ float ls[4], lq[4];
    int w = t >> 6;
    if ((t & 63) == 0) { ls[w] = s; lq[w] = q; }
    __syncthreads();
    if (t == 0) {
        atomicAdd(&stats[(B + b) * 2],     ls[0] + ls[1] + ls[2] + ls[3]);
        atomicAdd(&stats[(B + b) * 2 + 1], lq[0] + lq[1] + lq[2] + lq[3]);
    }
}

extern "C" void kernel_launch(void* const* d_in, const int* in_sizes, int n_in,
                              void* d_out, int out_size, void* d_ws, size_t ws_size,
                              hipStream_t stream) {
    const float* x_main = (const float*)d_in[0];
    const float* f_sem  = (const float*)d_in[1];
    const float* w_sh0 = (const float*)d_in[2];  const float* b_sh0 = (const float*)d_in[3];
    const float* w_g0  = (const float*)d_in[4];  const float* b_g0  = (const float*)d_in[5];
    const float* w_be0 = (const float*)d_in[6];  const float* b_be0 = (const float*)d_in[7];
    const float* w_sh1 = (const float*)d_in[8];  const float* b_sh1 = (const float*)d_in[9];
    const float* w_g1  = (const float*)d_in[10]; const float* b_g1  = (const float*)d_in[11];
    const float* w_be1 = (const float*)d_in[12]; const float* b_be1 = (const float*)d_in[13];
    const float* w_sh2 = (const float*)d_in[14]; const float* b_sh2 = (const float*)d_in[15];
    const float* w_g2  = (const float*)d_in[16]; const float* b_g2  = (const float*)d_in[17];
    const float* w_be2 = (const float*)d_in[18]; const float* b_be2 = (const float*)d_in[19];
    const float* w_c0  = (const float*)d_in[20]; const float* bias0 = (const float*)d_in[21];
    const float* w_c1  = (const float*)d_in[22]; const float* bias1 = (const float*)d_in[23];
    const float* w_c2  = (const float*)d_in[24]; const float* bias2 = (const float*)d_in[25];
    const int*   segmap = (const int*)d_in[26];

    float* ws = (float*)d_ws;
    float* out = (float*)d_out;
    float* stats = ws + OFF_STATS;
    ushort* semB = (ushort*)(ws + OFF_SEMT);
    ushort* hshU = (ushort*)(ws + OFF_HSHT);
    ushort* partU = (ushort*)(ws + OFF_OUT0);        // conv<0> bf16 partials
    float*  partA = ws + OFF_OUT0;                   // c1x1_a f32 partials (after hsh_fin)
    float*  Wtbl  = ws + OFF_WTBL;
    ushort* packU = (ushort*)(ws + OFF_PACK);

    hipMemsetAsync((void*)stats, 0, 16 * sizeof(float), stream);

    k_wpack<<<dim3(536), 256, 0, stream>>>(w_sh0, w_sh1, w_sh2, w_g0, w_be0,
                                           w_g1, w_be1, w_g2, w_be2, packU);
    k_seg_avg<<<dim3(48, B), 256, 0, stream>>>(f_sem, segmap, ws);
    k_ln0_stats<<<dim3(64, B), 256, 0, stream>>>(x_main, stats);
    k_paint_w<<<dim3(4, 32, B), 256, 0, stream>>>(segmap, Wtbl);
    k_paint_gemv<<<dim3(32, 12, B), 256, 0, stream>>>(Wtbl, ws + OFF_AVG, semB);

    k_conv_mfma<0><<<dim3(8, 12, 3 * B), 256, 0, stream>>>(
        semB, packU + PK0,
        nullptr, nullptr, nullptr, nullptr, 0.f,
        nullptr, nullptr, nullptr, nullptr, partU);
    k_hsh_fin<<<dim3(384), 256, 0, stream>>>(partU, b_sh0, b_sh1, b_sh2, hshU);

    // SPADE0 conv + LN0 combine + fused c1x1_a split-K partials
    k_conv_mfma<1><<<dim3(4, 96, B), 256, 0, stream>>>(
        hshU, packU + PK1,
        b_g0, b_be0, x_main, stats, 1.f / (float)(CM * P),
        w_c0, nullptr, partA, nullptr, nullptr);
    k_c1a_fin<<<dim3(32, B), 256, 0, stream>>>(partA, bias0, ws + OFF_H1A, stats);

    // SPADE1 conv + LN1 combine + fused c1x1_b + softplus + LN2 stats
    k_conv_mfma<2><<<dim3(4, 1, B), 256, 0, stream>>>(
        hshU, packU + PK2,
        b_g1, b_be1, ws + OFF_H1A, stats + 2 * B, 1.f / (float)(8 * P),
        w_c1, bias1, ws + OFF_H2A, stats + 4 * B, nullptr);

    // SPADE2 conv + LN2 combine + fused final 1x1 + softplus -> d_out
    k_conv_mfma<3><<<dim3(4, 1, B), 256, 0, stream>>>(
        hshU, packU + PK3,
        b_g2, b_be2, ws + OFF_H2A, stats + 4 * B, 1.f / (float)(16 * P),
        w_c2, bias2, out, nullptr, nullptr);
}